// Round 1
// baseline (10147.904 us; speedup 1.0000x reference)
//
#include <hip/hip_runtime.h>
#include <hip/hip_bf16.h>
#include <math.h>

// ---------------- constants ----------------
#define CIN 256
#define NUM_CLASSES 91
#define NUM_ANCH 9
#define KEY_CAP 65536
#define NCAND 5000
#define NEGV -1000000000.0f
#define BBOX_CLIP_F 4.135166556742356f
#define CLS_THRESH 0.05f

// ---------------- conv 3x3, SAME, Cin=256 ----------------
// grid.x: pixel tiles of 256, grid.y: cout groups of CPT
template<int CPT, bool RELU>
__global__ void conv3x3_k(const float* __restrict__ in, const float* __restrict__ wt,
                          const float* __restrict__ bias, float* __restrict__ out,
                          int HW, int Wsh) {
    const int W = 1 << Wsh;
    const int H = HW >> Wsh;
    const int pix = blockIdx.x * 256 + threadIdx.x;
    const int cout0 = blockIdx.y * CPT;
    const bool act = pix < HW;
    const int y = pix >> Wsh;
    const int x = pix & (W - 1);

    float acc[CPT];
#pragma unroll
    for (int j = 0; j < CPT; ++j) acc[j] = bias[cout0 + j];

    const bool ym = act && (y > 0);
    const bool yp = act && (y < H - 1);
    const bool xm = (x > 0);
    const bool xp = (x < W - 1);

    const float* wbase = wt + (size_t)cout0 * CIN * 9;

    for (int cin = 0; cin < CIN; ++cin) {
        const float* ip = in + (size_t)cin * HW + pix;
        float v0 = (ym && xm) ? ip[-W - 1] : 0.0f;
        float v1 = ym          ? ip[-W]     : 0.0f;
        float v2 = (ym && xp) ? ip[-W + 1] : 0.0f;
        float v3 = (act && xm) ? ip[-1]    : 0.0f;
        float v4 = act         ? ip[0]     : 0.0f;
        float v5 = (act && xp) ? ip[1]     : 0.0f;
        float v6 = (yp && xm) ? ip[W - 1]  : 0.0f;
        float v7 = yp          ? ip[W]      : 0.0f;
        float v8 = (yp && xp) ? ip[W + 1]  : 0.0f;
        const float* wp = wbase + cin * 9;
#pragma unroll
        for (int j = 0; j < CPT; ++j) {
            const float* w9 = wp + (size_t)j * (CIN * 9);
            acc[j] = fmaf(v0, w9[0], acc[j]);
            acc[j] = fmaf(v1, w9[1], acc[j]);
            acc[j] = fmaf(v2, w9[2], acc[j]);
            acc[j] = fmaf(v3, w9[3], acc[j]);
            acc[j] = fmaf(v4, w9[4], acc[j]);
            acc[j] = fmaf(v5, w9[5], acc[j]);
            acc[j] = fmaf(v6, w9[6], acc[j]);
            acc[j] = fmaf(v7, w9[7], acc[j]);
            acc[j] = fmaf(v8, w9[8], acc[j]);
        }
    }
    if (act) {
#pragma unroll
        for (int j = 0; j < CPT; ++j) {
            float r = RELU ? fmaxf(acc[j], 0.0f) : acc[j];
            out[(size_t)(cout0 + j) * HW + pix] = r;
        }
    }
}

// ---------------- collect valid candidates ----------------
// logits layout [819][HW]; flat score index = (pix*9 + a)*91 + cls, ch = a*91+cls
__global__ void collect_k(const float* __restrict__ logits, int HWsh, int HW,
                          unsigned long long* __restrict__ keys, int* __restrict__ cnt,
                          int total) {
    int r = blockIdx.x * 256 + threadIdx.x;
    if (r >= total) return;
    float lg = logits[r];
    float s = 1.0f / (1.0f + expf(-lg));
    if (s > CLS_THRESH) {
        int ch = r >> HWsh;
        int pix = r & (HW - 1);
        int a = ch / NUM_CLASSES;
        int cls = ch - a * NUM_CLASSES;
        unsigned flat = (unsigned)((pix * NUM_ANCH + a) * NUM_CLASSES + cls);
        int pos = atomicAdd(cnt, 1);
        if (pos < KEY_CAP) {
            keys[pos] = ((unsigned long long)__float_as_uint(s) << 32) |
                        (unsigned long long)(~flat);
        }
    }
}

// ---------------- single-block bitonic sort (descending) ----------------
__global__ __launch_bounds__(1024) void sort_k(unsigned long long* keys, const int* cntp) {
    int n = *cntp;
    if (n > KEY_CAP) n = KEY_CAP;
    int m = 2;
    while (m < n) m <<= 1;
    for (int i = threadIdx.x; i < m; i += 1024)
        if (i >= n) keys[i] = 0ull;
    __syncthreads();
    for (int k = 2; k <= m; k <<= 1) {
        for (int j = k >> 1; j > 0; j >>= 1) {
            for (int i = threadIdx.x; i < m; i += 1024) {
                int ixj = i ^ j;
                if (ixj > i) {
                    unsigned long long a = keys[i], b = keys[ixj];
                    bool desc = ((i & k) == 0);
                    bool swap = desc ? (a < b) : (a > b);
                    if (swap) { keys[i] = b; keys[ixj] = a; }
                }
            }
            __syncthreads();
        }
    }
}

// ---------------- emit 1000 candidates for a level ----------------
__global__ void emit_k(const unsigned long long* __restrict__ keys, const int* __restrict__ cntp,
                       const float* __restrict__ regout, const float* __restrict__ anc,
                       int HW, float* __restrict__ cs, float* __restrict__ cb,
                       int* __restrict__ cl, int offs) {
#pragma clang fp contract(off)
    int r = blockIdx.x * 256 + threadIdx.x;
    if (r >= 1000) return;
    int n = *cntp;
    if (n > KEY_CAP) n = KEY_CAP;
    if (n > 1000) n = 1000;
    float score = -1.0f;
    float b0 = 0.f, b1 = 0.f, b2 = 0.f, b3 = 0.f;
    int label = 0;
    if (r < n) {
        unsigned long long key = keys[r];
        score = __uint_as_float((unsigned)(key >> 32));
        unsigned flat = ~((unsigned)(key & 0xFFFFFFFFull));
        label = (int)(flat % NUM_CLASSES);
        int af = (int)(flat / NUM_CLASSES);      // pix*9 + a
        int a = af % NUM_ANCH;
        int pix = af / NUM_ANCH;
        float dx = regout[(size_t)(a * 4 + 0) * HW + pix];
        float dy = regout[(size_t)(a * 4 + 1) * HW + pix];
        float dw = regout[(size_t)(a * 4 + 2) * HW + pix];
        float dh = regout[(size_t)(a * 4 + 3) * HW + pix];
        const float* an = anc + (size_t)af * 4;
        float aw = an[2] - an[0];
        float ah = an[3] - an[1];
        float cx = an[0] + 0.5f * aw;
        float cy = an[1] + 0.5f * ah;
        dw = fminf(dw, BBOX_CLIP_F);
        dh = fminf(dh, BBOX_CLIP_F);
        float pcx = dx * aw + cx;
        float pcy = dy * ah + cy;
        float pw = expf(dw) * aw;
        float ph = expf(dh) * ah;
        b0 = fminf(fmaxf(pcx - 0.5f * pw, 0.0f), 512.0f);
        b1 = fminf(fmaxf(pcy - 0.5f * ph, 0.0f), 512.0f);
        b2 = fminf(fmaxf(pcx + 0.5f * pw, 0.0f), 512.0f);
        b3 = fminf(fmaxf(pcy + 0.5f * ph, 0.0f), 512.0f);
    }
    cs[offs + r] = score;
    cb[(size_t)(offs + r) * 4 + 0] = b0;
    cb[(size_t)(offs + r) * 4 + 1] = b1;
    cb[(size_t)(offs + r) * 4 + 2] = b2;
    cb[(size_t)(offs + r) * 4 + 3] = b3;
    cl[offs + r] = label;
}

// ---------------- NMS, single block ----------------
__device__ inline unsigned long long umax64(unsigned long long a, unsigned long long b) {
    return a > b ? a : b;
}

__global__ __launch_bounds__(1024) void nms_k(const float* __restrict__ cs,
                                              const float* __restrict__ cb,
                                              const int* __restrict__ cl,
                                              float* __restrict__ out) {
#pragma clang fp contract(off)
    __shared__ float alive[NCAND];
    __shared__ unsigned long long wbest[16];
    __shared__ float bj[5];
    __shared__ int jsh;
    const int t = threadIdx.x;

    float b0[5], b1[5], b2[5], b3[5], ar[5];
#pragma unroll
    for (int q = 0; q < 5; ++q) {
        int c = t + q * 1024;
        if (c < NCAND) {
            float s = cs[c];
            float off = (float)cl[c] * 513.0f;   // max(boxes)=512 -> spacing 513; cross-class IoU==0 exactly
            float x1 = cb[(size_t)c * 4 + 0] + off;
            float y1 = cb[(size_t)c * 4 + 1] + off;
            float x2 = cb[(size_t)c * 4 + 2] + off;
            float y2 = cb[(size_t)c * 4 + 3] + off;
            b0[q] = x1; b1[q] = y1; b2[q] = x2; b3[q] = y2;
            ar[q] = (x2 - x1) * (y2 - y1);
            alive[c] = (s > CLS_THRESH) ? s : NEGV;
        }
    }
    __syncthreads();

    for (int step = 0; step < 300; ++step) {
        // ---- argmax(alive), tie -> lowest index ----
        unsigned long long best = 0ull;
#pragma unroll
        for (int q = 0; q < 5; ++q) {
            int c = t + q * 1024;
            if (c < NCAND) {
                unsigned u = __float_as_uint(alive[c]);
                u = (u & 0x80000000u) ? ~u : (u | 0x80000000u);
                unsigned long long key = ((unsigned long long)u << 32) |
                                         (unsigned long long)(0xFFFFFFFFu - (unsigned)c);
                best = umax64(best, key);
            }
        }
#pragma unroll
        for (int s = 32; s > 0; s >>= 1)
            best = umax64(best, (unsigned long long)__shfl_down(best, s, 64));
        if ((t & 63) == 0) wbest[t >> 6] = best;
        __syncthreads();
        if (t < 64) {
            unsigned long long bb = (t < 16) ? wbest[t] : 0ull;
#pragma unroll
            for (int s = 32; s > 0; s >>= 1)
                bb = umax64(bb, (unsigned long long)__shfl_down(bb, s, 64));
            if (t == 0) {
                jsh = (int)(0xFFFFFFFFu - (unsigned)(bb & 0xFFFFFFFFull));
            }
        }
        __syncthreads();
        const int j = jsh;
        if (t == (j & 1023)) {
            int q = j >> 10;
            float vj = alive[j];
            bool valid = vj > CLS_THRESH;
            bj[0] = b0[q]; bj[1] = b1[q]; bj[2] = b2[q]; bj[3] = b3[q]; bj[4] = ar[q];
            alive[j] = NEGV;
            out[step * 5 + 0] = valid ? cs[j] : 0.0f;
            out[step * 5 + 1] = valid ? cb[(size_t)j * 4 + 0] : 0.0f;
            out[step * 5 + 2] = valid ? cb[(size_t)j * 4 + 1] : 0.0f;
            out[step * 5 + 3] = valid ? cb[(size_t)j * 4 + 2] : 0.0f;
            out[step * 5 + 4] = valid ? cb[(size_t)j * 4 + 3] : 0.0f;
            out[1500 + step] = valid ? (float)cl[j] : -1.0f;
        }
        __syncthreads();
        float j0 = bj[0], j1 = bj[1], j2 = bj[2], j3 = bj[3], ja = bj[4];
#pragma unroll
        for (int q = 0; q < 5; ++q) {
            int c = t + q * 1024;
            if (c < NCAND) {
                float ltx = fmaxf(j0, b0[q]);
                float lty = fmaxf(j1, b1[q]);
                float rbx = fminf(j2, b2[q]);
                float rby = fminf(j3, b3[q]);
                float wx = fmaxf(rbx - ltx, 0.0f);
                float wy = fmaxf(rby - lty, 0.0f);
                float inter = wx * wy;
                float iou = inter / (ja + ar[q] - inter + 1e-12f);
                if (iou > 0.5f) alive[c] = NEGV;
            }
        }
        __syncthreads();
    }
}

// ---------------- host launch ----------------
extern "C" void kernel_launch(void* const* d_in, const int* in_sizes, int n_in,
                              void* d_out, int out_size, void* d_ws, size_t ws_size,
                              hipStream_t stream) {
    const float* feats[5] = {(const float*)d_in[0], (const float*)d_in[1],
                             (const float*)d_in[2], (const float*)d_in[3],
                             (const float*)d_in[4]};
    const float* anchors = (const float*)d_in[5];
    const float* ctw = (const float*)d_in[6];
    const float* ctb = (const float*)d_in[7];
    const float* cow = (const float*)d_in[8];
    const float* cob = (const float*)d_in[9];
    const float* rtw = (const float*)d_in[10];
    const float* rtb = (const float*)d_in[11];
    const float* row_ = (const float*)d_in[12];
    const float* rob = (const float*)d_in[13];
    float* out = (float*)d_out;

    float* ws = (float*)d_ws;
    float* actA = ws;                                   // 256*4096
    float* actB = actA + 256 * 4096;                    // 256*4096
    float* logits = actB + 256 * 4096;                  // 819*4096
    float* regout = logits + 819 * 4096;                // 36*4096
    float* cs = regout + 36 * 4096;                     // 5000
    float* cb = cs + NCAND;                             // 20000
    int* cl = (int*)(cb + NCAND * 4);                   // 5000
    int* cnt = cl + NCAND;                              // 1
    unsigned long long* keys = (unsigned long long*)actA;  // reused after convs (512 KB)

    const int HWs[5]  = {4096, 1024, 256, 64, 16};
    const int Wsh[5]  = {6, 5, 4, 3, 2};
    const int aoff[5] = {0, 36864, 46080, 48384, 48960};

    for (int l = 0; l < 5; ++l) {
        const int HW = HWs[l];
        const int sh = Wsh[l];
        const int pg = (HW + 255) / 256;

        // cls tower: feat -> A -> B -> A -> B
        const float* src = feats[l];
        float* dst = actA;
        for (int i = 0; i < 4; ++i) {
            conv3x3_k<8, true><<<dim3(pg, 32), 256, 0, stream>>>(
                src, ctw + (size_t)i * 256 * 256 * 9, ctb + i * 256, dst, HW, sh);
            src = dst;
            dst = (dst == actA) ? actB : actA;
        }
        conv3x3_k<9, false><<<dim3(pg, 91), 256, 0, stream>>>(
            src, cow, cob, logits, HW, sh);

        // reg tower
        src = feats[l];
        dst = actA;
        for (int i = 0; i < 4; ++i) {
            conv3x3_k<8, true><<<dim3(pg, 32), 256, 0, stream>>>(
                src, rtw + (size_t)i * 256 * 256 * 9, rtb + i * 256, dst, HW, sh);
            src = dst;
            dst = (dst == actA) ? actB : actA;
        }
        conv3x3_k<9, false><<<dim3(pg, 4), 256, 0, stream>>>(
            src, row_, rob, regout, HW, sh);

        // candidates
        hipMemsetAsync(cnt, 0, sizeof(int), stream);
        int total = HW * NUM_ANCH * NUM_CLASSES;
        collect_k<<<(total + 255) / 256, 256, 0, stream>>>(
            logits, 2 * sh, HW, keys, cnt, total);
        sort_k<<<1, 1024, 0, stream>>>(keys, cnt);
        emit_k<<<4, 256, 0, stream>>>(keys, cnt, regout,
                                      anchors + (size_t)aoff[l] * 4, HW,
                                      cs, cb, cl, l * 1000);
    }

    nms_k<<<1, 1024, 0, stream>>>(cs, cb, cl, out);
}

// Round 2
// 3122.735 us; speedup vs baseline: 3.2497x; 3.2497x over previous
//
#include <hip/hip_runtime.h>
#include <hip/hip_bf16.h>
#include <math.h>

#define CIN 256
#define NUM_CLASSES 91
#define NUM_ANCH 9
#define KEY_CAP 65536
#define NCAND 5000
#define BBOX_CLIP_F 4.135166556742356f
#define CLS_THRESH 0.05f
#define PITCH 5456
#define NTILES 23
#define CPT 16

__constant__ int c_tlvl[NTILES] = {0,0,0,0,0,0,0,0,0,0,0,0,0,0,0,0, 1,1,1,1, 2, 3, 4};
__constant__ int c_tg0[NTILES]  = {0,256,512,768,1024,1280,1536,1792,2048,2304,2560,2816,3072,3328,3584,3840,
                                   4096,4352,4608,4864, 5120, 5376, 5440};
__constant__ int c_wsh[5]  = {6,5,4,3,2};
__constant__ int c_hw[5]   = {4096,1024,256,64,16};
__constant__ int c_loff[5] = {0,4096,5120,5376,5440};
__constant__ int c_aoff[5] = {0,36864,46080,48384,48960};

// ---------------- pyramid gather ----------------
__global__ void pyr_k(const float* __restrict__ f0, const float* __restrict__ f1,
                      const float* __restrict__ f2, const float* __restrict__ f3,
                      const float* __restrict__ f4, float* __restrict__ P) {
    int idx = blockIdx.x * 256 + threadIdx.x;
    if (idx >= 256 * PITCH) return;
    int ch = idx / PITCH, g = idx - ch * PITCH;
    int lvl = (g < 4096) ? 0 : (g < 5120) ? 1 : (g < 5376) ? 2 : (g < 5440) ? 3 : 4;
    const float* f = (lvl == 0) ? f0 : (lvl == 1) ? f1 : (lvl == 2) ? f2 : (lvl == 3) ? f3 : f4;
    int lp = g - c_loff[lvl];
    P[idx] = f[(size_t)ch * c_hw[lvl] + lp];
}

// ---------------- conv core: 16 couts x 1 pixel per thread ----------------
template<bool RELU>
__device__ __forceinline__ void conv_core(const float* __restrict__ src,
        const float* __restrict__ wt, const float* __restrict__ bias,
        float* __restrict__ dst, int g, int lp, int lvl, int cout0, bool act)
{
    const int wsh = c_wsh[lvl];
    const int W = 1 << wsh;
    const int HW = c_hw[lvl];
    const int H = HW >> wsh;
    const int y = lp >> wsh;
    const int x = lp & (W - 1);
    const bool ym = act && (y > 0);
    const bool yp = act && (y < H - 1);
    const bool xm = (x > 0), xp = (x < W - 1);

    bool m[9];
    m[0] = ym && xm; m[1] = ym;  m[2] = ym && xp;
    m[3] = act && xm; m[4] = act; m[5] = act && xp;
    m[6] = yp && xm; m[7] = yp;  m[8] = yp && xp;
    int o[9];
    const int bo[9] = {-W - 1, -W, -W + 1, -1, 0, 1, W - 1, W, W + 1};
#pragma unroll
    for (int k = 0; k < 9; ++k) o[k] = m[k] ? bo[k] : 0;   // masked taps read own (valid) pixel

    float acc[CPT];
#pragma unroll
    for (int j = 0; j < CPT; ++j) acc[j] = bias[cout0 + j];
    const float* wb = wt + (size_t)cout0 * (CIN * 9);

#pragma unroll 2
    for (int cin = 0; cin < CIN; ++cin) {
        const float* ip = src + (size_t)cin * PITCH + g;
        float v[9];
#pragma unroll
        for (int k = 0; k < 9; ++k) { float t = ip[o[k]]; v[k] = m[k] ? t : 0.0f; }
        const float* wc = wb + cin * 9;
#pragma unroll
        for (int j = 0; j < CPT; ++j) {
            const float* w9 = wc + j * (CIN * 9);
#pragma unroll
            for (int k = 0; k < 9; ++k) acc[j] = fmaf(v[k], w9[k], acc[j]);
        }
    }
    if (act) {
#pragma unroll
        for (int j = 0; j < CPT; ++j)
            dst[(size_t)(cout0 + j) * PITCH + g] = RELU ? fmaxf(acc[j], 0.0f) : acc[j];
    }
}

// ---------------- fused tower layer: all levels, both towers ----------------
__global__ __launch_bounds__(256, 4) void tower_k(const float* __restrict__ srcC,
        const float* __restrict__ srcR, float* __restrict__ dstC, float* __restrict__ dstR,
        const float* __restrict__ wC, const float* __restrict__ bC,
        const float* __restrict__ wR, const float* __restrict__ bR)
{
    const int tile = blockIdx.x;
    const int lvl = c_tlvl[tile];
    const int g = c_tg0[tile] + threadIdx.x;
    const int lp = g - c_loff[lvl];
    const bool act = lp < c_hw[lvl];
    const int cout0 = blockIdx.y * CPT;
    if (blockIdx.z == 0) conv_core<true>(srcC, wC, bC, dstC, g, lp, lvl, cout0, act);
    else                 conv_core<true>(srcR, wR, bR, dstR, g, lp, lvl, cout0, act);
}

// ---------------- fused head layer: cls(819) + reg(36) ----------------
__global__ __launch_bounds__(256, 4) void head_k(const float* __restrict__ srcC,
        const float* __restrict__ srcR, float* __restrict__ logits, float* __restrict__ regout,
        const float* __restrict__ cow, const float* __restrict__ cob,
        const float* __restrict__ row_, const float* __restrict__ rob)
{
    const int tile = blockIdx.x;
    const int lvl = c_tlvl[tile];
    const int g = c_tg0[tile] + threadIdx.x;
    const int lp = g - c_loff[lvl];
    const bool act = lp < c_hw[lvl];
    const int y = blockIdx.y;
    if (y < 52) {
        int cout0 = y * CPT; if (cout0 > 819 - CPT) cout0 = 819 - CPT;  // overlap tail: identical double-writes
        conv_core<false>(srcC, cow, cob, logits, g, lp, lvl, cout0, act);
    } else {
        int cout0 = (y - 52) * CPT; if (cout0 > 36 - CPT) cout0 = 36 - CPT;
        conv_core<false>(srcR, row_, rob, regout, g, lp, lvl, cout0, act);
    }
}

// ---------------- collect valid candidates (all levels) ----------------
__global__ void collect_k(const float* __restrict__ logits,
                          unsigned long long* __restrict__ keys, int* __restrict__ cnt) {
    int idx = blockIdx.x * 256 + threadIdx.x;
    if (idx >= 819 * PITCH) return;
    float lg = logits[idx];
    float s = 1.0f / (1.0f + expf(-lg));
    if (s > CLS_THRESH) {
        int ch = idx / PITCH, g = idx - ch * PITCH;
        int lvl = (g < 4096) ? 0 : (g < 5120) ? 1 : (g < 5376) ? 2 : (g < 5440) ? 3 : 4;
        int pix = g - c_loff[lvl];
        int a = ch / NUM_CLASSES, cls = ch - a * NUM_CLASSES;
        unsigned flat = (unsigned)((pix * NUM_ANCH + a) * NUM_CLASSES + cls);
        int pos = atomicAdd(cnt + lvl, 1);
        if (pos < KEY_CAP)
            keys[(size_t)lvl * KEY_CAP + pos] =
                ((unsigned long long)__float_as_uint(s) << 32) | (unsigned long long)(~flat);
    }
}

// ---------------- 5 per-level sorts, one launch (LDS bitonic) ----------------
__global__ __launch_bounds__(1024) void sort5_k(unsigned long long* keys, const int* cnt) {
    const int lvl = blockIdx.x;
    unsigned long long* kb = keys + (size_t)lvl * KEY_CAP;
    int n = cnt[lvl]; if (n > KEY_CAP) n = KEY_CAP;
    int m = 2; while (m < n) m <<= 1;
    __shared__ unsigned long long sk[8192];
    if (m <= 8192) {
        for (int i = threadIdx.x; i < m; i += 1024) sk[i] = (i < n) ? kb[i] : 0ull;
        __syncthreads();
        for (int k = 2; k <= m; k <<= 1)
            for (int j = k >> 1; j > 0; j >>= 1) {
                for (int i = threadIdx.x; i < m; i += 1024) {
                    int ixj = i ^ j;
                    if (ixj > i) {
                        unsigned long long a = sk[i], b = sk[ixj];
                        bool desc = (i & k) == 0;
                        if (desc ? (a < b) : (a > b)) { sk[i] = b; sk[ixj] = a; }
                    }
                }
                __syncthreads();
            }
        for (int i = threadIdx.x; i < m; i += 1024) kb[i] = sk[i];
    } else {
        for (int i = threadIdx.x; i < m; i += 1024) if (i >= n) kb[i] = 0ull;
        __syncthreads();
        for (int k = 2; k <= m; k <<= 1)
            for (int j = k >> 1; j > 0; j >>= 1) {
                for (int i = threadIdx.x; i < m; i += 1024) {
                    int ixj = i ^ j;
                    if (ixj > i) {
                        unsigned long long a = kb[i], b = kb[ixj];
                        bool desc = (i & k) == 0;
                        if (desc ? (a < b) : (a > b)) { kb[i] = b; kb[ixj] = a; }
                    }
                }
                __syncthreads();
            }
    }
}

// ---------------- emit top-1000 per level ----------------
__global__ void emit_k(const unsigned long long* __restrict__ keys, const int* __restrict__ cnt,
                       const float* __restrict__ regout, const float* __restrict__ anchors,
                       float* __restrict__ cs, float* __restrict__ cb, int* __restrict__ cl) {
#pragma clang fp contract(off)
    int r = blockIdx.x * 256 + threadIdx.x;
    if (r >= NCAND) return;
    int lvl = r / 1000, rr = r - lvl * 1000;
    int n = cnt[lvl]; if (n > KEY_CAP) n = KEY_CAP; if (n > 1000) n = 1000;
    float score = -1.0f, b0 = 0.f, b1 = 0.f, b2 = 0.f, b3 = 0.f;
    int label = 0;
    if (rr < n) {
        unsigned long long key = keys[(size_t)lvl * KEY_CAP + rr];
        score = __uint_as_float((unsigned)(key >> 32));
        unsigned flat = ~((unsigned)(key & 0xFFFFFFFFull));
        label = (int)(flat % NUM_CLASSES);
        int af = (int)(flat / NUM_CLASSES);
        int a = af % NUM_ANCH;
        int pix = af / NUM_ANCH;
        int gp = c_loff[lvl] + pix;
        float dx = regout[(size_t)(a * 4 + 0) * PITCH + gp];
        float dy = regout[(size_t)(a * 4 + 1) * PITCH + gp];
        float dw = regout[(size_t)(a * 4 + 2) * PITCH + gp];
        float dh = regout[(size_t)(a * 4 + 3) * PITCH + gp];
        const float* an = anchors + (size_t)(c_aoff[lvl] + af) * 4;
        float aw = an[2] - an[0];
        float ah = an[3] - an[1];
        float cx = an[0] + 0.5f * aw;
        float cy = an[1] + 0.5f * ah;
        dw = fminf(dw, BBOX_CLIP_F);
        dh = fminf(dh, BBOX_CLIP_F);
        float pcx = dx * aw + cx;
        float pcy = dy * ah + cy;
        float pw = expf(dw) * aw;
        float ph = expf(dh) * ah;
        b0 = fminf(fmaxf(pcx - 0.5f * pw, 0.0f), 512.0f);
        b1 = fminf(fmaxf(pcy - 0.5f * ph, 0.0f), 512.0f);
        b2 = fminf(fmaxf(pcx + 0.5f * pw, 0.0f), 512.0f);
        b3 = fminf(fmaxf(pcy + 0.5f * ph, 0.0f), 512.0f);
    }
    cs[r] = score;
    cb[(size_t)r * 4 + 0] = b0;
    cb[(size_t)r * 4 + 1] = b1;
    cb[(size_t)r * 4 + 2] = b2;
    cb[(size_t)r * 4 + 3] = b3;
    cl[r] = label;
}

// ---------------- global sort of the 5000 candidates ----------------
__global__ __launch_bounds__(1024) void gsort_k(const float* __restrict__ cs, int* __restrict__ order) {
    __shared__ unsigned long long sk[8192];
    for (int i = threadIdx.x; i < 8192; i += 1024) {
        unsigned long long key = 0ull;
        if (i < NCAND) {
            unsigned u = __float_as_uint(cs[i]);
            u = (u & 0x80000000u) ? ~u : (u | 0x80000000u);
            key = ((unsigned long long)u << 32) | (unsigned long long)(~(unsigned)i);
        }
        sk[i] = key;
    }
    __syncthreads();
    for (int k = 2; k <= 8192; k <<= 1)
        for (int j = k >> 1; j > 0; j >>= 1) {
            for (int i = threadIdx.x; i < 8192; i += 1024) {
                int ixj = i ^ j;
                if (ixj > i) {
                    unsigned long long a = sk[i], b = sk[ixj];
                    bool d = (i & k) == 0;
                    if (d ? (a < b) : (a > b)) { sk[i] = b; sk[ixj] = a; }
                }
            }
            __syncthreads();
        }
    for (int i = threadIdx.x; i < NCAND; i += 1024)
        order[i] = (int)(~(unsigned)(sk[i] & 0xFFFFFFFFull));
}

// ---------------- IoU suppression bitmask: 5000 x 80 words ----------------
__global__ void mask_k(const float* __restrict__ cb, const int* __restrict__ cl,
                       unsigned long long* __restrict__ mask) {
#pragma clang fp contract(off)
    int t = blockIdx.x * 256 + threadIdx.x;
    if (t >= NCAND * 80) return;
    int i = t / 80, w = t - i * 80;
    float offi = (float)cl[i] * 513.0f;   // max(boxes)=512 -> class spacing; cross-class IoU == 0
    float ix1 = cb[(size_t)i * 4 + 0] + offi;
    float iy1 = cb[(size_t)i * 4 + 1] + offi;
    float ix2 = cb[(size_t)i * 4 + 2] + offi;
    float iy2 = cb[(size_t)i * 4 + 3] + offi;
    float ai = (ix2 - ix1) * (iy2 - iy1);
    unsigned long long bits = 0ull;
    int j0 = w * 64;
    for (int b = 0; b < 64; ++b) {
        int j = j0 + b;
        if (j < NCAND) {
            float offj = (float)cl[j] * 513.0f;
            float jx1 = cb[(size_t)j * 4 + 0] + offj;
            float jy1 = cb[(size_t)j * 4 + 1] + offj;
            float jx2 = cb[(size_t)j * 4 + 2] + offj;
            float jy2 = cb[(size_t)j * 4 + 3] + offj;
            float aj = (jx2 - jx1) * (jy2 - jy1);
            float ltx = fmaxf(ix1, jx1), lty = fmaxf(iy1, jy1);
            float rbx = fminf(ix2, jx2), rby = fminf(iy2, jy2);
            float wx = fmaxf(rbx - ltx, 0.0f), wy = fmaxf(rby - lty, 0.0f);
            float inter = wx * wy;
            float iou = inter / (ai + aj - inter + 1e-12f);
            if (iou > 0.5f) bits |= (1ull << b);
        }
    }
    mask[(size_t)i * 80 + w] = bits;
}

// ---------------- single-wave greedy sweep (== 300-step argmax NMS) ----------------
__global__ __launch_bounds__(64) void sweep_k(const float* __restrict__ cs,
        const float* __restrict__ cb, const int* __restrict__ cl,
        const int* __restrict__ order, const unsigned long long* __restrict__ mask,
        float* __restrict__ out) {
    const int lane = threadIdx.x;
    for (int k = lane; k < 1500; k += 64) out[k] = 0.0f;
    for (int k = lane; k < 300; k += 64) out[1500 + k] = -1.0f;
    unsigned long long r0 = 0ull, r1 = 0ull;   // suppression bitmap: lane L owns words L and 64+L (L<16)
    int nacc = 0;
    bool done = false;
    for (int base = 0; base < NCAND && !done; base += 64) {
        int lim = NCAND - base; if (lim > 64) lim = 64;
        int cL = 0; float sL = -1.0f;
        if (lane < lim) { cL = order[base + lane]; sL = cs[cL]; }
        for (int q = 0; q < lim; ++q) {
            int c = __shfl(cL, q, 64);
            float s = __shfl(sL, q, 64);
            if (!(s > CLS_THRESH)) { done = true; break; }
            int w = c >> 6, b = c & 63;
            unsigned long long word = (w < 64) ? __shfl(r0, w, 64) : __shfl(r1, w - 64, 64);
            if (!((word >> b) & 1ull)) {
                if (lane == 0) {
                    out[nacc * 5 + 0] = s;
                    out[nacc * 5 + 1] = cb[(size_t)c * 4 + 0];
                    out[nacc * 5 + 2] = cb[(size_t)c * 4 + 1];
                    out[nacc * 5 + 3] = cb[(size_t)c * 4 + 2];
                    out[nacc * 5 + 4] = cb[(size_t)c * 4 + 3];
                    out[1500 + nacc] = (float)cl[c];
                }
                const unsigned long long* mr = mask + (size_t)c * 80;
                r0 |= mr[lane];
                if (lane < 16) r1 |= mr[64 + lane];
                ++nacc;
                if (nacc == 300) { done = true; break; }
            }
        }
    }
}

// ---------------- host launch ----------------
extern "C" void kernel_launch(void* const* d_in, const int* in_sizes, int n_in,
                              void* d_out, int out_size, void* d_ws, size_t ws_size,
                              hipStream_t stream) {
    const float* f0 = (const float*)d_in[0];
    const float* f1 = (const float*)d_in[1];
    const float* f2 = (const float*)d_in[2];
    const float* f3 = (const float*)d_in[3];
    const float* f4 = (const float*)d_in[4];
    const float* anchors = (const float*)d_in[5];
    const float* ctw = (const float*)d_in[6];
    const float* ctb = (const float*)d_in[7];
    const float* cow = (const float*)d_in[8];
    const float* cob = (const float*)d_in[9];
    const float* rtw = (const float*)d_in[10];
    const float* rtb = (const float*)d_in[11];
    const float* row_ = (const float*)d_in[12];
    const float* rob = (const float*)d_in[13];
    float* out = (float*)d_out;

    float* ws = (float*)d_ws;
    float* P = ws;                       // 256*PITCH  (feat pyramid, then ping-pong)
    float* A = P + 256 * PITCH;
    float* B = A + 256 * PITCH;
    float* C = B + 256 * PITCH;
    float* logits = C + 256 * PITCH;     // 819*PITCH
    float* regout = logits + 819 * PITCH;// 36*PITCH
    float* cs = regout + 36 * PITCH;     // 5000
    float* cb = cs + NCAND;              // 20000
    int* cl = (int*)(cb + 4 * NCAND);    // 5000
    int* cnt = cl + NCAND;               // 8 (5 used)
    int* order = cnt + 8;                // 5000
    unsigned long long* keys = (unsigned long long*)(order + NCAND);   // 5*KEY_CAP u64
    unsigned long long* mask = (unsigned long long*)logits;            // aliases logits (dead after collect)

    const int WSLICE = 256 * 256 * 9;

    hipMemsetAsync(cnt, 0, 5 * sizeof(int), stream);
    pyr_k<<<(256 * PITCH + 255) / 256, 256, 0, stream>>>(f0, f1, f2, f3, f4, P);

    // towers: L0 P->A(cls),P->B(reg); L1 A->C,B->P; L2 C->A,P->B; L3 A->C,B->P
    tower_k<<<dim3(NTILES, 16, 2), 256, 0, stream>>>(P, P, A, B, ctw, ctb, rtw, rtb);
    tower_k<<<dim3(NTILES, 16, 2), 256, 0, stream>>>(A, B, C, P,
        ctw + WSLICE, ctb + 256, rtw + WSLICE, rtb + 256);
    tower_k<<<dim3(NTILES, 16, 2), 256, 0, stream>>>(C, P, A, B,
        ctw + 2 * WSLICE, ctb + 512, rtw + 2 * WSLICE, rtb + 512);
    tower_k<<<dim3(NTILES, 16, 2), 256, 0, stream>>>(A, B, C, P,
        ctw + 3 * WSLICE, ctb + 768, rtw + 3 * WSLICE, rtb + 768);

    head_k<<<dim3(NTILES, 55), 256, 0, stream>>>(C, P, logits, regout, cow, cob, row_, rob);

    collect_k<<<(819 * PITCH + 255) / 256, 256, 0, stream>>>(logits, keys, cnt);
    sort5_k<<<5, 1024, 0, stream>>>(keys, cnt);
    emit_k<<<(NCAND + 255) / 256, 256, 0, stream>>>(keys, cnt, regout, anchors, cs, cb, cl);

    gsort_k<<<1, 1024, 0, stream>>>(cs, order);
    mask_k<<<(NCAND * 80 + 255) / 256, 256, 0, stream>>>(cb, cl, mask);
    sweep_k<<<1, 64, 0, stream>>>(cs, cb, cl, order, mask, out);
}

// Round 4
// 946.632 us; speedup vs baseline: 10.7200x; 3.2988x over previous
//
#include <hip/hip_runtime.h>
#include <hip/hip_bf16.h>
#include <math.h>

#define CIN 256
#define NUM_CLASSES 91
#define NUM_ANCH 9
#define KEY_CAP 65536
#define NCAND 5000
#define BBOX_CLIP_F 4.135166556742356f
#define CLS_THRESH 0.05f
#define PITCH 5456
#define PP_TOT 5972
#define PLANE_E 1528832      // ushorts per plane (8*5972*32)
#define PLANE_B 3057664      // bytes per plane
#define ABUF_B  6115328      // bytes per act buffer (hi+lo plane)
#define SLB     147456       // bytes per 16-cout weight-frag slice
#define NT 44

typedef __attribute__((ext_vector_type(4))) float f4;
typedef _Float16 h8 __attribute__((ext_vector_type(8)));

#define MFMA(a,b,c) __builtin_amdgcn_mfma_f32_16x16x32_f16(a,b,c,0,0,0)

__constant__ int t_lvl[NT] = {0,0,0,0,0,0,0,0,0,0,0,0,0,0,0,0,0,0,0,0,0,0,0,0,0,0,0,0,0,0,0,0,
                              1,1,1,1,1,1,1,1, 2,2, 3, 4};
__constant__ int t_px0[NT] = {0,128,256,384,512,640,768,896,1024,1152,1280,1408,1536,1664,1792,1920,
                              2048,2176,2304,2432,2560,2688,2816,2944,3072,3200,3328,3456,3584,3712,3840,3968,
                              0,128,256,384,512,640,768,896, 0,128, 0, 0};
__constant__ int t_y0[NT]  = {0,2,4,6,8,10,12,14,16,18,20,22,24,26,28,30,
                              32,34,36,38,40,42,44,46,48,50,52,54,56,58,60,62,
                              0,4,8,12,16,20,24,28, 0,8, 0, 0};
__constant__ int c_wsh[5]  = {6,5,4,3,2};
__constant__ int c_hw[5]   = {4096,1024,256,64,16};
__constant__ int c_wp[5]   = {66,34,18,10,6};
__constant__ int c_poff[5] = {0,4356,5512,5836,5936};
__constant__ int c_slen[5] = {264,204,180,100,36};
__constant__ int c_loff[5] = {0,4096,5120,5376,5440};
__constant__ int c_aoff[5] = {0,36864,46080,48384,48960};
// wf slice ranges: clsL2,clsL3,clsL4,regL1,regL2,regL3,regL4,clsHead(52),regHead(4),clsL1
__constant__ int s_cum[11] = {0,16,32,48,64,80,96,112,164,168,184};

__device__ __forceinline__ unsigned short f16r(float f) {
    _Float16 h = (_Float16)f;
    return __builtin_bit_cast(unsigned short, h);
}
__device__ __forceinline__ float f16tof(unsigned short u) {
    return (float)__builtin_bit_cast(_Float16, u);
}
// split v = h + l/4096, h zero-guarded against f16 denormal flush, l pre-scaled x4096
__device__ __forceinline__ void split16(float v, unsigned short& h, unsigned short& l) {
    unsigned short hh = (fabsf(v) < 6.103515625e-05f) ? (unsigned short)0 : f16r(v);
    h = hh;
    l = f16r((v - f16tof(hh)) * 4096.0f);
}
__device__ __forceinline__ void gl_lds(const void* g, void* l) {
    __builtin_amdgcn_global_load_lds((const __attribute__((address_space(1))) void*)g,
                                     (__attribute__((address_space(3))) void*)l, 16, 0, 0);
}

// ---------------- pad + split + chunk the input pyramid ----------------
__global__ void pad_k(const float* __restrict__ f0, const float* __restrict__ f1,
                      const float* __restrict__ f2, const float* __restrict__ f3,
                      const float* __restrict__ f4, unsigned short* __restrict__ IN) {
    int gid = blockIdx.x * 256 + threadIdx.x;
    if (gid >= 256 * PITCH) return;
    int cin = gid / PITCH, g = gid - cin * PITCH;
    int lvl = (g < 4096) ? 0 : (g < 5120) ? 1 : (g < 5376) ? 2 : (g < 5440) ? 3 : 4;
    const float* f = (lvl == 0) ? f0 : (lvl == 1) ? f1 : (lvl == 2) ? f2 : (lvl == 3) ? f3 : f4;
    int pix = g - c_loff[lvl];
    int wsh = c_wsh[lvl];
    int y = pix >> wsh, x = pix & ((1 << wsh) - 1);
    float v = f[(size_t)cin * c_hw[lvl] + pix];
    unsigned short h, l;
    split16(v, h, l);
    size_t idx = ((size_t)(cin >> 5) * PP_TOT + c_poff[lvl] + (size_t)(y + 1) * c_wp[lvl] + x + 1) * 32 + (cin & 31);
    IN[idx] = h;
    IN[PLANE_E + idx] = l;
}

// ---------------- weight fragment prep (f16 hi + scaled-lo, MFMA B-frag order) ----------------
__global__ void wprep_k(const float* __restrict__ ctw, const float* __restrict__ rtw,
                        const float* __restrict__ cow, const float* __restrict__ row_,
                        unsigned short* __restrict__ wf) {
    int gid = blockIdx.x * 256 + threadIdx.x;
    if (gid >= 184 * 72 * 64) return;
    int lane = gid & 63;
    int t = gid >> 6;
    int tap = t % 9;
    int t2 = t / 9;
    int chunk = t2 & 7;
    int cbg = t2 >> 3;
    int r = 0;
#pragma unroll
    for (int i = 1; i <= 10; ++i) if (cbg >= s_cum[i]) r = i;
    int cbl = cbg - s_cum[r];
    const float* src;
    int coutCnt;
    if (r < 3)       { src = ctw + (size_t)(r + 1) * 589824; coutCnt = 256; }
    else if (r < 7)  { src = rtw + (size_t)(r - 3) * 589824; coutCnt = 256; }
    else if (r == 7) { src = cow; coutCnt = 819; }
    else if (r == 8) { src = row_; coutCnt = 36; }
    else             { src = ctw; coutCnt = 256; }
    int cout = cbl * 16 + (lane & 15);
    int q = lane >> 4;
    unsigned short H[8], L[8];
#pragma unroll
    for (int j = 0; j < 8; ++j) {
        int cin = chunk * 32 + q * 8 + j;
        float v = (cout < coutCnt) ? src[((size_t)cout * 256 + cin) * 9 + tap] : 0.0f;
        split16(v, H[j], L[j]);
    }
    size_t off = (size_t)cbg * 73728 + (size_t)(chunk * 9 + tap) * 1024 + (size_t)lane * 8;
#pragma unroll
    for (int j = 0; j < 8; ++j) { wf[off + j] = H[j]; wf[off + 512 + j] = L[j]; }
}

// ---------------- shared MFMA K-loop (LDS double-buffered, 1 barrier/chunk) ----------------
__device__ __forceinline__ void kloop(const unsigned short* __restrict__ src,
        const char* __restrict__ wf0, char* sm, int wid, int lane,
        int s_base, int s_len, int Wp, const int sloc[4], f4 acc1[4][2], f4 acc2[4][2]) {
    const char* wp = wf0 + lane * 16;
    int nc = (s_len * 64 + 1023) >> 10;
    const char* gbase = (const char*)src;
    {   // prefetch chunk 0 into phase 0
        const char* g = gbase + (size_t)s_base * 64;
        for (int c = wid; c < nc; c += 4) {
            gl_lds(g + (size_t)c * 1024 + (size_t)lane * 16, sm + c * 1024);
            gl_lds(g + PLANE_B + (size_t)c * 1024 + (size_t)lane * 16, sm + 17408 + c * 1024);
        }
    }
    __syncthreads();
    for (int chunk = 0; chunk < 8; ++chunk) {
        int ph = chunk & 1;
        char* smc = sm + ph * 34816;
        if (chunk < 7) {   // issue next-chunk staging BEFORE compute; barrier drain is then ~free
            char* smn = sm + (1 - ph) * 34816;
            const char* g = gbase + ((size_t)(chunk + 1) * PP_TOT + s_base) * 64;
            for (int c = wid; c < nc; c += 4) {
                gl_lds(g + (size_t)c * 1024 + (size_t)lane * 16, smn + c * 1024);
                gl_lds(g + PLANE_B + (size_t)c * 1024 + (size_t)lane * 16, smn + 17408 + c * 1024);
            }
        }
#pragma unroll
        for (int tap = 0; tap < 9; ++tap) {
            int toff = ((tap / 3) - 1) * Wp + (tap % 3) - 1;
            int so = toff * 64;
            int wo = (chunk * 9 + tap) * 2048;
            h8 bh0 = *(const h8*)(wp + wo);
            h8 bl0 = *(const h8*)(wp + wo + 1024);
            h8 bh1 = *(const h8*)(wp + SLB + wo);
            h8 bl1 = *(const h8*)(wp + SLB + wo + 1024);
#pragma unroll
            for (int mb = 0; mb < 4; ++mb) {
                h8 ah = *(const h8*)(smc + sloc[mb] + so);
                h8 al = *(const h8*)(smc + 17408 + sloc[mb] + so);
                acc1[mb][0] = MFMA(ah, bh0, acc1[mb][0]);
                acc2[mb][0] = MFMA(al, bh0, acc2[mb][0]);
                acc2[mb][0] = MFMA(ah, bl0, acc2[mb][0]);
                acc1[mb][1] = MFMA(ah, bh1, acc1[mb][1]);
                acc2[mb][1] = MFMA(al, bh1, acc2[mb][1]);
                acc2[mb][1] = MFMA(ah, bl1, acc2[mb][1]);
            }
        }
        __syncthreads();
    }
}

// ---------------- tower conv layer: 128 px x 64 couts per block ----------------
__global__ __launch_bounds__(256, 2) void conv_t(const unsigned short* __restrict__ src,
        unsigned short* __restrict__ dst, const unsigned short* __restrict__ wfL,
        const float* __restrict__ bias) {
    __shared__ __align__(16) char sm[69632];
    int tid = threadIdx.x, lane = tid & 63, wid = tid >> 6;
    int quad = lane >> 4, l16 = lane & 15;
    int bx = blockIdx.x, tile = bx >> 2, cb64 = bx & 3;
    int lvl = t_lvl[tile], px0 = t_px0[tile], y0 = t_y0[tile];
    int wsh = c_wsh[lvl], HW = c_hw[lvl], Wp = c_wp[lvl];
    int poff = c_poff[lvl];
    int s_base = poff + y0 * Wp, s_len = c_slen[lvl];
    int Mh = (wid & 1) * 64, Nh = (wid >> 1) * 32;

    int sloc[4];
#pragma unroll
    for (int mb = 0; mb < 4; ++mb) {
        int p = px0 + Mh + mb * 16 + l16;
        if (p >= HW) p = HW - 1;
        int y = p >> wsh, x = p & ((1 << wsh) - 1);
        sloc[mb] = ((y - y0 + 1) * Wp + x + 1) * 64 + quad * 16;
    }
    f4 acc1[4][2], acc2[4][2];
#pragma unroll
    for (int mb = 0; mb < 4; ++mb) {
        acc1[mb][0] = (f4)0.0f; acc1[mb][1] = (f4)0.0f;
        acc2[mb][0] = (f4)0.0f; acc2[mb][1] = (f4)0.0f;
    }
    const char* wf0 = (const char*)wfL + (size_t)(cb64 * 4 + (Nh >> 4)) * SLB;
    kloop(src, wf0, sm, wid, lane, s_base, s_len, Wp, sloc, acc1, acc2);

    int cbase = cb64 * 64;
    float b0 = bias[cbase + Nh + l16];
    float b1 = bias[cbase + Nh + 16 + l16];
#pragma unroll
    for (int mb = 0; mb < 4; ++mb) {
        int pb = px0 + Mh + mb * 16 + quad * 4;
#pragma unroll
        for (int r = 0; r < 4; ++r) {
            int p = pb + r;
            bool valid = p < HW;
            int pc = valid ? p : 0;
            int y = pc >> wsh, x = pc & ((1 << wsh) - 1);
            size_t ppix = poff + (size_t)(y + 1) * Wp + x + 1;
#pragma unroll
            for (int nb = 0; nb < 2; ++nb) {
                int coutg = cbase + Nh + nb * 16 + l16;
                float v = fmaf(acc2[mb][nb][r], 0.000244140625f, acc1[mb][nb][r]) + (nb ? b1 : b0);
                v = fmaxf(v, 0.0f);
                unsigned short h, l;
                split16(v, h, l);
                size_t idx = ((size_t)(coutg >> 5) * PP_TOT + ppix) * 32 + (coutg & 31);
                if (valid) { dst[idx] = h; dst[PLANE_E + idx] = l; }
            }
        }
    }
}

// ---------------- fused heads: cls (sigmoid+collect fused) + reg ----------------
__global__ __launch_bounds__(256, 2) void mhead_t(
        const unsigned short* __restrict__ srcC, const unsigned short* __restrict__ srcR,
        const unsigned short* __restrict__ wfCls, const unsigned short* __restrict__ wfReg,
        const float* __restrict__ cob, const float* __restrict__ rob,
        unsigned long long* __restrict__ keys, int* __restrict__ cnt,
        float* __restrict__ regout) {
    __shared__ __align__(16) char sm[69632];
    int tid = threadIdx.x, lane = tid & 63, wid = tid >> 6;
    int quad = lane >> 4, l16 = lane & 15;
    int bx = blockIdx.x, tile = bx / 14, sub = bx - tile * 14;
    bool isCls = sub < 13;

    int lvl = t_lvl[tile], px0 = t_px0[tile], y0 = t_y0[tile];
    int wsh = c_wsh[lvl], HW = c_hw[lvl], Wp = c_wp[lvl];
    int poff = c_poff[lvl];
    int s_base = poff + y0 * Wp, s_len = c_slen[lvl];
    int Mh = (wid & 1) * 64, Nh = (wid >> 1) * 32;

    int sloc[4];
#pragma unroll
    for (int mb = 0; mb < 4; ++mb) {
        int p = px0 + Mh + mb * 16 + l16;
        if (p >= HW) p = HW - 1;
        int y = p >> wsh, x = p & ((1 << wsh) - 1);
        sloc[mb] = ((y - y0 + 1) * Wp + x + 1) * 64 + quad * 16;
    }
    f4 acc1[4][2], acc2[4][2];
#pragma unroll
    for (int mb = 0; mb < 4; ++mb) {
        acc1[mb][0] = (f4)0.0f; acc1[mb][1] = (f4)0.0f;
        acc2[mb][0] = (f4)0.0f; acc2[mb][1] = (f4)0.0f;
    }
    const unsigned short* src = isCls ? srcC : srcR;
    const char* wf0 = isCls ? (const char*)wfCls + (size_t)(sub * 4 + (Nh >> 4)) * SLB
                            : (const char*)wfReg + (size_t)(Nh >> 4) * SLB;
    kloop(src, wf0, sm, wid, lane, s_base, s_len, Wp, sloc, acc1, acc2);

    if (isCls) {
        int ch0 = sub * 64 + Nh + l16;
        float cb0 = (ch0 < 819) ? cob[ch0] : 0.0f;
        float cb1 = (ch0 + 16 < 819) ? cob[ch0 + 16] : 0.0f;
#pragma unroll
        for (int mb = 0; mb < 4; ++mb) {
            int pb = px0 + Mh + mb * 16 + quad * 4;
#pragma unroll
            for (int r = 0; r < 4; ++r) {
                int p = pb + r;
                bool valid = p < HW;
#pragma unroll
                for (int nb = 0; nb < 2; ++nb) {
                    int ch = ch0 + nb * 16;
                    if (valid && ch < 819) {
                        float lg = fmaf(acc2[mb][nb][r], 0.000244140625f, acc1[mb][nb][r]) + (nb ? cb1 : cb0);
                        float s = 1.0f / (1.0f + expf(-lg));
                        if (s > CLS_THRESH) {
                            int a = ch / NUM_CLASSES;
                            int cls = ch - a * NUM_CLASSES;
                            unsigned flat = (unsigned)((p * NUM_ANCH + a) * NUM_CLASSES + cls);
                            int pos = atomicAdd(cnt + lvl, 1);
                            if (pos < KEY_CAP)
                                keys[(size_t)lvl * KEY_CAP + pos] =
                                    ((unsigned long long)__float_as_uint(s) << 32) |
                                    (unsigned long long)(~flat);
                        }
                    }
                }
            }
        }
    } else {
        int ch0 = Nh + l16;
        float rb0 = (ch0 < 36) ? rob[ch0] : 0.0f;
        float rb1 = (ch0 + 16 < 36) ? rob[ch0 + 16] : 0.0f;
        int loff = c_loff[lvl];
#pragma unroll
        for (int mb = 0; mb < 4; ++mb) {
            int pb = px0 + Mh + mb * 16 + quad * 4;
#pragma unroll
            for (int r = 0; r < 4; ++r) {
                int p = pb + r;
                bool valid = p < HW;
#pragma unroll
                for (int nb = 0; nb < 2; ++nb) {
                    int ch = ch0 + nb * 16;
                    if (valid && ch < 36)
                        regout[(size_t)ch * PITCH + loff + p] =
                            fmaf(acc2[mb][nb][r], 0.000244140625f, acc1[mb][nb][r]) + (nb ? rb1 : rb0);
                }
            }
        }
    }
}

// ---------------- 5 per-level sorts ----------------
__global__ __launch_bounds__(1024) void sort5_k(unsigned long long* keys, const int* cnt) {
    const int lvl = blockIdx.x;
    unsigned long long* kb = keys + (size_t)lvl * KEY_CAP;
    int n = cnt[lvl]; if (n > KEY_CAP) n = KEY_CAP;
    int m = 2; while (m < n) m <<= 1;
    __shared__ unsigned long long sk[8192];
    if (m <= 8192) {
        for (int i = threadIdx.x; i < m; i += 1024) sk[i] = (i < n) ? kb[i] : 0ull;
        __syncthreads();
        for (int k = 2; k <= m; k <<= 1)
            for (int j = k >> 1; j > 0; j >>= 1) {
                for (int i = threadIdx.x; i < m; i += 1024) {
                    int ixj = i ^ j;
                    if (ixj > i) {
                        unsigned long long a = sk[i], b = sk[ixj];
                        bool desc = (i & k) == 0;
                        if (desc ? (a < b) : (a > b)) { sk[i] = b; sk[ixj] = a; }
                    }
                }
                __syncthreads();
            }
        for (int i = threadIdx.x; i < m; i += 1024) kb[i] = sk[i];
    } else {
        for (int i = threadIdx.x; i < m; i += 1024) if (i >= n) kb[i] = 0ull;
        __syncthreads();
        for (int k = 2; k <= m; k <<= 1)
            for (int j = k >> 1; j > 0; j >>= 1) {
                for (int i = threadIdx.x; i < m; i += 1024) {
                    int ixj = i ^ j;
                    if (ixj > i) {
                        unsigned long long a = kb[i], b = kb[ixj];
                        bool desc = (i & k) == 0;
                        if (desc ? (a < b) : (a > b)) { kb[i] = b; kb[ixj] = a; }
                    }
                }
                __syncthreads();
            }
    }
}

// ---------------- emit top-1000 per level ----------------
__global__ void emit_k(const unsigned long long* __restrict__ keys, const int* __restrict__ cnt,
                       const float* __restrict__ regout, const float* __restrict__ anchors,
                       float* __restrict__ cs, float* __restrict__ cb, int* __restrict__ cl) {
#pragma clang fp contract(off)
    int r = blockIdx.x * 256 + threadIdx.x;
    if (r >= NCAND) return;
    int lvl = r / 1000, rr = r - lvl * 1000;
    int n = cnt[lvl]; if (n > KEY_CAP) n = KEY_CAP; if (n > 1000) n = 1000;
    float score = -1.0f, b0 = 0.f, b1 = 0.f, b2 = 0.f, b3 = 0.f;
    int label = 0;
    if (rr < n) {
        unsigned long long key = keys[(size_t)lvl * KEY_CAP + rr];
        score = __uint_as_float((unsigned)(key >> 32));
        unsigned flat = ~((unsigned)(key & 0xFFFFFFFFull));
        label = (int)(flat % NUM_CLASSES);
        int af = (int)(flat / NUM_CLASSES);
        int a = af % NUM_ANCH;
        int pix = af / NUM_ANCH;
        int gp = c_loff[lvl] + pix;
        float dx = regout[(size_t)(a * 4 + 0) * PITCH + gp];
        float dy = regout[(size_t)(a * 4 + 1) * PITCH + gp];
        float dw = regout[(size_t)(a * 4 + 2) * PITCH + gp];
        float dh = regout[(size_t)(a * 4 + 3) * PITCH + gp];
        const float* an = anchors + (size_t)(c_aoff[lvl] + af) * 4;
        float aw = an[2] - an[0];
        float ah = an[3] - an[1];
        float cx = an[0] + 0.5f * aw;
        float cy = an[1] + 0.5f * ah;
        dw = fminf(dw, BBOX_CLIP_F);
        dh = fminf(dh, BBOX_CLIP_F);
        float pcx = dx * aw + cx;
        float pcy = dy * ah + cy;
        float pw = expf(dw) * aw;
        float ph = expf(dh) * ah;
        b0 = fminf(fmaxf(pcx - 0.5f * pw, 0.0f), 512.0f);
        b1 = fminf(fmaxf(pcy - 0.5f * ph, 0.0f), 512.0f);
        b2 = fminf(fmaxf(pcx + 0.5f * pw, 0.0f), 512.0f);
        b3 = fminf(fmaxf(pcy + 0.5f * ph, 0.0f), 512.0f);
    }
    cs[r] = score;
    cb[(size_t)r * 4 + 0] = b0;
    cb[(size_t)r * 4 + 1] = b1;
    cb[(size_t)r * 4 + 2] = b2;
    cb[(size_t)r * 4 + 3] = b3;
    cl[r] = label;
}

// ---------------- global sort of 5000 candidates ----------------
__global__ __launch_bounds__(1024) void gsort_k(const float* __restrict__ cs, int* __restrict__ order) {
    __shared__ unsigned long long sk[8192];
    for (int i = threadIdx.x; i < 8192; i += 1024) {
        unsigned long long key = 0ull;
        if (i < NCAND) {
            unsigned u = __float_as_uint(cs[i]);
            u = (u & 0x80000000u) ? ~u : (u | 0x80000000u);
            key = ((unsigned long long)u << 32) | (unsigned long long)(~(unsigned)i);
        }
        sk[i] = key;
    }
    __syncthreads();
    for (int k = 2; k <= 8192; k <<= 1)
        for (int j = k >> 1; j > 0; j >>= 1) {
            for (int i = threadIdx.x; i < 8192; i += 1024) {
                int ixj = i ^ j;
                if (ixj > i) {
                    unsigned long long a = sk[i], b = sk[ixj];
                    bool d = (i & k) == 0;
                    if (d ? (a < b) : (a > b)) { sk[i] = b; sk[ixj] = a; }
                }
            }
            __syncthreads();
        }
    for (int i = threadIdx.x; i < NCAND; i += 1024)
        order[i] = (int)(~(unsigned)(sk[i] & 0xFFFFFFFFull));
}

// ---------------- IoU suppression bitmask ----------------
__global__ void mask_k(const float* __restrict__ cb, const int* __restrict__ cl,
                       unsigned long long* __restrict__ mask) {
#pragma clang fp contract(off)
    int t = blockIdx.x * 256 + threadIdx.x;
    if (t >= NCAND * 80) return;
    int i = t / 80, w = t - i * 80;
    float offi = (float)cl[i] * 513.0f;
    float ix1 = cb[(size_t)i * 4 + 0] + offi;
    float iy1 = cb[(size_t)i * 4 + 1] + offi;
    float ix2 = cb[(size_t)i * 4 + 2] + offi;
    float iy2 = cb[(size_t)i * 4 + 3] + offi;
    float ai = (ix2 - ix1) * (iy2 - iy1);
    unsigned long long bits = 0ull;
    int j0 = w * 64;
    for (int b = 0; b < 64; ++b) {
        int j = j0 + b;
        if (j < NCAND) {
            float offj = (float)cl[j] * 513.0f;
            float jx1 = cb[(size_t)j * 4 + 0] + offj;
            float jy1 = cb[(size_t)j * 4 + 1] + offj;
            float jx2 = cb[(size_t)j * 4 + 2] + offj;
            float jy2 = cb[(size_t)j * 4 + 3] + offj;
            float aj = (jx2 - jx1) * (jy2 - jy1);
            float ltx = fmaxf(ix1, jx1), lty = fmaxf(iy1, jy1);
            float rbx = fminf(ix2, jx2), rby = fminf(iy2, jy2);
            float wx = fmaxf(rbx - ltx, 0.0f), wy = fmaxf(rby - lty, 0.0f);
            float inter = wx * wy;
            float iou = inter / (ai + aj - inter + 1e-12f);
            if (iou > 0.5f) bits |= (1ull << b);
        }
    }
    mask[(size_t)i * 80 + w] = bits;
}

// ---------------- single-wave greedy sweep ----------------
__global__ __launch_bounds__(64) void sweep_k(const float* __restrict__ cs,
        const float* __restrict__ cb, const int* __restrict__ cl,
        const int* __restrict__ order, const unsigned long long* __restrict__ mask,
        float* __restrict__ out) {
    const int lane = threadIdx.x;
    for (int k = lane; k < 1500; k += 64) out[k] = 0.0f;
    for (int k = lane; k < 300; k += 64) out[1500 + k] = -1.0f;
    unsigned long long r0 = 0ull, r1 = 0ull;
    int nacc = 0;
    bool done = false;
    for (int base = 0; base < NCAND && !done; base += 64) {
        int lim = NCAND - base; if (lim > 64) lim = 64;
        int cL = 0; float sL = -1.0f;
        if (lane < lim) { cL = order[base + lane]; sL = cs[cL]; }
        for (int q = 0; q < lim; ++q) {
            int c = __shfl(cL, q, 64);
            float s = __shfl(sL, q, 64);
            if (!(s > CLS_THRESH)) { done = true; break; }
            int w = c >> 6, b = c & 63;
            unsigned long long word = (w < 64) ? __shfl(r0, w, 64) : __shfl(r1, w - 64, 64);
            if (!((word >> b) & 1ull)) {
                if (lane == 0) {
                    out[nacc * 5 + 0] = s;
                    out[nacc * 5 + 1] = cb[(size_t)c * 4 + 0];
                    out[nacc * 5 + 2] = cb[(size_t)c * 4 + 1];
                    out[nacc * 5 + 3] = cb[(size_t)c * 4 + 2];
                    out[nacc * 5 + 4] = cb[(size_t)c * 4 + 3];
                    out[1500 + nacc] = (float)cl[c];
                }
                const unsigned long long* mr = mask + (size_t)c * 80;
                r0 |= mr[lane];
                if (lane < 16) r1 |= mr[64 + lane];
                ++nacc;
                if (nacc == 300) { done = true; break; }
            }
        }
    }
}

// ---------------- host launch ----------------
extern "C" void kernel_launch(void* const* d_in, const int* in_sizes, int n_in,
                              void* d_out, int out_size, void* d_ws, size_t ws_size,
                              hipStream_t stream) {
    const float* f0 = (const float*)d_in[0];
    const float* f1 = (const float*)d_in[1];
    const float* f2 = (const float*)d_in[2];
    const float* f3 = (const float*)d_in[3];
    const float* f4 = (const float*)d_in[4];
    const float* anchors = (const float*)d_in[5];
    const float* ctw = (const float*)d_in[6];
    const float* ctb = (const float*)d_in[7];
    const float* cow = (const float*)d_in[8];
    const float* cob = (const float*)d_in[9];
    const float* rtw = (const float*)d_in[10];
    const float* rtb = (const float*)d_in[11];
    const float* row_ = (const float*)d_in[12];
    const float* rob = (const float*)d_in[13];
    float* out = (float*)d_out;

    // layout (43.12 MB total, < 43.77 MB proven available):
    //   wf slices 0..183 at 0..27131904; B overlaps slices 168..183 (cls L1 wts, dead before B written)
    char* base = (char*)d_ws;
    unsigned short* wf = (unsigned short*)base;
    unsigned short* B  = (unsigned short*)(base + 24772608);
    unsigned short* IN = (unsigned short*)(base + 30887936);
    unsigned short* A  = (unsigned short*)(base + 37003264);
    int* cnt           = (int*)(base + 43118592);
    // tail buffers alias dead regions:
    float* cs    = (float*)(base + 0);          // wf head slices (dead after heads)
    float* cbx   = (float*)(base + 32768);
    int*   cl    = (int*)(base + 131072);
    int*   order = (int*)(base + 163840);
    unsigned long long* mask = (unsigned long long*)(base + 196608);
    unsigned long long* keys = (unsigned long long*)(base + 37003264);          // aliases A (dead)
    float* regout            = (float*)(base + 37003264 + 2621440);             // aliases A

    unsigned short* SL_clsL[4] = {wf + (size_t)168 * 73728, wf + (size_t)0 * 73728,
                                  wf + (size_t)16 * 73728,  wf + (size_t)32 * 73728};
    unsigned short* SL_regL[4] = {wf + (size_t)48 * 73728, wf + (size_t)64 * 73728,
                                  wf + (size_t)80 * 73728, wf + (size_t)96 * 73728};
    unsigned short* SL_clsH = wf + (size_t)112 * 73728;
    unsigned short* SL_regH = wf + (size_t)164 * 73728;

    hipMemsetAsync(IN, 0, 2 * (size_t)ABUF_B, stream);   // zero IN + A (padding borders)
    hipMemsetAsync(cnt, 0, 32, stream);

    pad_k<<<(256 * PITCH + 255) / 256, 256, 0, stream>>>(f0, f1, f2, f3, f4, IN);
    wprep_k<<<(184 * 72 * 64 + 255) / 256, 256, 0, stream>>>(ctw, rtw, cow, row_, wf);

    // cls tower: IN->A->B->A->B  (B memset after clsL1 frees its overlapped weight slices)
    conv_t<<<176, 256, 0, stream>>>(IN, A, SL_clsL[0], ctb);
    hipMemsetAsync(B, 0, (size_t)ABUF_B, stream);
    conv_t<<<176, 256, 0, stream>>>(A, B, SL_clsL[1], ctb + 256);
    conv_t<<<176, 256, 0, stream>>>(B, A, SL_clsL[2], ctb + 512);
    conv_t<<<176, 256, 0, stream>>>(A, B, SL_clsL[3], ctb + 768);
    // reg tower: IN->A->IN->A->IN  (cls feat stays in B)
    conv_t<<<176, 256, 0, stream>>>(IN, A, SL_regL[0], rtb);
    conv_t<<<176, 256, 0, stream>>>(A, IN, SL_regL[1], rtb + 256);
    conv_t<<<176, 256, 0, stream>>>(IN, A, SL_regL[2], rtb + 512);
    conv_t<<<176, 256, 0, stream>>>(A, IN, SL_regL[3], rtb + 768);

    mhead_t<<<44 * 14, 256, 0, stream>>>(B, IN, SL_clsH, SL_regH, cob, rob, keys, cnt, regout);

    sort5_k<<<5, 1024, 0, stream>>>(keys, cnt);
    emit_k<<<(NCAND + 255) / 256, 256, 0, stream>>>(keys, cnt, regout, anchors, cs, cbx, cl);
    gsort_k<<<1, 1024, 0, stream>>>(cs, order);
    mask_k<<<(NCAND * 80 + 255) / 256, 256, 0, stream>>>(cbx, cl, mask);
    sweep_k<<<1, 64, 0, stream>>>(cs, cbx, cl, order, mask, out);
}

// Round 5
// 781.129 us; speedup vs baseline: 12.9913x; 1.2119x over previous
//
#include <hip/hip_runtime.h>
#include <hip/hip_bf16.h>
#include <math.h>

#define CIN 256
#define NUM_CLASSES 91
#define NUM_ANCH 9
#define KEY_CAP 65536
#define NCAND 5000
#define BBOX_CLIP_F 4.135166556742356f
#define CLS_THRESH 0.05f
#define PITCH 5456
#define PP_TOT 5972
#define PLANE_E 1528832      // ushorts per plane (8*5972*32)
#define PLANE_B 3057664      // bytes per plane
#define ABUF_B  6115328      // bytes per act buffer (hi+lo plane)
#define SLB     147456       // bytes per 16-cout weight-frag slice
#define LO_OFF  13312        // LDS offset of lo plane within a phase
#define PHASE   26624        // LDS bytes per phase (hi+lo)

typedef __attribute__((ext_vector_type(4))) float f4;
typedef _Float16 h8 __attribute__((ext_vector_type(8)));

#define MFMA(a,b,c) __builtin_amdgcn_mfma_f32_16x16x32_f16(a,b,c,0,0,0)

__constant__ int c_wsh[5]  = {6,5,4,3,2};
__constant__ int c_hw[5]   = {4096,1024,256,64,16};
__constant__ int c_wp[5]   = {66,34,18,10,6};
__constant__ int c_poff[5] = {0,4356,5512,5836,5936};
__constant__ int c_slen[5] = {198,136,108,100,36};   // strip len for 64-px tiles
__constant__ int c_loff[5] = {0,4096,5120,5376,5440};
__constant__ int c_aoff[5] = {0,36864,46080,48384,48960};
// wf slice ranges: clsL2,clsL3,clsL4,regL1,regL2,regL3,regL4,clsHead(52),regHead(4),clsL1(16)
__constant__ int s_cum[11] = {0,16,32,48,64,80,96,112,164,168,184};

__device__ __forceinline__ unsigned short f16r(float f) {
    _Float16 h = (_Float16)f;
    return __builtin_bit_cast(unsigned short, h);
}
__device__ __forceinline__ float f16tof(unsigned short u) {
    return (float)__builtin_bit_cast(_Float16, u);
}
// split v = h + l/4096, h zero-guarded against f16 denormal flush, l pre-scaled x4096
__device__ __forceinline__ void split16(float v, unsigned short& h, unsigned short& l) {
    unsigned short hh = (fabsf(v) < 6.103515625e-05f) ? (unsigned short)0 : f16r(v);
    h = hh;
    l = f16r((v - f16tof(hh)) * 4096.0f);
}
__device__ __forceinline__ void gl_lds(const void* g, void* l) {
    __builtin_amdgcn_global_load_lds((const __attribute__((address_space(1))) void*)g,
                                     (__attribute__((address_space(3))) void*)l, 16, 0, 0);
}
__device__ __forceinline__ void tile_geom(int tile, int& lvl, int& px0, int& y0) {
    if (tile < 64)      { lvl = 0; px0 = tile << 6; y0 = tile; }
    else if (tile < 80) { lvl = 1; int j = tile - 64; px0 = j << 6; y0 = j << 1; }
    else if (tile < 84) { lvl = 2; int j = tile - 80; px0 = j << 6; y0 = j << 2; }
    else if (tile == 84){ lvl = 3; px0 = 0; y0 = 0; }
    else                { lvl = 4; px0 = 0; y0 = 0; }
}

// ---------------- pad + split + chunk the input pyramid ----------------
__global__ void pad_k(const float* __restrict__ f0, const float* __restrict__ f1,
                      const float* __restrict__ f2, const float* __restrict__ f3,
                      const float* __restrict__ f4, unsigned short* __restrict__ IN) {
    int gid = blockIdx.x * 256 + threadIdx.x;
    if (gid >= 256 * PITCH) return;
    int cin = gid / PITCH, g = gid - cin * PITCH;
    int lvl = (g < 4096) ? 0 : (g < 5120) ? 1 : (g < 5376) ? 2 : (g < 5440) ? 3 : 4;
    const float* f = (lvl == 0) ? f0 : (lvl == 1) ? f1 : (lvl == 2) ? f2 : (lvl == 3) ? f3 : f4;
    int pix = g - c_loff[lvl];
    int wsh = c_wsh[lvl];
    int y = pix >> wsh, x = pix & ((1 << wsh) - 1);
    float v = f[(size_t)cin * c_hw[lvl] + pix];
    unsigned short h, l;
    split16(v, h, l);
    size_t idx = ((size_t)(cin >> 5) * PP_TOT + c_poff[lvl] + (size_t)(y + 1) * c_wp[lvl] + x + 1) * 32 + (cin & 31);
    IN[idx] = h;
    IN[PLANE_E + idx] = l;
}

// ---------------- weight fragment prep (f16 hi + scaled-lo, MFMA B-frag order) ----------------
__global__ void wprep_k(const float* __restrict__ ctw, const float* __restrict__ rtw,
                        const float* __restrict__ cow, const float* __restrict__ row_,
                        unsigned short* __restrict__ wf) {
    int gid = blockIdx.x * 256 + threadIdx.x;
    if (gid >= 184 * 72 * 64) return;
    int lane = gid & 63;
    int t = gid >> 6;
    int tap = t % 9;
    int t2 = t / 9;
    int chunk = t2 & 7;
    int cbg = t2 >> 3;
    int r = 0;
#pragma unroll
    for (int i = 1; i <= 10; ++i) if (cbg >= s_cum[i]) r = i;
    int cbl = cbg - s_cum[r];
    const float* src;
    int coutCnt;
    if (r < 3)       { src = ctw + (size_t)(r + 1) * 589824; coutCnt = 256; }
    else if (r < 7)  { src = rtw + (size_t)(r - 3) * 589824; coutCnt = 256; }
    else if (r == 7) { src = cow; coutCnt = 819; }
    else if (r == 8) { src = row_; coutCnt = 36; }
    else             { src = ctw; coutCnt = 256; }
    int cout = cbl * 16 + (lane & 15);
    int q = lane >> 4;
    unsigned short H[8], L[8];
#pragma unroll
    for (int j = 0; j < 8; ++j) {
        int cin = chunk * 32 + q * 8 + j;
        float v = (cout < coutCnt) ? src[((size_t)cout * 256 + cin) * 9 + tap] : 0.0f;
        split16(v, H[j], L[j]);
    }
    size_t off = (size_t)cbg * 73728 + (size_t)(chunk * 9 + tap) * 1024 + (size_t)lane * 8;
#pragma unroll
    for (int j = 0; j < 8; ++j) { wf[off + j] = H[j]; wf[off + 512 + j] = L[j]; }
}

// ---------------- shared MFMA K-loop (LDS double-buffered, wave = 32px x 32cout) ----------------
__device__ __forceinline__ void kloop(const unsigned short* __restrict__ src,
        const char* __restrict__ wf0, char* sm, int wid, int lane,
        int s_base, int s_len, int Wp, const int sloc[2], f4 acc1[2][2], f4 acc2[2][2]) {
    const char* wp = wf0 + lane * 16;
    int nc = (s_len * 64 + 1023) >> 10;
    const char* gbase = (const char*)src;
    {
        const char* g = gbase + (size_t)s_base * 64;
        for (int c = wid; c < nc; c += 4) {
            gl_lds(g + (size_t)c * 1024 + (size_t)lane * 16, sm + c * 1024);
            gl_lds(g + PLANE_B + (size_t)c * 1024 + (size_t)lane * 16, sm + LO_OFF + c * 1024);
        }
    }
    __syncthreads();
    for (int chunk = 0; chunk < 8; ++chunk) {
        char* smc = sm + (chunk & 1) * PHASE;
        if (chunk < 7) {
            char* smn = sm + ((chunk & 1) ^ 1) * PHASE;
            const char* g = gbase + ((size_t)(chunk + 1) * PP_TOT + s_base) * 64;
            for (int c = wid; c < nc; c += 4) {
                gl_lds(g + (size_t)c * 1024 + (size_t)lane * 16, smn + c * 1024);
                gl_lds(g + PLANE_B + (size_t)c * 1024 + (size_t)lane * 16, smn + LO_OFF + c * 1024);
            }
        }
#pragma unroll
        for (int tap = 0; tap < 9; ++tap) {
            int toff = ((tap / 3) - 1) * Wp + (tap % 3) - 1;
            int so = toff * 64;
            int wo = (chunk * 9 + tap) * 2048;
            h8 bh0 = *(const h8*)(wp + wo);
            h8 bl0 = *(const h8*)(wp + wo + 1024);
            h8 bh1 = *(const h8*)(wp + SLB + wo);
            h8 bl1 = *(const h8*)(wp + SLB + wo + 1024);
#pragma unroll
            for (int mb = 0; mb < 2; ++mb) {
                h8 ah = *(const h8*)(smc + sloc[mb] + so);
                h8 al = *(const h8*)(smc + LO_OFF + sloc[mb] + so);
                acc1[mb][0] = MFMA(ah, bh0, acc1[mb][0]);
                acc2[mb][0] = MFMA(al, bh0, acc2[mb][0]);
                acc2[mb][0] = MFMA(ah, bl0, acc2[mb][0]);
                acc1[mb][1] = MFMA(ah, bh1, acc1[mb][1]);
                acc2[mb][1] = MFMA(al, bh1, acc2[mb][1]);
                acc2[mb][1] = MFMA(ah, bl1, acc2[mb][1]);
            }
        }
        __syncthreads();
    }
}

// ---------------- fused tower layer: both towers, 64px x 64cout blocks ----------------
__global__ __launch_bounds__(256, 3) void conv_t(
        const unsigned short* __restrict__ srcC, const unsigned short* __restrict__ srcR,
        unsigned short* __restrict__ dstC, unsigned short* __restrict__ dstR,
        const unsigned short* __restrict__ wfC, const unsigned short* __restrict__ wfR,
        const float* __restrict__ bC, const float* __restrict__ bR) {
    __shared__ __align__(16) char sm[2 * PHASE];
    int tid = threadIdx.x, lane = tid & 63, wid = tid >> 6;
    int quad = lane >> 4, l16 = lane & 15;
    int bx = blockIdx.x, tile = bx >> 3, cb = bx & 7;
    int tower = cb >> 2, cbl = cb & 3;
    const unsigned short* src = tower ? srcR : srcC;
    unsigned short* dst = tower ? dstR : dstC;
    const unsigned short* wfx = tower ? wfR : wfC;
    const float* bias = tower ? bR : bC;

    int lvl, px0, y0;
    tile_geom(tile, lvl, px0, y0);
    int wsh = c_wsh[lvl], HW = c_hw[lvl], Wp = c_wp[lvl];
    int poff = c_poff[lvl];
    int s_base = poff + y0 * Wp, s_len = c_slen[lvl];
    int Mh = (wid & 1) * 32, Nh = (wid >> 1) * 32;

    int sloc[2];
#pragma unroll
    for (int mb = 0; mb < 2; ++mb) {
        int p = px0 + Mh + mb * 16 + l16;
        if (p >= HW) p = HW - 1;
        int y = p >> wsh, x = p & ((1 << wsh) - 1);
        sloc[mb] = ((y - y0 + 1) * Wp + x + 1) * 64 + quad * 16;
    }
    f4 acc1[2][2], acc2[2][2];
#pragma unroll
    for (int mb = 0; mb < 2; ++mb) {
        acc1[mb][0] = (f4)0.0f; acc1[mb][1] = (f4)0.0f;
        acc2[mb][0] = (f4)0.0f; acc2[mb][1] = (f4)0.0f;
    }
    const char* wf0 = (const char*)wfx + (size_t)(cbl * 4 + (Nh >> 4)) * SLB;
    kloop(src, wf0, sm, wid, lane, s_base, s_len, Wp, sloc, acc1, acc2);

    int cbase = cbl * 64;
    float b0 = bias[cbase + Nh + l16];
    float b1 = bias[cbase + Nh + 16 + l16];
#pragma unroll
    for (int mb = 0; mb < 2; ++mb) {
        int pb = px0 + Mh + mb * 16 + quad * 4;
#pragma unroll
        for (int r = 0; r < 4; ++r) {
            int p = pb + r;
            bool valid = p < HW;
            int pc = valid ? p : 0;
            int y = pc >> wsh, x = pc & ((1 << wsh) - 1);
            size_t ppix = poff + (size_t)(y + 1) * Wp + x + 1;
#pragma unroll
            for (int nb = 0; nb < 2; ++nb) {
                int coutg = cbase + Nh + nb * 16 + l16;
                float v = fmaf(acc2[mb][nb][r], 0.000244140625f, acc1[mb][nb][r]) + (nb ? b1 : b0);
                v = fmaxf(v, 0.0f);
                unsigned short h, l;
                split16(v, h, l);
                size_t idx = ((size_t)(coutg >> 5) * PP_TOT + ppix) * 32 + (coutg & 31);
                if (valid) { dst[idx] = h; dst[PLANE_E + idx] = l; }
            }
        }
    }
}

// ---------------- fused heads: cls (sigmoid+collect fused) + reg ----------------
__global__ __launch_bounds__(256, 3) void mhead_t(
        const unsigned short* __restrict__ srcC, const unsigned short* __restrict__ srcR,
        const unsigned short* __restrict__ wfCls, const unsigned short* __restrict__ wfReg,
        const float* __restrict__ cob, const float* __restrict__ rob,
        unsigned long long* __restrict__ keys, int* __restrict__ cnt,
        float* __restrict__ regout) {
    __shared__ __align__(16) char sm[2 * PHASE];
    int tid = threadIdx.x, lane = tid & 63, wid = tid >> 6;
    int quad = lane >> 4, l16 = lane & 15;
    int bx = blockIdx.x, tile = bx / 14, sub = bx - tile * 14;
    bool isCls = sub < 13;

    int lvl, px0, y0;
    tile_geom(tile, lvl, px0, y0);
    int wsh = c_wsh[lvl], HW = c_hw[lvl], Wp = c_wp[lvl];
    int poff = c_poff[lvl];
    int s_base = poff + y0 * Wp, s_len = c_slen[lvl];
    int Mh = (wid & 1) * 32, Nh = (wid >> 1) * 32;

    int sloc[2];
#pragma unroll
    for (int mb = 0; mb < 2; ++mb) {
        int p = px0 + Mh + mb * 16 + l16;
        if (p >= HW) p = HW - 1;
        int y = p >> wsh, x = p & ((1 << wsh) - 1);
        sloc[mb] = ((y - y0 + 1) * Wp + x + 1) * 64 + quad * 16;
    }
    f4 acc1[2][2], acc2[2][2];
#pragma unroll
    for (int mb = 0; mb < 2; ++mb) {
        acc1[mb][0] = (f4)0.0f; acc1[mb][1] = (f4)0.0f;
        acc2[mb][0] = (f4)0.0f; acc2[mb][1] = (f4)0.0f;
    }
    const unsigned short* src = isCls ? srcC : srcR;
    const char* wf0 = isCls ? (const char*)wfCls + (size_t)(sub * 4 + (Nh >> 4)) * SLB
                            : (const char*)wfReg + (size_t)(Nh >> 4) * SLB;
    kloop(src, wf0, sm, wid, lane, s_base, s_len, Wp, sloc, acc1, acc2);

    if (isCls) {
        int ch0 = sub * 64 + Nh + l16;
        float cb0 = (ch0 < 819) ? cob[ch0] : 0.0f;
        float cb1 = (ch0 + 16 < 819) ? cob[ch0 + 16] : 0.0f;
#pragma unroll
        for (int mb = 0; mb < 2; ++mb) {
            int pb = px0 + Mh + mb * 16 + quad * 4;
#pragma unroll
            for (int r = 0; r < 4; ++r) {
                int p = pb + r;
                bool valid = p < HW;
#pragma unroll
                for (int nb = 0; nb < 2; ++nb) {
                    int ch = ch0 + nb * 16;
                    if (valid && ch < 819) {
                        float lg = fmaf(acc2[mb][nb][r], 0.000244140625f, acc1[mb][nb][r]) + (nb ? cb1 : cb0);
                        float s = 1.0f / (1.0f + expf(-lg));
                        if (s > CLS_THRESH) {
                            int a = ch / NUM_CLASSES;
                            int cls = ch - a * NUM_CLASSES;
                            unsigned flat = (unsigned)((p * NUM_ANCH + a) * NUM_CLASSES + cls);
                            int pos = atomicAdd(cnt + lvl, 1);
                            if (pos < KEY_CAP)
                                keys[(size_t)lvl * KEY_CAP + pos] =
                                    ((unsigned long long)__float_as_uint(s) << 32) |
                                    (unsigned long long)(~flat);
                        }
                    }
                }
            }
        }
    } else {
        int ch0 = Nh + l16;
        float rb0 = (ch0 < 36) ? rob[ch0] : 0.0f;
        float rb1 = (ch0 + 16 < 36) ? rob[ch0 + 16] : 0.0f;
        int loff = c_loff[lvl];
#pragma unroll
        for (int mb = 0; mb < 2; ++mb) {
            int pb = px0 + Mh + mb * 16 + quad * 4;
#pragma unroll
            for (int r = 0; r < 4; ++r) {
                int p = pb + r;
                bool valid = p < HW;
#pragma unroll
                for (int nb = 0; nb < 2; ++nb) {
                    int ch = ch0 + nb * 16;
                    if (valid && ch < 36)
                        regout[(size_t)ch * PITCH + loff + p] =
                            fmaf(acc2[mb][nb][r], 0.000244140625f, acc1[mb][nb][r]) + (nb ? rb1 : rb0);
                }
            }
        }
    }
}

// ---------------- 5 per-level sorts ----------------
__global__ __launch_bounds__(1024) void sort5_k(unsigned long long* keys, const int* cnt) {
    const int lvl = blockIdx.x;
    unsigned long long* kb = keys + (size_t)lvl * KEY_CAP;
    int n = cnt[lvl]; if (n > KEY_CAP) n = KEY_CAP;
    int m = 2; while (m < n) m <<= 1;
    __shared__ unsigned long long sk[8192];
    if (m <= 8192) {
        for (int i = threadIdx.x; i < m; i += 1024) sk[i] = (i < n) ? kb[i] : 0ull;
        __syncthreads();
        for (int k = 2; k <= m; k <<= 1)
            for (int j = k >> 1; j > 0; j >>= 1) {
                for (int i = threadIdx.x; i < m; i += 1024) {
                    int ixj = i ^ j;
                    if (ixj > i) {
                        unsigned long long a = sk[i], b = sk[ixj];
                        bool desc = (i & k) == 0;
                        if (desc ? (a < b) : (a > b)) { sk[i] = b; sk[ixj] = a; }
                    }
                }
                __syncthreads();
            }
        for (int i = threadIdx.x; i < m; i += 1024) kb[i] = sk[i];
    } else {
        for (int i = threadIdx.x; i < m; i += 1024) if (i >= n) kb[i] = 0ull;
        __syncthreads();
        for (int k = 2; k <= m; k <<= 1)
            for (int j = k >> 1; j > 0; j >>= 1) {
                for (int i = threadIdx.x; i < m; i += 1024) {
                    int ixj = i ^ j;
                    if (ixj > i) {
                        unsigned long long a = kb[i], b = kb[ixj];
                        bool desc = (i & k) == 0;
                        if (desc ? (a < b) : (a > b)) { kb[i] = b; kb[ixj] = a; }
                    }
                }
                __syncthreads();
            }
    }
}

// ---------------- emit top-1000 per level ----------------
__global__ void emit_k(const unsigned long long* __restrict__ keys, const int* __restrict__ cnt,
                       const float* __restrict__ regout, const float* __restrict__ anchors,
                       float* __restrict__ cs, float* __restrict__ cb, int* __restrict__ cl) {
#pragma clang fp contract(off)
    int r = blockIdx.x * 256 + threadIdx.x;
    if (r >= NCAND) return;
    int lvl = r / 1000, rr = r - lvl * 1000;
    int n = cnt[lvl]; if (n > KEY_CAP) n = KEY_CAP; if (n > 1000) n = 1000;
    float score = -1.0f, b0 = 0.f, b1 = 0.f, b2 = 0.f, b3 = 0.f;
    int label = 0;
    if (rr < n) {
        unsigned long long key = keys[(size_t)lvl * KEY_CAP + rr];
        score = __uint_as_float((unsigned)(key >> 32));
        unsigned flat = ~((unsigned)(key & 0xFFFFFFFFull));
        label = (int)(flat % NUM_CLASSES);
        int af = (int)(flat / NUM_CLASSES);
        int a = af % NUM_ANCH;
        int pix = af / NUM_ANCH;
        int gp = c_loff[lvl] + pix;
        float dx = regout[(size_t)(a * 4 + 0) * PITCH + gp];
        float dy = regout[(size_t)(a * 4 + 1) * PITCH + gp];
        float dw = regout[(size_t)(a * 4 + 2) * PITCH + gp];
        float dh = regout[(size_t)(a * 4 + 3) * PITCH + gp];
        const float* an = anchors + (size_t)(c_aoff[lvl] + af) * 4;
        float aw = an[2] - an[0];
        float ah = an[3] - an[1];
        float cx = an[0] + 0.5f * aw;
        float cy = an[1] + 0.5f * ah;
        dw = fminf(dw, BBOX_CLIP_F);
        dh = fminf(dh, BBOX_CLIP_F);
        float pcx = dx * aw + cx;
        float pcy = dy * ah + cy;
        float pw = expf(dw) * aw;
        float ph = expf(dh) * ah;
        b0 = fminf(fmaxf(pcx - 0.5f * pw, 0.0f), 512.0f);
        b1 = fminf(fmaxf(pcy - 0.5f * ph, 0.0f), 512.0f);
        b2 = fminf(fmaxf(pcx + 0.5f * pw, 0.0f), 512.0f);
        b3 = fminf(fmaxf(pcy + 0.5f * ph, 0.0f), 512.0f);
    }
    cs[r] = score;
    cb[(size_t)r * 4 + 0] = b0;
    cb[(size_t)r * 4 + 1] = b1;
    cb[(size_t)r * 4 + 2] = b2;
    cb[(size_t)r * 4 + 3] = b3;
    cl[r] = label;
}

// ---------------- global sort + sorted-box materialization + nvalid ----------------
__global__ __launch_bounds__(1024) void gsort_k(const float* __restrict__ cs,
        const float* __restrict__ cb, const int* __restrict__ cl,
        int* __restrict__ order, float* __restrict__ sbox, float* __restrict__ sarea,
        int* __restrict__ nvp) {
#pragma clang fp contract(off)
    __shared__ unsigned long long sk[8192];
    __shared__ int cv;
    if (threadIdx.x == 0) cv = 0;
    for (int i = threadIdx.x; i < 8192; i += 1024) {
        unsigned long long key = 0ull;
        if (i < NCAND) {
            unsigned u = __float_as_uint(cs[i]);
            u = (u & 0x80000000u) ? ~u : (u | 0x80000000u);
            key = ((unsigned long long)u << 32) | (unsigned long long)(~(unsigned)i);
        }
        sk[i] = key;
    }
    __syncthreads();
    for (int k = 2; k <= 8192; k <<= 1)
        for (int j = k >> 1; j > 0; j >>= 1) {
            for (int i = threadIdx.x; i < 8192; i += 1024) {
                int ixj = i ^ j;
                if (ixj > i) {
                    unsigned long long a = sk[i], b = sk[ixj];
                    bool d = (i & k) == 0;
                    if (d ? (a < b) : (a > b)) { sk[i] = b; sk[ixj] = a; }
                }
            }
            __syncthreads();
        }
    int local = 0;
    for (int i = threadIdx.x; i < NCAND; i += 1024) {
        int c = (int)(~(unsigned)(sk[i] & 0xFFFFFFFFull));
        order[i] = c;
        float off = (float)cl[c] * 513.0f;   // class spacing; cross-class IoU == 0 exactly
        float x1 = cb[(size_t)c * 4 + 0] + off;
        float y1 = cb[(size_t)c * 4 + 1] + off;
        float x2 = cb[(size_t)c * 4 + 2] + off;
        float y2 = cb[(size_t)c * 4 + 3] + off;
        sbox[(size_t)i * 4 + 0] = x1;
        sbox[(size_t)i * 4 + 1] = y1;
        sbox[(size_t)i * 4 + 2] = x2;
        sbox[(size_t)i * 4 + 3] = y2;
        sarea[i] = (x2 - x1) * (y2 - y1);
        if ((unsigned)(sk[i] >> 32) > 0xBD4CCCCDu) ++local;   // score > 0.05
    }
    atomicAdd(&cv, local);
    __syncthreads();
    if (threadIdx.x == 0) *nvp = cv;
}

// ---------------- IoU suppression bitmask over SORTED ranks ----------------
__global__ void mask_k(const float* __restrict__ sbox, const float* __restrict__ sarea,
                       unsigned long long* __restrict__ mask) {
#pragma clang fp contract(off)
    int t = blockIdx.x * 256 + threadIdx.x;
    if (t >= NCAND * 80) return;
    int i = t / 80, w = t - i * 80;
    float ix1 = sbox[(size_t)i * 4 + 0];
    float iy1 = sbox[(size_t)i * 4 + 1];
    float ix2 = sbox[(size_t)i * 4 + 2];
    float iy2 = sbox[(size_t)i * 4 + 3];
    float ai = sarea[i];
    unsigned long long bits = 0ull;
    int j0 = w * 64;
    for (int b = 0; b < 64; ++b) {
        int j = j0 + b;
        if (j < NCAND) {
            float jx1 = sbox[(size_t)j * 4 + 0];
            float jy1 = sbox[(size_t)j * 4 + 1];
            float jx2 = sbox[(size_t)j * 4 + 2];
            float jy2 = sbox[(size_t)j * 4 + 3];
            float aj = sarea[j];
            float ltx = fmaxf(ix1, jx1), lty = fmaxf(iy1, jy1);
            float rbx = fminf(ix2, jx2), rby = fminf(iy2, jy2);
            float wx = fmaxf(rbx - ltx, 0.0f), wy = fmaxf(rby - lty, 0.0f);
            float inter = wx * wy;
            float iou = inter / (ai + aj - inter + 1e-12f);
            if (iou > 0.5f) bits |= (1ull << b);
        }
    }
    mask[(size_t)i * 80 + w] = bits;
}

// ---------------- single-wave greedy sweep v3 (ctz accept-jumping) ----------------
__global__ __launch_bounds__(64) void sweep_k(const float* __restrict__ cs,
        const float* __restrict__ cb, const int* __restrict__ cl,
        const int* __restrict__ order, const unsigned long long* __restrict__ mask,
        const int* __restrict__ nvp, float* __restrict__ out) {
    const int l = threadIdx.x;
    for (int k = l; k < 1500; k += 64) out[k] = 0.0f;
    for (int k = l; k < 300; k += 64) out[1500 + k] = -1.0f;
    int nv = *nvp; if (nv > NCAND) nv = NCAND;
    if (nv <= 0) return;
    unsigned long long sup0 = 0ull, sup1 = 0ull;   // lane l owns word l; lanes<16 also word 64+l
    int nacc = 0;
    int ntiles = (nv + 63) >> 6;
    for (int g0 = 0; g0 < ntiles; g0 += 8) {
        int gcnt = ntiles - g0; if (gcnt > 8) gcnt = 8;
        unsigned long long ml[8];
#pragma unroll
        for (int g = 0; g < 8; ++g) {
            int t = g0 + g;
            int row = (t << 6) + l;
            ml[g] = (g < gcnt && row < NCAND) ? mask[(size_t)row * 80 + t] : 0ull;
        }
#pragma unroll
        for (int g = 0; g < 8; ++g) {
            if (g >= gcnt) break;
            int t = g0 + g;
            unsigned long long cur = (t < 64) ? (unsigned long long)__shfl((long long)sup0, t, 64)
                                              : (unsigned long long)__shfl((long long)sup1, t - 64, 64);
            int lim = nv - (t << 6);
            unsigned long long valid = (lim >= 64) ? ~0ull : ((1ull << lim) - 1ull);
            unsigned long long rem = ~cur & valid;
            while (rem) {
                int k = __builtin_ctzll(rem);
                int rank = (t << 6) + k;
                unsigned long long mlk = (unsigned long long)__shfl((long long)ml[g], k, 64);
                cur |= mlk;
                rem &= ~cur;
                rem &= ~(1ull << k);
                const unsigned long long* mr = mask + (size_t)rank * 80;
                sup0 |= mr[l];
                if (l < 16) sup1 |= mr[64 + l];
                if (l == 0) {
                    int c = order[rank];
                    out[nacc * 5 + 0] = cs[c];
                    out[nacc * 5 + 1] = cb[(size_t)c * 4 + 0];
                    out[nacc * 5 + 2] = cb[(size_t)c * 4 + 1];
                    out[nacc * 5 + 3] = cb[(size_t)c * 4 + 2];
                    out[nacc * 5 + 4] = cb[(size_t)c * 4 + 3];
                    out[1500 + nacc] = (float)cl[c];
                }
                ++nacc;
                if (nacc == 300) return;
            }
        }
    }
}

// ---------------- host launch ----------------
extern "C" void kernel_launch(void* const* d_in, const int* in_sizes, int n_in,
                              void* d_out, int out_size, void* d_ws, size_t ws_size,
                              hipStream_t stream) {
    const float* f0 = (const float*)d_in[0];
    const float* f1 = (const float*)d_in[1];
    const float* f2 = (const float*)d_in[2];
    const float* f3 = (const float*)d_in[3];
    const float* f4 = (const float*)d_in[4];
    const float* anchors = (const float*)d_in[5];
    const float* ctw = (const float*)d_in[6];
    const float* ctb = (const float*)d_in[7];
    const float* cow = (const float*)d_in[8];
    const float* cob = (const float*)d_in[9];
    const float* rtw = (const float*)d_in[10];
    const float* rtb = (const float*)d_in[11];
    const float* row_ = (const float*)d_in[12];
    const float* rob = (const float*)d_in[13];
    float* out = (float*)d_out;

    // layout (49.2 MB, < 61.3 MB proven in round 2):
    //   wf slices 0..183 @0..27131904; C overlaps slices 168..183 (cls-L1 wts, dead after layer 1)
    char* base = (char*)d_ws;
    unsigned short* wf = (unsigned short*)base;
    unsigned short* C  = (unsigned short*)(base + 24772608);
    unsigned short* IN = (unsigned short*)(base + 30887936);
    unsigned short* A  = (unsigned short*)(base + 37003264);
    unsigned short* B  = (unsigned short*)(base + 43118592);
    int* cnt           = (int*)(base + 49233920);   // 32 B: cnt[0..4], nv at cnt[6]
    int* nvp           = cnt + 6;
    // tail aliases (all dead regions at time of use):
    float* cs    = (float*)(base + 0);              // wf head (dead after mhead)
    float* cbx   = (float*)(base + 32768);
    int*   cl    = (int*)(base + 131072);
    int*   order = (int*)(base + 163840);
    float* sbox  = (float*)(base + 262144);
    float* sarea = (float*)(base + 344064);
    unsigned long long* keys = (unsigned long long*)A;          // A dead after layer 4
    float* regout            = (float*)(base + 37003264 + 2621440);
    unsigned long long* mask = (unsigned long long*)B;          // B dead after layer 4

    unsigned short* SL_clsL[4] = {wf + (size_t)168 * 73728, wf + (size_t)0 * 73728,
                                  wf + (size_t)16 * 73728,  wf + (size_t)32 * 73728};
    unsigned short* SL_regL[4] = {wf + (size_t)48 * 73728, wf + (size_t)64 * 73728,
                                  wf + (size_t)80 * 73728, wf + (size_t)96 * 73728};
    unsigned short* SL_clsH = wf + (size_t)112 * 73728;
    unsigned short* SL_regH = wf + (size_t)164 * 73728;

    hipMemsetAsync(C, 0, 4 * (size_t)ABUF_B, stream);   // zero C, IN, A, B (contiguous)
    hipMemsetAsync(cnt, 0, 32, stream);

    pad_k<<<(256 * PITCH + 255) / 256, 256, 0, stream>>>(f0, f1, f2, f3, f4, IN);
    wprep_k<<<(184 * 72 * 64 + 255) / 256, 256, 0, stream>>>(ctw, rtw, cow, row_, wf);

    // L1: (IN,IN)->(A,B)    [cls-L1 weights live where C will go]
    conv_t<<<86 * 8, 256, 0, stream>>>(IN, IN, A, B, SL_clsL[0], SL_regL[0], ctb, rtb);
    hipMemsetAsync(C, 0, (size_t)ABUF_B, stream);       // re-zero C (was weight data)
    // L2: (A,B)->(C,IN)
    conv_t<<<86 * 8, 256, 0, stream>>>(A, B, C, IN, SL_clsL[1], SL_regL[1], ctb + 256, rtb + 256);
    // L3: (C,IN)->(A,B)
    conv_t<<<86 * 8, 256, 0, stream>>>(C, IN, A, B, SL_clsL[2], SL_regL[2], ctb + 512, rtb + 512);
    // L4: (A,B)->(C,IN)
    conv_t<<<86 * 8, 256, 0, stream>>>(A, B, C, IN, SL_clsL[3], SL_regL[3], ctb + 768, rtb + 768);

    mhead_t<<<86 * 14, 256, 0, stream>>>(C, IN, SL_clsH, SL_regH, cob, rob, keys, cnt, regout);

    sort5_k<<<5, 1024, 0, stream>>>(keys, cnt);
    emit_k<<<(NCAND + 255) / 256, 256, 0, stream>>>(keys, cnt, regout, anchors, cs, cbx, cl);
    gsort_k<<<1, 1024, 0, stream>>>(cs, cbx, cl, order, sbox, sarea, nvp);
    mask_k<<<(NCAND * 80 + 255) / 256, 256, 0, stream>>>(sbox, sarea, mask);
    sweep_k<<<1, 64, 0, stream>>>(cs, cbx, cl, order, mask, nvp, out);
}

// Round 6
// 766.444 us; speedup vs baseline: 13.2402x; 1.0192x over previous
//
#include <hip/hip_runtime.h>
#include <hip/hip_bf16.h>
#include <math.h>

#define CIN 256
#define NUM_CLASSES 91
#define NUM_ANCH 9
#define KEY_CAP 65536
#define NCAND 5000
#define BBOX_CLIP_F 4.135166556742356f
#define CLS_THRESH 0.05f
#define PITCH 5456
#define PP_TOT 5972
#define PLANE_E 1528832      // ushorts per plane (8*5972*32)
#define PLANE_B 3057664      // bytes per plane
#define ABUF_B  6115328      // bytes per act buffer (hi+lo plane)
#define SLB     147456       // bytes per 16-cout weight-frag slice
#define LO_OFF  13312        // LDS offset of lo plane
#define PHASE   26624        // LDS bytes (hi+lo), single-buffered

typedef __attribute__((ext_vector_type(4))) float f4;
typedef _Float16 h8 __attribute__((ext_vector_type(8)));

#define MFMA(a,b,c) __builtin_amdgcn_mfma_f32_16x16x32_f16(a,b,c,0,0,0)

__constant__ int c_wsh[5]  = {6,5,4,3,2};
__constant__ int c_hw[5]   = {4096,1024,256,64,16};
__constant__ int c_wp[5]   = {66,34,18,10,6};
__constant__ int c_poff[5] = {0,4356,5512,5836,5936};
__constant__ int c_slen[5] = {198,136,108,100,36};   // strip len for 64-px tiles
__constant__ int c_loff[5] = {0,4096,5120,5376,5440};
__constant__ int c_aoff[5] = {0,36864,46080,48384,48960};
// wf slice ranges: clsL2,clsL3,clsL4,regL1,regL2,regL3,regL4,clsHead(52),regHead(4),clsL1(16)
__constant__ int s_cum[11] = {0,16,32,48,64,80,96,112,164,168,184};

__device__ __forceinline__ unsigned short f16r(float f) {
    _Float16 h = (_Float16)f;
    return __builtin_bit_cast(unsigned short, h);
}
__device__ __forceinline__ float f16tof(unsigned short u) {
    return (float)__builtin_bit_cast(_Float16, u);
}
// split v = h + l/4096, h zero-guarded against f16 denormal flush, l pre-scaled x4096
__device__ __forceinline__ void split16(float v, unsigned short& h, unsigned short& l) {
    unsigned short hh = (fabsf(v) < 6.103515625e-05f) ? (unsigned short)0 : f16r(v);
    h = hh;
    l = f16r((v - f16tof(hh)) * 4096.0f);
}
__device__ __forceinline__ void gl_lds(const void* g, void* l) {
    __builtin_amdgcn_global_load_lds((const __attribute__((address_space(1))) void*)g,
                                     (__attribute__((address_space(3))) void*)l, 16, 0, 0);
}
__device__ __forceinline__ void tile_geom(int tile, int& lvl, int& px0, int& y0) {
    if (tile < 64)      { lvl = 0; px0 = tile << 6; y0 = tile; }
    else if (tile < 80) { lvl = 1; int j = tile - 64; px0 = j << 6; y0 = j << 1; }
    else if (tile < 84) { lvl = 2; int j = tile - 80; px0 = j << 6; y0 = j << 2; }
    else if (tile == 84){ lvl = 3; px0 = 0; y0 = 0; }
    else                { lvl = 4; px0 = 0; y0 = 0; }
}

// ---------------- pad + split + chunk the input pyramid ----------------
__global__ void pad_k(const float* __restrict__ f0, const float* __restrict__ f1,
                      const float* __restrict__ f2, const float* __restrict__ f3,
                      const float* __restrict__ f4, unsigned short* __restrict__ IN) {
    int gid = blockIdx.x * 256 + threadIdx.x;
    if (gid >= 256 * PITCH) return;
    int cin = gid / PITCH, g = gid - cin * PITCH;
    int lvl = (g < 4096) ? 0 : (g < 5120) ? 1 : (g < 5376) ? 2 : (g < 5440) ? 3 : 4;
    const float* f = (lvl == 0) ? f0 : (lvl == 1) ? f1 : (lvl == 2) ? f2 : (lvl == 3) ? f3 : f4;
    int pix = g - c_loff[lvl];
    int wsh = c_wsh[lvl];
    int y = pix >> wsh, x = pix & ((1 << wsh) - 1);
    float v = f[(size_t)cin * c_hw[lvl] + pix];
    unsigned short h, l;
    split16(v, h, l);
    size_t idx = ((size_t)(cin >> 5) * PP_TOT + c_poff[lvl] + (size_t)(y + 1) * c_wp[lvl] + x + 1) * 32 + (cin & 31);
    IN[idx] = h;
    IN[PLANE_E + idx] = l;
}

// ---------------- weight fragment prep (f16 hi + scaled-lo, MFMA B-frag order) ----------------
__global__ void wprep_k(const float* __restrict__ ctw, const float* __restrict__ rtw,
                        const float* __restrict__ cow, const float* __restrict__ row_,
                        unsigned short* __restrict__ wf) {
    int gid = blockIdx.x * 256 + threadIdx.x;
    if (gid >= 184 * 72 * 64) return;
    int lane = gid & 63;
    int t = gid >> 6;
    int tap = t % 9;
    int t2 = t / 9;
    int chunk = t2 & 7;
    int cbg = t2 >> 3;
    int r = 0;
#pragma unroll
    for (int i = 1; i <= 10; ++i) if (cbg >= s_cum[i]) r = i;
    int cbl = cbg - s_cum[r];
    const float* src;
    int coutCnt;
    if (r < 3)       { src = ctw + (size_t)(r + 1) * 589824; coutCnt = 256; }
    else if (r < 7)  { src = rtw + (size_t)(r - 3) * 589824; coutCnt = 256; }
    else if (r == 7) { src = cow; coutCnt = 819; }
    else if (r == 8) { src = row_; coutCnt = 36; }
    else             { src = ctw; coutCnt = 256; }
    int cout = cbl * 16 + (lane & 15);
    int q = lane >> 4;
    unsigned short H[8], L[8];
#pragma unroll
    for (int j = 0; j < 8; ++j) {
        int cin = chunk * 32 + q * 8 + j;
        float v = (cout < coutCnt) ? src[((size_t)cout * 256 + cin) * 9 + tap] : 0.0f;
        split16(v, H[j], L[j]);
    }
    size_t off = (size_t)cbg * 73728 + (size_t)(chunk * 9 + tap) * 1024 + (size_t)lane * 8;
#pragma unroll
    for (int j = 0; j < 8; ++j) { wf[off + j] = H[j]; wf[off + 512 + j] = L[j]; }
}

// ---------------- shared MFMA K-loop (single LDS buffer, 2 barriers/chunk, high occupancy) ----------------
__device__ __forceinline__ void kloop(const unsigned short* __restrict__ src,
        const char* __restrict__ wf0, char* sm, int wid, int lane,
        int s_base, int s_len, int Wp, const int sloc[2], f4 acc1[2][2], f4 acc2[2][2]) {
    const char* wp = wf0 + lane * 16;
    int nc = (s_len * 64 + 1023) >> 10;
    const char* gbase = (const char*)src;
    for (int chunk = 0; chunk < 8; ++chunk) {
        const char* g = gbase + ((size_t)chunk * PP_TOT + s_base) * 64;
        for (int c = wid; c < nc; c += 4) {
            gl_lds(g + (size_t)c * 1024 + (size_t)lane * 16, sm + c * 1024);
            gl_lds(g + PLANE_B + (size_t)c * 1024 + (size_t)lane * 16, sm + LO_OFF + c * 1024);
        }
        __syncthreads();
#pragma unroll
        for (int tap = 0; tap < 9; ++tap) {
            int toff = ((tap / 3) - 1) * Wp + (tap % 3) - 1;
            int so = toff * 64;
            int wo = (chunk * 9 + tap) * 2048;
            h8 bh0 = *(const h8*)(wp + wo);
            h8 bl0 = *(const h8*)(wp + wo + 1024);
            h8 bh1 = *(const h8*)(wp + SLB + wo);
            h8 bl1 = *(const h8*)(wp + SLB + wo + 1024);
#pragma unroll
            for (int mb = 0; mb < 2; ++mb) {
                h8 ah = *(const h8*)(sm + sloc[mb] + so);
                h8 al = *(const h8*)(sm + LO_OFF + sloc[mb] + so);
                acc1[mb][0] = MFMA(ah, bh0, acc1[mb][0]);
                acc2[mb][0] = MFMA(al, bh0, acc2[mb][0]);
                acc2[mb][0] = MFMA(ah, bl0, acc2[mb][0]);
                acc1[mb][1] = MFMA(ah, bh1, acc1[mb][1]);
                acc2[mb][1] = MFMA(al, bh1, acc2[mb][1]);
                acc2[mb][1] = MFMA(ah, bl1, acc2[mb][1]);
            }
        }
        if (chunk < 7) __syncthreads();
    }
}

// ---------------- fused tower layer: both towers, 64px x 64cout blocks ----------------
__global__ __launch_bounds__(256, 5) void conv_t(
        const unsigned short* __restrict__ srcC, const unsigned short* __restrict__ srcR,
        unsigned short* __restrict__ dstC, unsigned short* __restrict__ dstR,
        const unsigned short* __restrict__ wfC, const unsigned short* __restrict__ wfR,
        const float* __restrict__ bC, const float* __restrict__ bR) {
    __shared__ __align__(16) char sm[PHASE];
    int tid = threadIdx.x, lane = tid & 63, wid = tid >> 6;
    int quad = lane >> 4, l16 = lane & 15;
    int bx = blockIdx.x, tile = bx >> 3, cb = bx & 7;
    int tower = cb >> 2, cbl = cb & 3;
    const unsigned short* src = tower ? srcR : srcC;
    unsigned short* dst = tower ? dstR : dstC;
    const unsigned short* wfx = tower ? wfR : wfC;
    const float* bias = tower ? bR : bC;

    int lvl, px0, y0;
    tile_geom(tile, lvl, px0, y0);
    int wsh = c_wsh[lvl], HW = c_hw[lvl], Wp = c_wp[lvl];
    int poff = c_poff[lvl];
    int s_base = poff + y0 * Wp, s_len = c_slen[lvl];
    int Mh = (wid & 1) * 32, Nh = (wid >> 1) * 32;

    int sloc[2];
#pragma unroll
    for (int mb = 0; mb < 2; ++mb) {
        int p = px0 + Mh + mb * 16 + l16;
        if (p >= HW) p = HW - 1;
        int y = p >> wsh, x = p & ((1 << wsh) - 1);
        sloc[mb] = ((y - y0 + 1) * Wp + x + 1) * 64 + quad * 16;
    }
    f4 acc1[2][2], acc2[2][2];
#pragma unroll
    for (int mb = 0; mb < 2; ++mb) {
        acc1[mb][0] = (f4)0.0f; acc1[mb][1] = (f4)0.0f;
        acc2[mb][0] = (f4)0.0f; acc2[mb][1] = (f4)0.0f;
    }
    const char* wf0 = (const char*)wfx + (size_t)(cbl * 4 + (Nh >> 4)) * SLB;
    kloop(src, wf0, sm, wid, lane, s_base, s_len, Wp, sloc, acc1, acc2);

    int cbase = cbl * 64;
    float b0 = bias[cbase + Nh + l16];
    float b1 = bias[cbase + Nh + 16 + l16];
#pragma unroll
    for (int mb = 0; mb < 2; ++mb) {
        int pb = px0 + Mh + mb * 16 + quad * 4;
#pragma unroll
        for (int r = 0; r < 4; ++r) {
            int p = pb + r;
            bool valid = p < HW;
            int pc = valid ? p : 0;
            int y = pc >> wsh, x = pc & ((1 << wsh) - 1);
            size_t ppix = poff + (size_t)(y + 1) * Wp + x + 1;
#pragma unroll
            for (int nb = 0; nb < 2; ++nb) {
                int coutg = cbase + Nh + nb * 16 + l16;
                float v = fmaf(acc2[mb][nb][r], 0.000244140625f, acc1[mb][nb][r]) + (nb ? b1 : b0);
                v = fmaxf(v, 0.0f);
                unsigned short h, l;
                split16(v, h, l);
                size_t idx = ((size_t)(coutg >> 5) * PP_TOT + ppix) * 32 + (coutg & 31);
                if (valid) { dst[idx] = h; dst[PLANE_E + idx] = l; }
            }
        }
    }
}

// ---------------- fused heads: cls (sigmoid+collect fused) + reg ----------------
__global__ __launch_bounds__(256, 5) void mhead_t(
        const unsigned short* __restrict__ srcC, const unsigned short* __restrict__ srcR,
        const unsigned short* __restrict__ wfCls, const unsigned short* __restrict__ wfReg,
        const float* __restrict__ cob, const float* __restrict__ rob,
        unsigned long long* __restrict__ keys, int* __restrict__ cnt,
        float* __restrict__ regout) {
    __shared__ __align__(16) char sm[PHASE];
    int tid = threadIdx.x, lane = tid & 63, wid = tid >> 6;
    int quad = lane >> 4, l16 = lane & 15;
    int bx = blockIdx.x, tile = bx / 14, sub = bx - tile * 14;
    bool isCls = sub < 13;

    int lvl, px0, y0;
    tile_geom(tile, lvl, px0, y0);
    int wsh = c_wsh[lvl], HW = c_hw[lvl], Wp = c_wp[lvl];
    int poff = c_poff[lvl];
    int s_base = poff + y0 * Wp, s_len = c_slen[lvl];
    int Mh = (wid & 1) * 32, Nh = (wid >> 1) * 32;

    int sloc[2];
#pragma unroll
    for (int mb = 0; mb < 2; ++mb) {
        int p = px0 + Mh + mb * 16 + l16;
        if (p >= HW) p = HW - 1;
        int y = p >> wsh, x = p & ((1 << wsh) - 1);
        sloc[mb] = ((y - y0 + 1) * Wp + x + 1) * 64 + quad * 16;
    }
    f4 acc1[2][2], acc2[2][2];
#pragma unroll
    for (int mb = 0; mb < 2; ++mb) {
        acc1[mb][0] = (f4)0.0f; acc1[mb][1] = (f4)0.0f;
        acc2[mb][0] = (f4)0.0f; acc2[mb][1] = (f4)0.0f;
    }
    const unsigned short* src = isCls ? srcC : srcR;
    const char* wf0 = isCls ? (const char*)wfCls + (size_t)(sub * 4 + (Nh >> 4)) * SLB
                            : (const char*)wfReg + (size_t)(Nh >> 4) * SLB;
    kloop(src, wf0, sm, wid, lane, s_base, s_len, Wp, sloc, acc1, acc2);

    if (isCls) {
        int ch0 = sub * 64 + Nh + l16;
        float cb0 = (ch0 < 819) ? cob[ch0] : 0.0f;
        float cb1 = (ch0 + 16 < 819) ? cob[ch0 + 16] : 0.0f;
#pragma unroll
        for (int mb = 0; mb < 2; ++mb) {
            int pb = px0 + Mh + mb * 16 + quad * 4;
#pragma unroll
            for (int r = 0; r < 4; ++r) {
                int p = pb + r;
                bool valid = p < HW;
#pragma unroll
                for (int nb = 0; nb < 2; ++nb) {
                    int ch = ch0 + nb * 16;
                    if (valid && ch < 819) {
                        float lg = fmaf(acc2[mb][nb][r], 0.000244140625f, acc1[mb][nb][r]) + (nb ? cb1 : cb0);
                        float s = 1.0f / (1.0f + expf(-lg));
                        if (s > CLS_THRESH) {
                            int a = ch / NUM_CLASSES;
                            int cls = ch - a * NUM_CLASSES;
                            unsigned flat = (unsigned)((p * NUM_ANCH + a) * NUM_CLASSES + cls);
                            int pos = atomicAdd(cnt + lvl, 1);
                            if (pos < KEY_CAP)
                                keys[(size_t)lvl * KEY_CAP + pos] =
                                    ((unsigned long long)__float_as_uint(s) << 32) |
                                    (unsigned long long)(~flat);
                        }
                    }
                }
            }
        }
    } else {
        int ch0 = Nh + l16;
        float rb0 = (ch0 < 36) ? rob[ch0] : 0.0f;
        float rb1 = (ch0 + 16 < 36) ? rob[ch0 + 16] : 0.0f;
        int loff = c_loff[lvl];
#pragma unroll
        for (int mb = 0; mb < 2; ++mb) {
            int pb = px0 + Mh + mb * 16 + quad * 4;
#pragma unroll
            for (int r = 0; r < 4; ++r) {
                int p = pb + r;
                bool valid = p < HW;
#pragma unroll
                for (int nb = 0; nb < 2; ++nb) {
                    int ch = ch0 + nb * 16;
                    if (valid && ch < 36)
                        regout[(size_t)ch * PITCH + loff + p] =
                            fmaf(acc2[mb][nb][r], 0.000244140625f, acc1[mb][nb][r]) + (nb ? rb1 : rb0);
                }
            }
        }
    }
}

// ---------------- 5 per-level sorts ----------------
__global__ __launch_bounds__(1024) void sort5_k(unsigned long long* keys, const int* cnt) {
    const int lvl = blockIdx.x;
    unsigned long long* kb = keys + (size_t)lvl * KEY_CAP;
    int n = cnt[lvl]; if (n > KEY_CAP) n = KEY_CAP;
    int m = 2; while (m < n) m <<= 1;
    __shared__ unsigned long long sk[8192];
    if (m <= 8192) {
        for (int i = threadIdx.x; i < m; i += 1024) sk[i] = (i < n) ? kb[i] : 0ull;
        __syncthreads();
        for (int k = 2; k <= m; k <<= 1)
            for (int j = k >> 1; j > 0; j >>= 1) {
                for (int i = threadIdx.x; i < m; i += 1024) {
                    int ixj = i ^ j;
                    if (ixj > i) {
                        unsigned long long a = sk[i], b = sk[ixj];
                        bool desc = (i & k) == 0;
                        if (desc ? (a < b) : (a > b)) { sk[i] = b; sk[ixj] = a; }
                    }
                }
                __syncthreads();
            }
        for (int i = threadIdx.x; i < m; i += 1024) kb[i] = sk[i];
    } else {
        for (int i = threadIdx.x; i < m; i += 1024) if (i >= n) kb[i] = 0ull;
        __syncthreads();
        for (int k = 2; k <= m; k <<= 1)
            for (int j = k >> 1; j > 0; j >>= 1) {
                for (int i = threadIdx.x; i < m; i += 1024) {
                    int ixj = i ^ j;
                    if (ixj > i) {
                        unsigned long long a = kb[i], b = kb[ixj];
                        bool desc = (i & k) == 0;
                        if (desc ? (a < b) : (a > b)) { kb[i] = b; kb[ixj] = a; }
                    }
                }
                __syncthreads();
            }
    }
}

// ---------------- emit top-1000 per level ----------------
__global__ void emit_k(const unsigned long long* __restrict__ keys, const int* __restrict__ cnt,
                       const float* __restrict__ regout, const float* __restrict__ anchors,
                       float* __restrict__ cs, float* __restrict__ cb, int* __restrict__ cl) {
#pragma clang fp contract(off)
    int r = blockIdx.x * 256 + threadIdx.x;
    if (r >= NCAND) return;
    int lvl = r / 1000, rr = r - lvl * 1000;
    int n = cnt[lvl]; if (n > KEY_CAP) n = KEY_CAP; if (n > 1000) n = 1000;
    float score = -1.0f, b0 = 0.f, b1 = 0.f, b2 = 0.f, b3 = 0.f;
    int label = 0;
    if (rr < n) {
        unsigned long long key = keys[(size_t)lvl * KEY_CAP + rr];
        score = __uint_as_float((unsigned)(key >> 32));
        unsigned flat = ~((unsigned)(key & 0xFFFFFFFFull));
        label = (int)(flat % NUM_CLASSES);
        int af = (int)(flat / NUM_CLASSES);
        int a = af % NUM_ANCH;
        int pix = af / NUM_ANCH;
        int gp = c_loff[lvl] + pix;
        float dx = regout[(size_t)(a * 4 + 0) * PITCH + gp];
        float dy = regout[(size_t)(a * 4 + 1) * PITCH + gp];
        float dw = regout[(size_t)(a * 4 + 2) * PITCH + gp];
        float dh = regout[(size_t)(a * 4 + 3) * PITCH + gp];
        const float* an = anchors + (size_t)(c_aoff[lvl] + af) * 4;
        float aw = an[2] - an[0];
        float ah = an[3] - an[1];
        float cx = an[0] + 0.5f * aw;
        float cy = an[1] + 0.5f * ah;
        dw = fminf(dw, BBOX_CLIP_F);
        dh = fminf(dh, BBOX_CLIP_F);
        float pcx = dx * aw + cx;
        float pcy = dy * ah + cy;
        float pw = expf(dw) * aw;
        float ph = expf(dh) * ah;
        b0 = fminf(fmaxf(pcx - 0.5f * pw, 0.0f), 512.0f);
        b1 = fminf(fmaxf(pcy - 0.5f * ph, 0.0f), 512.0f);
        b2 = fminf(fmaxf(pcx + 0.5f * pw, 0.0f), 512.0f);
        b3 = fminf(fmaxf(pcy + 0.5f * ph, 0.0f), 512.0f);
    }
    cs[r] = score;
    cb[(size_t)r * 4 + 0] = b0;
    cb[(size_t)r * 4 + 1] = b1;
    cb[(size_t)r * 4 + 2] = b2;
    cb[(size_t)r * 4 + 3] = b3;
    cl[r] = label;
}

// ---------------- global sort + sorted-box materialization + nvalid ----------------
__global__ __launch_bounds__(1024) void gsort_k(const float* __restrict__ cs,
        const float* __restrict__ cb, const int* __restrict__ cl,
        int* __restrict__ order, float* __restrict__ sbox, float* __restrict__ sarea,
        int* __restrict__ nvp) {
#pragma clang fp contract(off)
    __shared__ unsigned long long sk[8192];
    __shared__ int cv;
    if (threadIdx.x == 0) cv = 0;
    for (int i = threadIdx.x; i < 8192; i += 1024) {
        unsigned long long key = 0ull;
        if (i < NCAND) {
            unsigned u = __float_as_uint(cs[i]);
            u = (u & 0x80000000u) ? ~u : (u | 0x80000000u);
            key = ((unsigned long long)u << 32) | (unsigned long long)(~(unsigned)i);
        }
        sk[i] = key;
    }
    __syncthreads();
    for (int k = 2; k <= 8192; k <<= 1)
        for (int j = k >> 1; j > 0; j >>= 1) {
            for (int i = threadIdx.x; i < 8192; i += 1024) {
                int ixj = i ^ j;
                if (ixj > i) {
                    unsigned long long a = sk[i], b = sk[ixj];
                    bool d = (i & k) == 0;
                    if (d ? (a < b) : (a > b)) { sk[i] = b; sk[ixj] = a; }
                }
            }
            __syncthreads();
        }
    int local = 0;
    for (int i = threadIdx.x; i < NCAND; i += 1024) {
        int c = (int)(~(unsigned)(sk[i] & 0xFFFFFFFFull));
        order[i] = c;
        float off = (float)cl[c] * 513.0f;   // class spacing; cross-class IoU == 0 exactly
        float x1 = cb[(size_t)c * 4 + 0] + off;
        float y1 = cb[(size_t)c * 4 + 1] + off;
        float x2 = cb[(size_t)c * 4 + 2] + off;
        float y2 = cb[(size_t)c * 4 + 3] + off;
        sbox[(size_t)i * 4 + 0] = x1;
        sbox[(size_t)i * 4 + 1] = y1;
        sbox[(size_t)i * 4 + 2] = x2;
        sbox[(size_t)i * 4 + 3] = y2;
        sarea[i] = (x2 - x1) * (y2 - y1);
        if ((unsigned)(sk[i] >> 32) > 0xBD4CCCCDu) ++local;   // score > 0.05
    }
    atomicAdd(&cv, local);
    __syncthreads();
    if (threadIdx.x == 0) *nvp = cv;
}

// ---------------- IoU suppression bitmask over SORTED ranks ----------------
__global__ void mask_k(const float* __restrict__ sbox, const float* __restrict__ sarea,
                       unsigned long long* __restrict__ mask) {
#pragma clang fp contract(off)
    int t = blockIdx.x * 256 + threadIdx.x;
    if (t >= NCAND * 80) return;
    int i = t / 80, w = t - i * 80;
    float ix1 = sbox[(size_t)i * 4 + 0];
    float iy1 = sbox[(size_t)i * 4 + 1];
    float ix2 = sbox[(size_t)i * 4 + 2];
    float iy2 = sbox[(size_t)i * 4 + 3];
    float ai = sarea[i];
    unsigned long long bits = 0ull;
    int j0 = w * 64;
    for (int b = 0; b < 64; ++b) {
        int j = j0 + b;
        if (j < NCAND) {
            float jx1 = sbox[(size_t)j * 4 + 0];
            float jy1 = sbox[(size_t)j * 4 + 1];
            float jx2 = sbox[(size_t)j * 4 + 2];
            float jy2 = sbox[(size_t)j * 4 + 3];
            float aj = sarea[j];
            float ltx = fmaxf(ix1, jx1), lty = fmaxf(iy1, jy1);
            float rbx = fminf(ix2, jx2), rby = fminf(iy2, jy2);
            float wx = fmaxf(rbx - ltx, 0.0f), wy = fmaxf(rby - lty, 0.0f);
            float inter = wx * wy;
            float iou = inter / (ai + aj - inter + 1e-12f);
            if (iou > 0.5f) bits |= (1ull << b);
        }
    }
    mask[(size_t)i * 80 + w] = bits;
}

// ---------------- single-wave greedy sweep v4: tile-batched parallel row gather ----------------
__global__ __launch_bounds__(64) void sweep_k(const unsigned long long* __restrict__ mask,
        const int* __restrict__ nvp, int* __restrict__ accbuf, int* __restrict__ naccp) {
    const int l = threadIdx.x;
    int nv = *nvp; if (nv > NCAND) nv = NCAND;
    int nacc = 0;
    if (nv > 0) {
        unsigned long long sup0 = 0ull, sup1 = 0ull;   // lane l owns word l; lanes<16 also word 64+l
        int ntiles = (nv + 63) >> 6;
        bool done = false;
        for (int g0 = 0; g0 < ntiles && !done; g0 += 8) {
            int gcnt = ntiles - g0; if (gcnt > 8) gcnt = 8;
            unsigned long long ml[8];
#pragma unroll
            for (int g = 0; g < 8; ++g) {
                int t = g0 + g;
                int row = (t << 6) + l;
                ml[g] = (g < gcnt && row < NCAND) ? mask[(size_t)row * 80 + t] : 0ull;
            }
            for (int g = 0; g < gcnt && !done; ++g) {
                int t = g0 + g;
                unsigned long long cur = (t < 64)
                    ? (unsigned long long)__shfl((long long)sup0, t, 64)
                    : (unsigned long long)__shfl((long long)sup1, t - 64, 64);
                int lim = nv - (t << 6);
                unsigned long long valid = (lim >= 64) ? ~0ull : ((1ull << lim) - 1ull);
                unsigned long long rem = ~cur & valid;
                unsigned long long Aset = 0ull;
                while (rem) {
                    int k = __builtin_ctzll(rem);
                    Aset |= 1ull << k;
                    if (l == 0) accbuf[nacc] = (t << 6) + k;
                    ++nacc;
                    if (nacc == 300) { done = true; break; }
                    unsigned long long mlk = (unsigned long long)__shfl((long long)ml[g], k, 64);
                    cur |= mlk | (1ull << k);
                    rem = ~cur & valid;
                }
                if (!done) {
                    // parallel gather: OR accepted rows into distributed sup bitmap, 4 loads in flight
                    unsigned long long t2 = Aset;
                    while (t2) {
                        int i0 = __builtin_ctzll(t2); t2 &= t2 - 1;
                        int i1 = -1, i2 = -1, i3 = -1;
                        if (t2) { i1 = __builtin_ctzll(t2); t2 &= t2 - 1; }
                        if (t2) { i2 = __builtin_ctzll(t2); t2 &= t2 - 1; }
                        if (t2) { i3 = __builtin_ctzll(t2); t2 &= t2 - 1; }
                        size_t r0 = (size_t)((t << 6) + i0) * 80;
                        unsigned long long w0 = mask[r0 + l];
                        unsigned long long w1 = (i1 >= 0) ? mask[(size_t)((t << 6) + i1) * 80 + l] : 0ull;
                        unsigned long long w2 = (i2 >= 0) ? mask[(size_t)((t << 6) + i2) * 80 + l] : 0ull;
                        unsigned long long w3 = (i3 >= 0) ? mask[(size_t)((t << 6) + i3) * 80 + l] : 0ull;
                        sup0 |= w0 | w1 | w2 | w3;
                        if (l < 16) {
                            unsigned long long v0 = mask[r0 + 64 + l];
                            unsigned long long v1 = (i1 >= 0) ? mask[(size_t)((t << 6) + i1) * 80 + 64 + l] : 0ull;
                            unsigned long long v2 = (i2 >= 0) ? mask[(size_t)((t << 6) + i2) * 80 + 64 + l] : 0ull;
                            unsigned long long v3 = (i3 >= 0) ? mask[(size_t)((t << 6) + i3) * 80 + 64 + l] : 0ull;
                            sup1 |= v0 | v1 | v2 | v3;
                        }
                    }
                }
            }
        }
    }
    if (l == 0) *naccp = nacc;
}

// ---------------- fill outputs from accepted ranks ----------------
__global__ void fill_k(const float* __restrict__ cs, const float* __restrict__ cb,
                       const int* __restrict__ cl, const int* __restrict__ order,
                       const int* __restrict__ accbuf, const int* __restrict__ naccp,
                       float* __restrict__ out) {
    int t = blockIdx.x * 64 + threadIdx.x;
    if (t >= 300) return;
    int na = *naccp;
    if (t < na) {
        int c = order[accbuf[t]];
        out[t * 5 + 0] = cs[c];
        out[t * 5 + 1] = cb[(size_t)c * 4 + 0];
        out[t * 5 + 2] = cb[(size_t)c * 4 + 1];
        out[t * 5 + 3] = cb[(size_t)c * 4 + 2];
        out[t * 5 + 4] = cb[(size_t)c * 4 + 3];
        out[1500 + t] = (float)cl[c];
    } else {
        out[t * 5 + 0] = 0.0f; out[t * 5 + 1] = 0.0f; out[t * 5 + 2] = 0.0f;
        out[t * 5 + 3] = 0.0f; out[t * 5 + 4] = 0.0f;
        out[1500 + t] = -1.0f;
    }
}

// ---------------- host launch ----------------
extern "C" void kernel_launch(void* const* d_in, const int* in_sizes, int n_in,
                              void* d_out, int out_size, void* d_ws, size_t ws_size,
                              hipStream_t stream) {
    const float* f0 = (const float*)d_in[0];
    const float* f1 = (const float*)d_in[1];
    const float* f2 = (const float*)d_in[2];
    const float* f3 = (const float*)d_in[3];
    const float* f4 = (const float*)d_in[4];
    const float* anchors = (const float*)d_in[5];
    const float* ctw = (const float*)d_in[6];
    const float* ctb = (const float*)d_in[7];
    const float* cow = (const float*)d_in[8];
    const float* cob = (const float*)d_in[9];
    const float* rtw = (const float*)d_in[10];
    const float* rtb = (const float*)d_in[11];
    const float* row_ = (const float*)d_in[12];
    const float* rob = (const float*)d_in[13];
    float* out = (float*)d_out;

    // layout (49.2 MB):
    //   wf slices 0..183 @0..27131904; C overlaps slices 168..183 (cls-L1 wts, dead after layer 1)
    char* base = (char*)d_ws;
    unsigned short* wf = (unsigned short*)base;
    unsigned short* C  = (unsigned short*)(base + 24772608);
    unsigned short* IN = (unsigned short*)(base + 30887936);
    unsigned short* A  = (unsigned short*)(base + 37003264);
    unsigned short* B  = (unsigned short*)(base + 43118592);
    int* cnt           = (int*)(base + 49233920);   // 32 B: cnt[0..4], nv at [6], nacc at [7]
    int* nvp           = cnt + 6;
    int* naccp         = cnt + 7;
    // tail aliases (all dead regions at time of use):
    float* cs    = (float*)(base + 0);              // wf head (dead after mhead)
    float* cbx   = (float*)(base + 32768);
    int*   cl    = (int*)(base + 131072);
    int*   order = (int*)(base + 163840);
    float* sbox  = (float*)(base + 262144);
    float* sarea = (float*)(base + 344064);
    int*   accbuf = (int*)(base + 368640);
    unsigned long long* keys = (unsigned long long*)A;          // A dead after layer 4
    float* regout            = (float*)(base + 37003264 + 2621440);
    unsigned long long* mask = (unsigned long long*)B;          // B dead after layer 4

    unsigned short* SL_clsL[4] = {wf + (size_t)168 * 73728, wf + (size_t)0 * 73728,
                                  wf + (size_t)16 * 73728,  wf + (size_t)32 * 73728};
    unsigned short* SL_regL[4] = {wf + (size_t)48 * 73728, wf + (size_t)64 * 73728,
                                  wf + (size_t)80 * 73728, wf + (size_t)96 * 73728};
    unsigned short* SL_clsH = wf + (size_t)112 * 73728;
    unsigned short* SL_regH = wf + (size_t)164 * 73728;

    hipMemsetAsync(C, 0, 4 * (size_t)ABUF_B, stream);   // zero C, IN, A, B (contiguous)
    hipMemsetAsync(cnt, 0, 32, stream);

    pad_k<<<(256 * PITCH + 255) / 256, 256, 0, stream>>>(f0, f1, f2, f3, f4, IN);
    wprep_k<<<(184 * 72 * 64 + 255) / 256, 256, 0, stream>>>(ctw, rtw, cow, row_, wf);

    // L1: (IN,IN)->(A,B)    [cls-L1 weights live where C will go]
    conv_t<<<86 * 8, 256, 0, stream>>>(IN, IN, A, B, SL_clsL[0], SL_regL[0], ctb, rtb);
    hipMemsetAsync(C, 0, (size_t)ABUF_B, stream);       // re-zero C (was weight data)
    // L2: (A,B)->(C,IN)
    conv_t<<<86 * 8, 256, 0, stream>>>(A, B, C, IN, SL_clsL[1], SL_regL[1], ctb + 256, rtb + 256);
    // L3: (C,IN)->(A,B)
    conv_t<<<86 * 8, 256, 0, stream>>>(C, IN, A, B, SL_clsL[2], SL_regL[2], ctb + 512, rtb + 512);
    // L4: (A,B)->(C,IN)
    conv_t<<<86 * 8, 256, 0, stream>>>(A, B, C, IN, SL_clsL[3], SL_regL[3], ctb + 768, rtb + 768);

    mhead_t<<<86 * 14, 256, 0, stream>>>(C, IN, SL_clsH, SL_regH, cob, rob, keys, cnt, regout);

    sort5_k<<<5, 1024, 0, stream>>>(keys, cnt);
    emit_k<<<(NCAND + 255) / 256, 256, 0, stream>>>(keys, cnt, regout, anchors, cs, cbx, cl);
    gsort_k<<<1, 1024, 0, stream>>>(cs, cbx, cl, order, sbox, sarea, nvp);
    mask_k<<<(NCAND * 80 + 255) / 256, 256, 0, stream>>>(sbox, sarea, mask);
    sweep_k<<<1, 64, 0, stream>>>(mask, nvp, accbuf, naccp);
    fill_k<<<5, 64, 0, stream>>>(cs, cbx, cl, order, accbuf, naccp, out);
}

// Round 7
// 653.176 us; speedup vs baseline: 15.5362x; 1.1734x over previous
//
#include <hip/hip_runtime.h>
#include <hip/hip_bf16.h>
#include <math.h>

#define CIN 256
#define NUM_CLASSES 91
#define NUM_ANCH 9
#define KEY_CAP 65536
#define NCAND 5000
#define BBOX_CLIP_F 4.135166556742356f
#define CLS_THRESH 0.05f
#define PITCH 5456
#define PP_TOT 5972
#define PLANE_E 1528832      // ushorts per plane (8*5972*32)
#define PLANE_B 3057664      // bytes per plane
#define ABUF_B  6115328      // bytes per act buffer (hi+lo plane)
#define SLB     147456       // bytes per 16-cout weight-frag slice
#define LO_OFF  13312        // LDS offset of lo plane within a phase
#define PHASE   26624        // LDS bytes per phase (hi+lo)

typedef __attribute__((ext_vector_type(4))) float f4;
typedef _Float16 h8 __attribute__((ext_vector_type(8)));

#define MFMA(a,b,c) __builtin_amdgcn_mfma_f32_16x16x32_f16(a,b,c,0,0,0)

__constant__ int c_wsh[5]  = {6,5,4,3,2};
__constant__ int c_hw[5]   = {4096,1024,256,64,16};
__constant__ int c_wp[5]   = {66,34,18,10,6};
__constant__ int c_poff[5] = {0,4356,5512,5836,5936};
__constant__ int c_slen[5] = {198,136,108,100,36};   // strip len for 64-px tiles
__constant__ int c_loff[5] = {0,4096,5120,5376,5440};
__constant__ int c_aoff[5] = {0,36864,46080,48384,48960};
// wf slice ranges: clsL2,clsL3,clsL4,regL1,regL2,regL3,regL4,clsHead(52),regHead(4),clsL1(16)
__constant__ int s_cum[11] = {0,16,32,48,64,80,96,112,164,168,184};

__device__ __forceinline__ unsigned short f16r(float f) {
    _Float16 h = (_Float16)f;
    return __builtin_bit_cast(unsigned short, h);
}
__device__ __forceinline__ float f16tof(unsigned short u) {
    return (float)__builtin_bit_cast(_Float16, u);
}
// split v = h + l/4096, h zero-guarded against f16 denormal flush, l pre-scaled x4096
__device__ __forceinline__ void split16(float v, unsigned short& h, unsigned short& l) {
    unsigned short hh = (fabsf(v) < 6.103515625e-05f) ? (unsigned short)0 : f16r(v);
    h = hh;
    l = f16r((v - f16tof(hh)) * 4096.0f);
}
__device__ __forceinline__ void gl_lds(const void* g, void* l) {
    __builtin_amdgcn_global_load_lds((const __attribute__((address_space(1))) void*)g,
                                     (__attribute__((address_space(3))) void*)l, 16, 0, 0);
}
__device__ __forceinline__ void tile_geom(int tile, int& lvl, int& px0, int& y0) {
    if (tile < 64)      { lvl = 0; px0 = tile << 6; y0 = tile; }
    else if (tile < 80) { lvl = 1; int j = tile - 64; px0 = j << 6; y0 = j << 1; }
    else if (tile < 84) { lvl = 2; int j = tile - 80; px0 = j << 6; y0 = j << 2; }
    else if (tile == 84){ lvl = 3; px0 = 0; y0 = 0; }
    else                { lvl = 4; px0 = 0; y0 = 0; }
}

// ---------------- pad + split + chunk the input pyramid ----------------
__global__ void pad_k(const float* __restrict__ f0, const float* __restrict__ f1,
                      const float* __restrict__ f2, const float* __restrict__ f3,
                      const float* __restrict__ f4, unsigned short* __restrict__ IN) {
    int gid = blockIdx.x * 256 + threadIdx.x;
    if (gid >= 256 * PITCH) return;
    int cin = gid / PITCH, g = gid - cin * PITCH;
    int lvl = (g < 4096) ? 0 : (g < 5120) ? 1 : (g < 5376) ? 2 : (g < 5440) ? 3 : 4;
    const float* f = (lvl == 0) ? f0 : (lvl == 1) ? f1 : (lvl == 2) ? f2 : (lvl == 3) ? f3 : f4;
    int pix = g - c_loff[lvl];
    int wsh = c_wsh[lvl];
    int y = pix >> wsh, x = pix & ((1 << wsh) - 1);
    float v = f[(size_t)cin * c_hw[lvl] + pix];
    unsigned short h, l;
    split16(v, h, l);
    size_t idx = ((size_t)(cin >> 5) * PP_TOT + c_poff[lvl] + (size_t)(y + 1) * c_wp[lvl] + x + 1) * 32 + (cin & 31);
    IN[idx] = h;
    IN[PLANE_E + idx] = l;
}

// ---------------- weight fragment prep (f16 hi + scaled-lo, MFMA B-frag order) ----------------
__global__ void wprep_k(const float* __restrict__ ctw, const float* __restrict__ rtw,
                        const float* __restrict__ cow, const float* __restrict__ row_,
                        unsigned short* __restrict__ wf) {
    int gid = blockIdx.x * 256 + threadIdx.x;
    if (gid >= 184 * 72 * 64) return;
    int lane = gid & 63;
    int t = gid >> 6;
    int tap = t % 9;
    int t2 = t / 9;
    int chunk = t2 & 7;
    int cbg = t2 >> 3;
    int r = 0;
#pragma unroll
    for (int i = 1; i <= 10; ++i) if (cbg >= s_cum[i]) r = i;
    int cbl = cbg - s_cum[r];
    const float* src;
    int coutCnt;
    if (r < 3)       { src = ctw + (size_t)(r + 1) * 589824; coutCnt = 256; }
    else if (r < 7)  { src = rtw + (size_t)(r - 3) * 589824; coutCnt = 256; }
    else if (r == 7) { src = cow; coutCnt = 819; }
    else if (r == 8) { src = row_; coutCnt = 36; }
    else             { src = ctw; coutCnt = 256; }
    int cout = cbl * 16 + (lane & 15);
    int q = lane >> 4;
    unsigned short H[8], L[8];
#pragma unroll
    for (int j = 0; j < 8; ++j) {
        int cin = chunk * 32 + q * 8 + j;
        float v = (cout < coutCnt) ? src[((size_t)cout * 256 + cin) * 9 + tap] : 0.0f;
        split16(v, H[j], L[j]);
    }
    size_t off = (size_t)cbg * 73728 + (size_t)(chunk * 9 + tap) * 1024 + (size_t)lane * 8;
#pragma unroll
    for (int j = 0; j < 8; ++j) { wf[off + j] = H[j]; wf[off + 512 + j] = L[j]; }
}

// ---------------- MFMA K-loop: wave = 32px x 64cout, LDS double-buffered ----------------
__device__ __forceinline__ void kloop(const unsigned short* __restrict__ src,
        const char* __restrict__ wf0, char* sm, int wid, int lane,
        int s_base, int s_len, int Wp, const int sloc[2], f4 acc1[2][4], f4 acc2[2][4]) {
    const char* wp = wf0 + lane * 16;
    int nc = (s_len * 64 + 1023) >> 10;
    const char* gbase = (const char*)src;
    {
        const char* g = gbase + (size_t)s_base * 64;
        for (int c = wid; c < nc; c += 4) {
            gl_lds(g + (size_t)c * 1024 + (size_t)lane * 16, sm + c * 1024);
            gl_lds(g + PLANE_B + (size_t)c * 1024 + (size_t)lane * 16, sm + LO_OFF + c * 1024);
        }
    }
    __syncthreads();
    for (int chunk = 0; chunk < 8; ++chunk) {
        char* smc = sm + (chunk & 1) * PHASE;
        if (chunk < 7) {   // issue next-chunk staging BEFORE compute
            char* smn = sm + ((chunk & 1) ^ 1) * PHASE;
            const char* g = gbase + ((size_t)(chunk + 1) * PP_TOT + s_base) * 64;
            for (int c = wid; c < nc; c += 4) {
                gl_lds(g + (size_t)c * 1024 + (size_t)lane * 16, smn + c * 1024);
                gl_lds(g + PLANE_B + (size_t)c * 1024 + (size_t)lane * 16, smn + LO_OFF + c * 1024);
            }
        }
#pragma unroll
        for (int tap = 0; tap < 9; ++tap) {
            int toff = ((tap / 3) - 1) * Wp + (tap % 3) - 1;
            int so = toff * 64;
            int wo = (chunk * 9 + tap) * 2048;
            h8 ah0 = *(const h8*)(smc + sloc[0] + so);
            h8 al0 = *(const h8*)(smc + LO_OFF + sloc[0] + so);
            h8 ah1 = *(const h8*)(smc + sloc[1] + so);
            h8 al1 = *(const h8*)(smc + LO_OFF + sloc[1] + so);
#pragma unroll
            for (int sl = 0; sl < 4; ++sl) {
                h8 bh = *(const h8*)(wp + (size_t)sl * SLB + wo);
                h8 bl = *(const h8*)(wp + (size_t)sl * SLB + wo + 1024);
                acc1[0][sl] = MFMA(ah0, bh, acc1[0][sl]);
                acc2[0][sl] = MFMA(al0, bh, acc2[0][sl]);
                acc2[0][sl] = MFMA(ah0, bl, acc2[0][sl]);
                acc1[1][sl] = MFMA(ah1, bh, acc1[1][sl]);
                acc2[1][sl] = MFMA(al1, bh, acc2[1][sl]);
                acc2[1][sl] = MFMA(ah1, bl, acc2[1][sl]);
            }
        }
        __syncthreads();
    }
}

// ---------------- fused tower layer: both towers, 64px x 128cout blocks (4 waves) ----------------
__global__ __launch_bounds__(256, 3) void conv_t(
        const unsigned short* __restrict__ srcC, const unsigned short* __restrict__ srcR,
        unsigned short* __restrict__ dstC, unsigned short* __restrict__ dstR,
        const unsigned short* __restrict__ wfC, const unsigned short* __restrict__ wfR,
        const float* __restrict__ bC, const float* __restrict__ bR) {
    __shared__ __align__(16) char sm[2 * PHASE];
    int tid = threadIdx.x, lane = tid & 63, wid = tid >> 6;
    int quad = lane >> 4, l16 = lane & 15;
    int bx = blockIdx.x, tile = bx >> 2, rem = bx & 3;
    int tower = rem >> 1, cb = rem & 1;
    const unsigned short* src = tower ? srcR : srcC;
    unsigned short* dst = tower ? dstR : dstC;
    const unsigned short* wfx = tower ? wfR : wfC;
    const float* bias = tower ? bR : bC;

    int lvl, px0, y0;
    tile_geom(tile, lvl, px0, y0);
    int wsh = c_wsh[lvl], HW = c_hw[lvl], Wp = c_wp[lvl];
    int poff = c_poff[lvl];
    int s_base = poff + y0 * Wp, s_len = c_slen[lvl];
    int Mh = (wid & 1) * 32, Nh64 = wid >> 1;          // wave: 32 px x 64 couts

    int sloc[2];
#pragma unroll
    for (int mb = 0; mb < 2; ++mb) {
        int p = px0 + Mh + mb * 16 + l16;
        if (p >= HW) p = HW - 1;
        int y = p >> wsh, x = p & ((1 << wsh) - 1);
        sloc[mb] = ((y - y0 + 1) * Wp + x + 1) * 64 + quad * 16;
    }
    f4 acc1[2][4], acc2[2][4];
#pragma unroll
    for (int mb = 0; mb < 2; ++mb)
#pragma unroll
        for (int sl = 0; sl < 4; ++sl) { acc1[mb][sl] = (f4)0.0f; acc2[mb][sl] = (f4)0.0f; }

    const char* wf0 = (const char*)wfx + (size_t)(cb * 8 + Nh64 * 4) * SLB;
    kloop(src, wf0, sm, wid, lane, s_base, s_len, Wp, sloc, acc1, acc2);

    int cbase = cb * 128 + Nh64 * 64;
    float bv[4];
#pragma unroll
    for (int sl = 0; sl < 4; ++sl) bv[sl] = bias[cbase + sl * 16 + l16];
#pragma unroll
    for (int mb = 0; mb < 2; ++mb) {
        int pb = px0 + Mh + mb * 16 + quad * 4;
#pragma unroll
        for (int r = 0; r < 4; ++r) {
            int p = pb + r;
            bool valid = p < HW;
            int pc = valid ? p : 0;
            int y = pc >> wsh, x = pc & ((1 << wsh) - 1);
            size_t ppix = poff + (size_t)(y + 1) * Wp + x + 1;
#pragma unroll
            for (int sl = 0; sl < 4; ++sl) {
                int coutg = cbase + sl * 16 + l16;
                float v = fmaf(acc2[mb][sl][r], 0.000244140625f, acc1[mb][sl][r]) + bv[sl];
                v = fmaxf(v, 0.0f);
                unsigned short h, l;
                split16(v, h, l);
                size_t idx = ((size_t)(coutg >> 5) * PP_TOT + ppix) * 32 + (coutg & 31);
                if (valid) { dst[idx] = h; dst[PLANE_E + idx] = l; }
            }
        }
    }
}

// ---------------- fused heads: cls (sigmoid+collect fused) + reg ----------------
__global__ __launch_bounds__(256, 3) void mhead_t(
        const unsigned short* __restrict__ srcC, const unsigned short* __restrict__ srcR,
        const unsigned short* __restrict__ wfCls, const unsigned short* __restrict__ wfReg,
        const float* __restrict__ cob, const float* __restrict__ rob,
        unsigned long long* __restrict__ keys, int* __restrict__ cnt,
        float* __restrict__ regout) {
    __shared__ __align__(16) char sm[2 * PHASE];
    int tid = threadIdx.x, lane = tid & 63, wid = tid >> 6;
    int quad = lane >> 4, l16 = lane & 15;
    int bx = blockIdx.x, tile = bx >> 3, sub = bx & 7;
    bool isCls = sub < 7;

    int lvl, px0, y0;
    tile_geom(tile, lvl, px0, y0);
    int wsh = c_wsh[lvl], HW = c_hw[lvl], Wp = c_wp[lvl];
    int poff = c_poff[lvl];
    int s_base = poff + y0 * Wp, s_len = c_slen[lvl];
    int Mh = (wid & 1) * 32, Nh64 = wid >> 1;          // wave: 32 px x 64 couts (2 Nh per block)

    int sloc[2];
#pragma unroll
    for (int mb = 0; mb < 2; ++mb) {
        int p = px0 + Mh + mb * 16 + l16;
        if (p >= HW) p = HW - 1;
        int y = p >> wsh, x = p & ((1 << wsh) - 1);
        sloc[mb] = ((y - y0 + 1) * Wp + x + 1) * 64 + quad * 16;
    }
    f4 acc1[2][4], acc2[2][4];
#pragma unroll
    for (int mb = 0; mb < 2; ++mb)
#pragma unroll
        for (int sl = 0; sl < 4; ++sl) { acc1[mb][sl] = (f4)0.0f; acc2[mb][sl] = (f4)0.0f; }

    const unsigned short* src = isCls ? srcC : srcR;
    // cls: subs 0..6 cover couts [sub*128, sub*128+128) (sub 6 tail guarded by ch<819)
    // reg: couts [Nh64*64 ...) guarded by ch<36. OOB slice reads hit dead wf regions (discarded).
    const char* wf0 = isCls ? (const char*)wfCls + (size_t)(sub * 8 + Nh64 * 4) * SLB
                            : (const char*)wfReg + (size_t)(Nh64 * 4) * SLB;
    kloop(src, wf0, sm, wid, lane, s_base, s_len, Wp, sloc, acc1, acc2);

    if (isCls) {
        int chb = sub * 128 + Nh64 * 64;
        float cbv[4];
#pragma unroll
        for (int sl = 0; sl < 4; ++sl) {
            int ch = chb + sl * 16 + l16;
            cbv[sl] = (ch < 819) ? cob[ch] : 0.0f;
        }
#pragma unroll
        for (int mb = 0; mb < 2; ++mb) {
            int pb = px0 + Mh + mb * 16 + quad * 4;
#pragma unroll
            for (int r = 0; r < 4; ++r) {
                int p = pb + r;
                bool valid = p < HW;
#pragma unroll
                for (int sl = 0; sl < 4; ++sl) {
                    int ch = chb + sl * 16 + l16;
                    if (valid && ch < 819) {
                        float lg = fmaf(acc2[mb][sl][r], 0.000244140625f, acc1[mb][sl][r]) + cbv[sl];
                        float s = 1.0f / (1.0f + expf(-lg));
                        if (s > CLS_THRESH) {
                            int a = ch / NUM_CLASSES;
                            int cls = ch - a * NUM_CLASSES;
                            unsigned flat = (unsigned)((p * NUM_ANCH + a) * NUM_CLASSES + cls);
                            int pos = atomicAdd(cnt + lvl, 1);
                            if (pos < KEY_CAP)
                                keys[(size_t)lvl * KEY_CAP + pos] =
                                    ((unsigned long long)__float_as_uint(s) << 32) |
                                    (unsigned long long)(~flat);
                        }
                    }
                }
            }
        }
    } else {
        int chb = Nh64 * 64;
        float rbv[4];
#pragma unroll
        for (int sl = 0; sl < 4; ++sl) {
            int ch = chb + sl * 16 + l16;
            rbv[sl] = (ch < 36) ? rob[ch] : 0.0f;
        }
        int loff = c_loff[lvl];
#pragma unroll
        for (int mb = 0; mb < 2; ++mb) {
            int pb = px0 + Mh + mb * 16 + quad * 4;
#pragma unroll
            for (int r = 0; r < 4; ++r) {
                int p = pb + r;
                bool valid = p < HW;
#pragma unroll
                for (int sl = 0; sl < 4; ++sl) {
                    int ch = chb + sl * 16 + l16;
                    if (valid && ch < 36)
                        regout[(size_t)ch * PITCH + loff + p] =
                            fmaf(acc2[mb][sl][r], 0.000244140625f, acc1[mb][sl][r]) + rbv[sl];
                }
            }
        }
    }
}

// ---------------- 5 per-level sorts ----------------
__global__ __launch_bounds__(1024) void sort5_k(unsigned long long* keys, const int* cnt) {
    const int lvl = blockIdx.x;
    unsigned long long* kb = keys + (size_t)lvl * KEY_CAP;
    int n = cnt[lvl]; if (n > KEY_CAP) n = KEY_CAP;
    int m = 2; while (m < n) m <<= 1;
    __shared__ unsigned long long sk[8192];
    if (m <= 8192) {
        for (int i = threadIdx.x; i < m; i += 1024) sk[i] = (i < n) ? kb[i] : 0ull;
        __syncthreads();
        for (int k = 2; k <= m; k <<= 1)
            for (int j = k >> 1; j > 0; j >>= 1) {
                for (int i = threadIdx.x; i < m; i += 1024) {
                    int ixj = i ^ j;
                    if (ixj > i) {
                        unsigned long long a = sk[i], b = sk[ixj];
                        bool desc = (i & k) == 0;
                        if (desc ? (a < b) : (a > b)) { sk[i] = b; sk[ixj] = a; }
                    }
                }
                __syncthreads();
            }
        for (int i = threadIdx.x; i < m; i += 1024) kb[i] = sk[i];
    } else {
        for (int i = threadIdx.x; i < m; i += 1024) if (i >= n) kb[i] = 0ull;
        __syncthreads();
        for (int k = 2; k <= m; k <<= 1)
            for (int j = k >> 1; j > 0; j >>= 1) {
                for (int i = threadIdx.x; i < m; i += 1024) {
                    int ixj = i ^ j;
                    if (ixj > i) {
                        unsigned long long a = kb[i], b = kb[ixj];
                        bool desc = (i & k) == 0;
                        if (desc ? (a < b) : (a > b)) { kb[i] = b; kb[ixj] = a; }
                    }
                }
                __syncthreads();
            }
    }
}

// ---------------- emit top-1000 per level ----------------
__global__ void emit_k(const unsigned long long* __restrict__ keys, const int* __restrict__ cnt,
                       const float* __restrict__ regout, const float* __restrict__ anchors,
                       float* __restrict__ cs, float* __restrict__ cb, int* __restrict__ cl) {
#pragma clang fp contract(off)
    int r = blockIdx.x * 256 + threadIdx.x;
    if (r >= NCAND) return;
    int lvl = r / 1000, rr = r - lvl * 1000;
    int n = cnt[lvl]; if (n > KEY_CAP) n = KEY_CAP; if (n > 1000) n = 1000;
    float score = -1.0f, b0 = 0.f, b1 = 0.f, b2 = 0.f, b3 = 0.f;
    int label = 0;
    if (rr < n) {
        unsigned long long key = keys[(size_t)lvl * KEY_CAP + rr];
        score = __uint_as_float((unsigned)(key >> 32));
        unsigned flat = ~((unsigned)(key & 0xFFFFFFFFull));
        label = (int)(flat % NUM_CLASSES);
        int af = (int)(flat / NUM_CLASSES);
        int a = af % NUM_ANCH;
        int pix = af / NUM_ANCH;
        int gp = c_loff[lvl] + pix;
        float dx = regout[(size_t)(a * 4 + 0) * PITCH + gp];
        float dy = regout[(size_t)(a * 4 + 1) * PITCH + gp];
        float dw = regout[(size_t)(a * 4 + 2) * PITCH + gp];
        float dh = regout[(size_t)(a * 4 + 3) * PITCH + gp];
        const float* an = anchors + (size_t)(c_aoff[lvl] + af) * 4;
        float aw = an[2] - an[0];
        float ah = an[3] - an[1];
        float cx = an[0] + 0.5f * aw;
        float cy = an[1] + 0.5f * ah;
        dw = fminf(dw, BBOX_CLIP_F);
        dh = fminf(dh, BBOX_CLIP_F);
        float pcx = dx * aw + cx;
        float pcy = dy * ah + cy;
        float pw = expf(dw) * aw;
        float ph = expf(dh) * ah;
        b0 = fminf(fmaxf(pcx - 0.5f * pw, 0.0f), 512.0f);
        b1 = fminf(fmaxf(pcy - 0.5f * ph, 0.0f), 512.0f);
        b2 = fminf(fmaxf(pcx + 0.5f * pw, 0.0f), 512.0f);
        b3 = fminf(fmaxf(pcy + 0.5f * ph, 0.0f), 512.0f);
    }
    cs[r] = score;
    cb[(size_t)r * 4 + 0] = b0;
    cb[(size_t)r * 4 + 1] = b1;
    cb[(size_t)r * 4 + 2] = b2;
    cb[(size_t)r * 4 + 3] = b3;
    cl[r] = label;
}

// ---------------- global rank via per-level binary search (replaces 8192-bitonic gsort) ----------------
// rank(c=(lvl,pos)) = pos + sum_{l'<lvl} #{score' >= s} + sum_{l'>lvl} #{score' > s}
// == stable merge by (score desc, global index asc): exact gsort tie-break.
__global__ void rank_k(const float* __restrict__ cs, const float* __restrict__ cbx,
                       const int* __restrict__ cl, const int* __restrict__ cnt,
                       int* __restrict__ order, float* __restrict__ sbox,
                       float* __restrict__ sarea, int* __restrict__ nvp) {
#pragma clang fp contract(off)
    __shared__ int vls[5];
    int t = blockIdx.x * 256 + threadIdx.x;
    if (threadIdx.x < 5) {
        int n = cnt[threadIdx.x]; if (n > 1000) n = 1000;
        vls[threadIdx.x] = n;
    }
    __syncthreads();
    if (t >= NCAND) return;
    if (t == 0) *nvp = vls[0] + vls[1] + vls[2] + vls[3] + vls[4];
    int lvl = t / 1000, pos = t - lvl * 1000;
    if (pos >= vls[lvl]) return;                 // filler slot
    float s = cs[t];
    int rank = pos;
#pragma unroll
    for (int l2 = 0; l2 < 5; ++l2) {
        if (l2 == lvl) continue;
        int n = vls[l2];
        const float* seg = cs + l2 * 1000;       // descending
        int lo = 0, hi = n;
        if (l2 < lvl) {                          // count >= s
            while (lo < hi) { int mid = (lo + hi) >> 1; if (seg[mid] >= s) lo = mid + 1; else hi = mid; }
        } else {                                 // count > s
            while (lo < hi) { int mid = (lo + hi) >> 1; if (seg[mid] > s) lo = mid + 1; else hi = mid; }
        }
        rank += lo;
    }
    order[rank] = t;
    float off = (float)cl[t] * 513.0f;           // class spacing; cross-class IoU == 0 exactly
    float x1 = cbx[(size_t)t * 4 + 0] + off;
    float y1 = cbx[(size_t)t * 4 + 1] + off;
    float x2 = cbx[(size_t)t * 4 + 2] + off;
    float y2 = cbx[(size_t)t * 4 + 3] + off;
    sbox[(size_t)rank * 4 + 0] = x1;
    sbox[(size_t)rank * 4 + 1] = y1;
    sbox[(size_t)rank * 4 + 2] = x2;
    sbox[(size_t)rank * 4 + 3] = y2;
    sarea[rank] = (x2 - x1) * (y2 - y1);
}

// ---------------- IoU suppression bitmask over SORTED ranks ----------------
__global__ void mask_k(const float* __restrict__ sbox, const float* __restrict__ sarea,
                       const int* __restrict__ nvp, unsigned long long* __restrict__ mask) {
#pragma clang fp contract(off)
    int nv = *nvp;
    int t = blockIdx.x * 256 + threadIdx.x;
    if (t >= NCAND * 80) return;
    int i = t / 80, w = t - i * 80;
    if (i >= nv) return;                         // rows beyond nv never read
    float ix1 = sbox[(size_t)i * 4 + 0];
    float iy1 = sbox[(size_t)i * 4 + 1];
    float ix2 = sbox[(size_t)i * 4 + 2];
    float iy2 = sbox[(size_t)i * 4 + 3];
    float ai = sarea[i];
    unsigned long long bits = 0ull;
    int j0 = w * 64;
    for (int b = 0; b < 64; ++b) {
        int j = j0 + b;
        if (j < nv) {
            float jx1 = sbox[(size_t)j * 4 + 0];
            float jy1 = sbox[(size_t)j * 4 + 1];
            float jx2 = sbox[(size_t)j * 4 + 2];
            float jy2 = sbox[(size_t)j * 4 + 3];
            float aj = sarea[j];
            float ltx = fmaxf(ix1, jx1), lty = fmaxf(iy1, jy1);
            float rbx = fminf(ix2, jx2), rby = fminf(iy2, jy2);
            float wx = fmaxf(rbx - ltx, 0.0f), wy = fmaxf(rby - lty, 0.0f);
            float inter = wx * wy;
            float iou = inter / (ai + aj - inter + 1e-12f);
            if (iou > 0.5f) bits |= (1ull << b);
        }
    }
    mask[(size_t)i * 80 + w] = bits;
}

// ---------------- single-wave greedy sweep: tile-batched parallel row gather ----------------
__global__ __launch_bounds__(64) void sweep_k(const unsigned long long* __restrict__ mask,
        const int* __restrict__ nvp, int* __restrict__ accbuf, int* __restrict__ naccp) {
    const int l = threadIdx.x;
    int nv = *nvp; if (nv > NCAND) nv = NCAND;
    int nacc = 0;
    if (nv > 0) {
        unsigned long long sup0 = 0ull, sup1 = 0ull;   // lane l owns word l; lanes<16 also word 64+l
        int ntiles = (nv + 63) >> 6;
        bool done = false;
        for (int g0 = 0; g0 < ntiles && !done; g0 += 8) {
            int gcnt = ntiles - g0; if (gcnt > 8) gcnt = 8;
            unsigned long long ml[8];
#pragma unroll
            for (int g = 0; g < 8; ++g) {
                int t = g0 + g;
                int row = (t << 6) + l;
                ml[g] = (g < gcnt && row < nv) ? mask[(size_t)row * 80 + t] : 0ull;
            }
            for (int g = 0; g < gcnt && !done; ++g) {
                int t = g0 + g;
                unsigned long long cur = (t < 64)
                    ? (unsigned long long)__shfl((long long)sup0, t, 64)
                    : (unsigned long long)__shfl((long long)sup1, t - 64, 64);
                int lim = nv - (t << 6);
                unsigned long long valid = (lim >= 64) ? ~0ull : ((1ull << lim) - 1ull);
                unsigned long long rem = ~cur & valid;
                unsigned long long Aset = 0ull;
                while (rem) {
                    int k = __builtin_ctzll(rem);
                    Aset |= 1ull << k;
                    if (l == 0) accbuf[nacc] = (t << 6) + k;
                    ++nacc;
                    if (nacc == 300) { done = true; break; }
                    unsigned long long mlk = (unsigned long long)__shfl((long long)ml[g], k, 64);
                    cur |= mlk | (1ull << k);
                    rem = ~cur & valid;
                }
                if (!done) {
                    unsigned long long t2 = Aset;
                    while (t2) {
                        int i0 = __builtin_ctzll(t2); t2 &= t2 - 1;
                        int i1 = -1, i2 = -1, i3 = -1;
                        if (t2) { i1 = __builtin_ctzll(t2); t2 &= t2 - 1; }
                        if (t2) { i2 = __builtin_ctzll(t2); t2 &= t2 - 1; }
                        if (t2) { i3 = __builtin_ctzll(t2); t2 &= t2 - 1; }
                        size_t r0 = (size_t)((t << 6) + i0) * 80;
                        unsigned long long w0 = mask[r0 + l];
                        unsigned long long w1 = (i1 >= 0) ? mask[(size_t)((t << 6) + i1) * 80 + l] : 0ull;
                        unsigned long long w2 = (i2 >= 0) ? mask[(size_t)((t << 6) + i2) * 80 + l] : 0ull;
                        unsigned long long w3 = (i3 >= 0) ? mask[(size_t)((t << 6) + i3) * 80 + l] : 0ull;
                        sup0 |= w0 | w1 | w2 | w3;
                        if (l < 16) {
                            unsigned long long v0 = mask[r0 + 64 + l];
                            unsigned long long v1 = (i1 >= 0) ? mask[(size_t)((t << 6) + i1) * 80 + 64 + l] : 0ull;
                            unsigned long long v2 = (i2 >= 0) ? mask[(size_t)((t << 6) + i2) * 80 + 64 + l] : 0ull;
                            unsigned long long v3 = (i3 >= 0) ? mask[(size_t)((t << 6) + i3) * 80 + 64 + l] : 0ull;
                            sup1 |= v0 | v1 | v2 | v3;
                        }
                    }
                }
            }
        }
    }
    if (l == 0) *naccp = nacc;
}

// ---------------- fill outputs from accepted ranks ----------------
__global__ void fill_k(const float* __restrict__ cs, const float* __restrict__ cb,
                       const int* __restrict__ cl, const int* __restrict__ order,
                       const int* __restrict__ accbuf, const int* __restrict__ naccp,
                       float* __restrict__ out) {
    int t = blockIdx.x * 64 + threadIdx.x;
    if (t >= 300) return;
    int na = *naccp;
    if (t < na) {
        int c = order[accbuf[t]];
        out[t * 5 + 0] = cs[c];
        out[t * 5 + 1] = cb[(size_t)c * 4 + 0];
        out[t * 5 + 2] = cb[(size_t)c * 4 + 1];
        out[t * 5 + 3] = cb[(size_t)c * 4 + 2];
        out[t * 5 + 4] = cb[(size_t)c * 4 + 3];
        out[1500 + t] = (float)cl[c];
    } else {
        out[t * 5 + 0] = 0.0f; out[t * 5 + 1] = 0.0f; out[t * 5 + 2] = 0.0f;
        out[t * 5 + 3] = 0.0f; out[t * 5 + 4] = 0.0f;
        out[1500 + t] = -1.0f;
    }
}

// ---------------- host launch ----------------
extern "C" void kernel_launch(void* const* d_in, const int* in_sizes, int n_in,
                              void* d_out, int out_size, void* d_ws, size_t ws_size,
                              hipStream_t stream) {
    const float* f0 = (const float*)d_in[0];
    const float* f1 = (const float*)d_in[1];
    const float* f2 = (const float*)d_in[2];
    const float* f3 = (const float*)d_in[3];
    const float* f4 = (const float*)d_in[4];
    const float* anchors = (const float*)d_in[5];
    const float* ctw = (const float*)d_in[6];
    const float* ctb = (const float*)d_in[7];
    const float* cow = (const float*)d_in[8];
    const float* cob = (const float*)d_in[9];
    const float* rtw = (const float*)d_in[10];
    const float* rtb = (const float*)d_in[11];
    const float* row_ = (const float*)d_in[12];
    const float* rob = (const float*)d_in[13];
    float* out = (float*)d_out;

    // layout (49.2 MB):
    //   wf slices 0..183 @0..27131904; C overlaps slices 168..183 (cls-L1 wts, dead after layer 1)
    char* base = (char*)d_ws;
    unsigned short* wf = (unsigned short*)base;
    unsigned short* C  = (unsigned short*)(base + 24772608);
    unsigned short* IN = (unsigned short*)(base + 30887936);
    unsigned short* A  = (unsigned short*)(base + 37003264);
    unsigned short* B  = (unsigned short*)(base + 43118592);
    int* cnt           = (int*)(base + 49233920);   // 32 B: cnt[0..4], nv at [6], nacc at [7]
    int* nvp           = cnt + 6;
    int* naccp         = cnt + 7;
    // tail aliases (all dead regions at time of use):
    float* cs    = (float*)(base + 0);              // wf head (dead after mhead)
    float* cbx   = (float*)(base + 32768);
    int*   cl    = (int*)(base + 131072);
    int*   order = (int*)(base + 163840);
    float* sbox  = (float*)(base + 262144);
    float* sarea = (float*)(base + 344064);
    int*   accbuf = (int*)(base + 368640);
    unsigned long long* keys = (unsigned long long*)A;          // A dead after layer 4
    float* regout            = (float*)(base + 37003264 + 2621440);
    unsigned long long* mask = (unsigned long long*)B;          // B dead after layer 4

    unsigned short* SL_clsL[4] = {wf + (size_t)168 * 73728, wf + (size_t)0 * 73728,
                                  wf + (size_t)16 * 73728,  wf + (size_t)32 * 73728};
    unsigned short* SL_regL[4] = {wf + (size_t)48 * 73728, wf + (size_t)64 * 73728,
                                  wf + (size_t)80 * 73728, wf + (size_t)96 * 73728};
    unsigned short* SL_clsH = wf + (size_t)112 * 73728;
    unsigned short* SL_regH = wf + (size_t)164 * 73728;

    hipMemsetAsync(C, 0, 4 * (size_t)ABUF_B, stream);   // zero C, IN, A, B (contiguous)
    hipMemsetAsync(cnt, 0, 32, stream);

    pad_k<<<(256 * PITCH + 255) / 256, 256, 0, stream>>>(f0, f1, f2, f3, f4, IN);
    wprep_k<<<(184 * 72 * 64 + 255) / 256, 256, 0, stream>>>(ctw, rtw, cow, row_, wf);

    // L1: (IN,IN)->(A,B)    [cls-L1 weights live where C will go]
    conv_t<<<86 * 4, 256, 0, stream>>>(IN, IN, A, B, SL_clsL[0], SL_regL[0], ctb, rtb);
    hipMemsetAsync(C, 0, (size_t)ABUF_B, stream);       // re-zero C (was weight data)
    // L2: (A,B)->(C,IN)
    conv_t<<<86 * 4, 256, 0, stream>>>(A, B, C, IN, SL_clsL[1], SL_regL[1], ctb + 256, rtb + 256);
    // L3: (C,IN)->(A,B)
    conv_t<<<86 * 4, 256, 0, stream>>>(C, IN, A, B, SL_clsL[2], SL_regL[2], ctb + 512, rtb + 512);
    // L4: (A,B)->(C,IN)
    conv_t<<<86 * 4, 256, 0, stream>>>(A, B, C, IN, SL_clsL[3], SL_regL[3], ctb + 768, rtb + 768);

    mhead_t<<<86 * 8, 256, 0, stream>>>(C, IN, SL_clsH, SL_regH, cob, rob, keys, cnt, regout);

    sort5_k<<<5, 1024, 0, stream>>>(keys, cnt);
    emit_k<<<(NCAND + 255) / 256, 256, 0, stream>>>(keys, cnt, regout, anchors, cs, cbx, cl);
    rank_k<<<(NCAND + 255) / 256, 256, 0, stream>>>(cs, cbx, cl, cnt, order, sbox, sarea, nvp);
    mask_k<<<(NCAND * 80 + 255) / 256, 256, 0, stream>>>(sbox, sarea, nvp, mask);
    sweep_k<<<1, 64, 0, stream>>>(mask, nvp, accbuf, naccp);
    fill_k<<<5, 64, 0, stream>>>(cs, cbx, cl, order, accbuf, naccp, out);
}

// Round 8
// 528.150 us; speedup vs baseline: 19.2141x; 1.2367x over previous
//
#include <hip/hip_runtime.h>
#include <hip/hip_bf16.h>
#include <math.h>

#define CIN 256
#define NUM_CLASSES 91
#define NUM_ANCH 9
#define KEY_CAP 65536
#define NCAND 5000
#define BBOX_CLIP_F 4.135166556742356f
#define CLS_THRESH 0.05f
#define PITCH 5456
#define PP_TOT 5972
#define PLANE_E 1528832      // ushorts per plane (8*5972*32)
#define PLANE_B 3057664      // bytes per plane
#define ABUF_B  6115328      // bytes per act buffer (hi+lo plane)
#define SLB     147456       // bytes per 16-cout weight-frag slice
#define LO_OFF  13312        // LDS offset of lo plane within a phase
#define PHASE   26624        // LDS bytes per phase (hi+lo)

typedef __attribute__((ext_vector_type(4))) float f4;
typedef _Float16 h8 __attribute__((ext_vector_type(8)));

#define MFMA(a,b,c) __builtin_amdgcn_mfma_f32_16x16x32_f16(a,b,c,0,0,0)

__constant__ int c_wsh[5]  = {6,5,4,3,2};
__constant__ int c_hw[5]   = {4096,1024,256,64,16};
__constant__ int c_wp[5]   = {66,34,18,10,6};
__constant__ int c_poff[5] = {0,4356,5512,5836,5936};
__constant__ int c_slen[5] = {198,136,108,100,36};   // strip len for 64-px tiles
__constant__ int c_loff[5] = {0,4096,5120,5376,5440};
__constant__ int c_aoff[5] = {0,36864,46080,48384,48960};
// wf slice ranges: clsL2,clsL3,clsL4,regL1,regL2,regL3,regL4,clsHead(52),regHead(4),clsL1(16)
__constant__ int s_cum[11] = {0,16,32,48,64,80,96,112,164,168,184};

__device__ __forceinline__ unsigned short f16r(float f) {
    _Float16 h = (_Float16)f;
    return __builtin_bit_cast(unsigned short, h);
}
__device__ __forceinline__ float f16tof(unsigned short u) {
    return (float)__builtin_bit_cast(_Float16, u);
}
// split v = h + l/4096, h zero-guarded against f16 denormal flush, l pre-scaled x4096
__device__ __forceinline__ void split16(float v, unsigned short& h, unsigned short& l) {
    unsigned short hh = (fabsf(v) < 6.103515625e-05f) ? (unsigned short)0 : f16r(v);
    h = hh;
    l = f16r((v - f16tof(hh)) * 4096.0f);
}
__device__ __forceinline__ void gl_lds(const void* g, void* l) {
    __builtin_amdgcn_global_load_lds((const __attribute__((address_space(1))) void*)g,
                                     (__attribute__((address_space(3))) void*)l, 16, 0, 0);
}
__device__ __forceinline__ void tile_geom(int tile, int& lvl, int& px0, int& y0) {
    if (tile < 64)      { lvl = 0; px0 = tile << 6; y0 = tile; }
    else if (tile < 80) { lvl = 1; int j = tile - 64; px0 = j << 6; y0 = j << 1; }
    else if (tile < 84) { lvl = 2; int j = tile - 80; px0 = j << 6; y0 = j << 2; }
    else if (tile == 84){ lvl = 3; px0 = 0; y0 = 0; }
    else                { lvl = 4; px0 = 0; y0 = 0; }
}

// ---------------- pad + split + chunk the input pyramid ----------------
__global__ void pad_k(const float* __restrict__ f0, const float* __restrict__ f1,
                      const float* __restrict__ f2, const float* __restrict__ f3,
                      const float* __restrict__ f4, unsigned short* __restrict__ IN) {
    int gid = blockIdx.x * 256 + threadIdx.x;
    if (gid >= 256 * PITCH) return;
    int cin = gid / PITCH, g = gid - cin * PITCH;
    int lvl = (g < 4096) ? 0 : (g < 5120) ? 1 : (g < 5376) ? 2 : (g < 5440) ? 3 : 4;
    const float* f = (lvl == 0) ? f0 : (lvl == 1) ? f1 : (lvl == 2) ? f2 : (lvl == 3) ? f3 : f4;
    int pix = g - c_loff[lvl];
    int wsh = c_wsh[lvl];
    int y = pix >> wsh, x = pix & ((1 << wsh) - 1);
    float v = f[(size_t)cin * c_hw[lvl] + pix];
    unsigned short h, l;
    split16(v, h, l);
    size_t idx = ((size_t)(cin >> 5) * PP_TOT + c_poff[lvl] + (size_t)(y + 1) * c_wp[lvl] + x + 1) * 32 + (cin & 31);
    IN[idx] = h;
    IN[PLANE_E + idx] = l;
}

// ---------------- weight fragment prep (f16 hi + scaled-lo, MFMA B-frag order) ----------------
__global__ void wprep_k(const float* __restrict__ ctw, const float* __restrict__ rtw,
                        const float* __restrict__ cow, const float* __restrict__ row_,
                        unsigned short* __restrict__ wf) {
    int gid = blockIdx.x * 256 + threadIdx.x;
    if (gid >= 184 * 72 * 64) return;
    int lane = gid & 63;
    int t = gid >> 6;
    int tap = t % 9;
    int t2 = t / 9;
    int chunk = t2 & 7;
    int cbg = t2 >> 3;
    int r = 0;
#pragma unroll
    for (int i = 1; i <= 10; ++i) if (cbg >= s_cum[i]) r = i;
    int cbl = cbg - s_cum[r];
    const float* src;
    int coutCnt;
    if (r < 3)       { src = ctw + (size_t)(r + 1) * 589824; coutCnt = 256; }
    else if (r < 7)  { src = rtw + (size_t)(r - 3) * 589824; coutCnt = 256; }
    else if (r == 7) { src = cow; coutCnt = 819; }
    else if (r == 8) { src = row_; coutCnt = 36; }
    else             { src = ctw; coutCnt = 256; }
    int cout = cbl * 16 + (lane & 15);
    int q = lane >> 4;
    unsigned short H[8], L[8];
#pragma unroll
    for (int j = 0; j < 8; ++j) {
        int cin = chunk * 32 + q * 8 + j;
        float v = (cout < coutCnt) ? src[((size_t)cout * 256 + cin) * 9 + tap] : 0.0f;
        split16(v, H[j], L[j]);
    }
    size_t off = (size_t)cbg * 73728 + (size_t)(chunk * 9 + tap) * 1024 + (size_t)lane * 8;
#pragma unroll
    for (int j = 0; j < 8; ++j) { wf[off + j] = H[j]; wf[off + 512 + j] = L[j]; }
}

// ---------------- MFMA K-loop: wave = 32px x 32cout, dbuf LDS, B register-pipelined ----------------
__device__ __forceinline__ void kloop(const unsigned short* __restrict__ src,
        const char* __restrict__ wf0, char* sm, int wid, int lane,
        int s_base, int s_len, int Wp, const int sloc[2], f4 acc1[2][2], f4 acc2[2][2]) {
    const char* wp = wf0 + lane * 16;
    int nc = (s_len * 64 + 1023) >> 10;
    const char* gbase = (const char*)src;
    {
        const char* g = gbase + (size_t)s_base * 64;
        for (int c = wid; c < nc; c += 4) {
            gl_lds(g + (size_t)c * 1024 + (size_t)lane * 16, sm + c * 1024);
            gl_lds(g + PLANE_B + (size_t)c * 1024 + (size_t)lane * 16, sm + LO_OFF + c * 1024);
        }
    }
    // prefetch B fragments for kt = 0
    h8 bh0 = *(const h8*)(wp);
    h8 bl0 = *(const h8*)(wp + 1024);
    h8 bh1 = *(const h8*)(wp + SLB);
    h8 bl1 = *(const h8*)(wp + SLB + 1024);
    __syncthreads();
    for (int chunk = 0; chunk < 8; ++chunk) {
        char* smc = sm + (chunk & 1) * PHASE;
        if (chunk < 7) {   // issue next-chunk staging BEFORE compute
            char* smn = sm + ((chunk & 1) ^ 1) * PHASE;
            const char* g = gbase + ((size_t)(chunk + 1) * PP_TOT + s_base) * 64;
            for (int c = wid; c < nc; c += 4) {
                gl_lds(g + (size_t)c * 1024 + (size_t)lane * 16, smn + c * 1024);
                gl_lds(g + PLANE_B + (size_t)c * 1024 + (size_t)lane * 16, smn + LO_OFF + c * 1024);
            }
        }
#pragma unroll
        for (int tap = 0; tap < 9; ++tap) {
            int kt = chunk * 9 + tap;
            int wo2 = ((kt < 71) ? kt + 1 : kt) * 2048;   // next-tap B prefetch (clamped)
            h8 nh0 = *(const h8*)(wp + wo2);
            h8 nl0 = *(const h8*)(wp + wo2 + 1024);
            h8 nh1 = *(const h8*)(wp + SLB + wo2);
            h8 nl1 = *(const h8*)(wp + SLB + wo2 + 1024);
            int toff = ((tap / 3) - 1) * Wp + (tap % 3) - 1;
            int so = toff * 64;
            h8 ah0 = *(const h8*)(smc + sloc[0] + so);
            h8 al0 = *(const h8*)(smc + LO_OFF + sloc[0] + so);
            h8 ah1 = *(const h8*)(smc + sloc[1] + so);
            h8 al1 = *(const h8*)(smc + LO_OFF + sloc[1] + so);
            acc1[0][0] = MFMA(ah0, bh0, acc1[0][0]);
            acc2[0][0] = MFMA(al0, bh0, acc2[0][0]);
            acc2[0][0] = MFMA(ah0, bl0, acc2[0][0]);
            acc1[1][0] = MFMA(ah1, bh0, acc1[1][0]);
            acc2[1][0] = MFMA(al1, bh0, acc2[1][0]);
            acc2[1][0] = MFMA(ah1, bl0, acc2[1][0]);
            acc1[0][1] = MFMA(ah0, bh1, acc1[0][1]);
            acc2[0][1] = MFMA(al0, bh1, acc2[0][1]);
            acc2[0][1] = MFMA(ah0, bl1, acc2[0][1]);
            acc1[1][1] = MFMA(ah1, bh1, acc1[1][1]);
            acc2[1][1] = MFMA(al1, bh1, acc2[1][1]);
            acc2[1][1] = MFMA(ah1, bl1, acc2[1][1]);
            bh0 = nh0; bl0 = nl0; bh1 = nh1; bl1 = nl1;
        }
        __syncthreads();
    }
}

// ---------------- fused tower layer: both towers, 64px x 64cout blocks (4 waves) ----------------
__global__ __launch_bounds__(256, 3) void conv_t(
        const unsigned short* __restrict__ srcC, const unsigned short* __restrict__ srcR,
        unsigned short* __restrict__ dstC, unsigned short* __restrict__ dstR,
        const unsigned short* __restrict__ wfC, const unsigned short* __restrict__ wfR,
        const float* __restrict__ bC, const float* __restrict__ bR) {
    __shared__ __align__(16) char sm[2 * PHASE];
    int tid = threadIdx.x, lane = tid & 63, wid = tid >> 6;
    int quad = lane >> 4, l16 = lane & 15;
    int bx = blockIdx.x;
    int cb = bx & 3, tower = (bx >> 2) & 1, tile = bx >> 3;
    const unsigned short* src = tower ? srcR : srcC;
    unsigned short* dst = tower ? dstR : dstC;
    const unsigned short* wfx = tower ? wfR : wfC;
    const float* bias = tower ? bR : bC;

    int lvl, px0, y0;
    tile_geom(tile, lvl, px0, y0);
    int wsh = c_wsh[lvl], HW = c_hw[lvl], Wp = c_wp[lvl];
    int poff = c_poff[lvl];
    int s_base = poff + y0 * Wp, s_len = c_slen[lvl];
    int Mh = (wid & 1) * 32, Nh32 = wid >> 1;      // wave: 32 px x 32 couts (2 slices)

    int sloc[2];
#pragma unroll
    for (int mb = 0; mb < 2; ++mb) {
        int p = px0 + Mh + mb * 16 + l16;
        if (p >= HW) p = HW - 1;
        int y = p >> wsh, x = p & ((1 << wsh) - 1);
        sloc[mb] = ((y - y0 + 1) * Wp + x + 1) * 64 + quad * 16;
    }
    f4 acc1[2][2], acc2[2][2];
#pragma unroll
    for (int mb = 0; mb < 2; ++mb)
#pragma unroll
        for (int sl = 0; sl < 2; ++sl) { acc1[mb][sl] = (f4)0.0f; acc2[mb][sl] = (f4)0.0f; }

    const char* wf0 = (const char*)wfx + (size_t)(cb * 4 + Nh32 * 2) * SLB;
    kloop(src, wf0, sm, wid, lane, s_base, s_len, Wp, sloc, acc1, acc2);

    int cbase = cb * 64 + Nh32 * 32;
    float bv[2];
    bv[0] = bias[cbase + l16];
    bv[1] = bias[cbase + 16 + l16];
#pragma unroll
    for (int mb = 0; mb < 2; ++mb) {
        int pb = px0 + Mh + mb * 16 + quad * 4;
#pragma unroll
        for (int r = 0; r < 4; ++r) {
            int p = pb + r;
            bool valid = p < HW;
            int pc = valid ? p : 0;
            int y = pc >> wsh, x = pc & ((1 << wsh) - 1);
            size_t ppix = poff + (size_t)(y + 1) * Wp + x + 1;
#pragma unroll
            for (int sl = 0; sl < 2; ++sl) {
                int coutg = cbase + sl * 16 + l16;
                float v = fmaf(acc2[mb][sl][r], 0.000244140625f, acc1[mb][sl][r]) + bv[sl];
                v = fmaxf(v, 0.0f);
                unsigned short h, l;
                split16(v, h, l);
                size_t idx = ((size_t)(coutg >> 5) * PP_TOT + ppix) * 32 + (coutg & 31);
                if (valid) { dst[idx] = h; dst[PLANE_E + idx] = l; }
            }
        }
    }
}

// ---------------- fused heads: cls (sigmoid+collect fused) + reg ----------------
__global__ __launch_bounds__(256, 3) void mhead_t(
        const unsigned short* __restrict__ srcC, const unsigned short* __restrict__ srcR,
        const unsigned short* __restrict__ wfCls, const unsigned short* __restrict__ wfReg,
        const float* __restrict__ cob, const float* __restrict__ rob,
        unsigned long long* __restrict__ keys, int* __restrict__ cnt,
        float* __restrict__ regout) {
    __shared__ __align__(16) char sm[2 * PHASE];
    int tid = threadIdx.x, lane = tid & 63, wid = tid >> 6;
    int quad = lane >> 4, l16 = lane & 15;
    int bx = blockIdx.x, tile = bx / 14, sub = bx - tile * 14;
    bool isCls = sub < 13;

    int lvl, px0, y0;
    tile_geom(tile, lvl, px0, y0);
    int wsh = c_wsh[lvl], HW = c_hw[lvl], Wp = c_wp[lvl];
    int poff = c_poff[lvl];
    int s_base = poff + y0 * Wp, s_len = c_slen[lvl];
    int Mh = (wid & 1) * 32, Nh32 = wid >> 1;      // wave: 32 px x 32 couts

    int sloc[2];
#pragma unroll
    for (int mb = 0; mb < 2; ++mb) {
        int p = px0 + Mh + mb * 16 + l16;
        if (p >= HW) p = HW - 1;
        int y = p >> wsh, x = p & ((1 << wsh) - 1);
        sloc[mb] = ((y - y0 + 1) * Wp + x + 1) * 64 + quad * 16;
    }
    f4 acc1[2][2], acc2[2][2];
#pragma unroll
    for (int mb = 0; mb < 2; ++mb)
#pragma unroll
        for (int sl = 0; sl < 2; ++sl) { acc1[mb][sl] = (f4)0.0f; acc2[mb][sl] = (f4)0.0f; }

    const unsigned short* src = isCls ? srcC : srcR;
    // cls: sub s covers couts [s*64, s*64+64) over 52 slices (tail zero-padded)
    // reg: couts [Nh32*32 ...), guarded by ch<36; OOB slices are zero-padded in wf
    const char* wf0 = isCls ? (const char*)wfCls + (size_t)(sub * 4 + Nh32 * 2) * SLB
                            : (const char*)wfReg + (size_t)(Nh32 * 2) * SLB;
    kloop(src, wf0, sm, wid, lane, s_base, s_len, Wp, sloc, acc1, acc2);

    if (isCls) {
        int chb = sub * 64 + Nh32 * 32;
        float cbv[2];
#pragma unroll
        for (int sl = 0; sl < 2; ++sl) {
            int ch = chb + sl * 16 + l16;
            cbv[sl] = (ch < 819) ? cob[ch] : 0.0f;
        }
#pragma unroll
        for (int mb = 0; mb < 2; ++mb) {
            int pb = px0 + Mh + mb * 16 + quad * 4;
#pragma unroll
            for (int r = 0; r < 4; ++r) {
                int p = pb + r;
                bool valid = p < HW;
#pragma unroll
                for (int sl = 0; sl < 2; ++sl) {
                    int ch = chb + sl * 16 + l16;
                    if (valid && ch < 819) {
                        float lg = fmaf(acc2[mb][sl][r], 0.000244140625f, acc1[mb][sl][r]) + cbv[sl];
                        float s = 1.0f / (1.0f + expf(-lg));
                        if (s > CLS_THRESH) {
                            int a = ch / NUM_CLASSES;
                            int cls = ch - a * NUM_CLASSES;
                            unsigned flat = (unsigned)((p * NUM_ANCH + a) * NUM_CLASSES + cls);
                            int pos = atomicAdd(cnt + lvl, 1);
                            if (pos < KEY_CAP)
                                keys[(size_t)lvl * KEY_CAP + pos] =
                                    ((unsigned long long)__float_as_uint(s) << 32) |
                                    (unsigned long long)(~flat);
                        }
                    }
                }
            }
        }
    } else {
        int chb = Nh32 * 32;
        float rbv[2];
#pragma unroll
        for (int sl = 0; sl < 2; ++sl) {
            int ch = chb + sl * 16 + l16;
            rbv[sl] = (ch < 36) ? rob[ch] : 0.0f;
        }
        int loff = c_loff[lvl];
#pragma unroll
        for (int mb = 0; mb < 2; ++mb) {
            int pb = px0 + Mh + mb * 16 + quad * 4;
#pragma unroll
            for (int r = 0; r < 4; ++r) {
                int p = pb + r;
                bool valid = p < HW;
#pragma unroll
                for (int sl = 0; sl < 2; ++sl) {
                    int ch = chb + sl * 16 + l16;
                    if (valid && ch < 36)
                        regout[(size_t)ch * PITCH + loff + p] =
                            fmaf(acc2[mb][sl][r], 0.000244140625f, acc1[mb][sl][r]) + rbv[sl];
                }
            }
        }
    }
}

// ---------------- 5 per-level sorts ----------------
__global__ __launch_bounds__(1024) void sort5_k(unsigned long long* keys, const int* cnt) {
    const int lvl = blockIdx.x;
    unsigned long long* kb = keys + (size_t)lvl * KEY_CAP;
    int n = cnt[lvl]; if (n > KEY_CAP) n = KEY_CAP;
    int m = 2; while (m < n) m <<= 1;
    __shared__ unsigned long long sk[8192];
    if (m <= 8192) {
        for (int i = threadIdx.x; i < m; i += 1024) sk[i] = (i < n) ? kb[i] : 0ull;
        __syncthreads();
        for (int k = 2; k <= m; k <<= 1)
            for (int j = k >> 1; j > 0; j >>= 1) {
                for (int i = threadIdx.x; i < m; i += 1024) {
                    int ixj = i ^ j;
                    if (ixj > i) {
                        unsigned long long a = sk[i], b = sk[ixj];
                        bool desc = (i & k) == 0;
                        if (desc ? (a < b) : (a > b)) { sk[i] = b; sk[ixj] = a; }
                    }
                }
                __syncthreads();
            }
        for (int i = threadIdx.x; i < m; i += 1024) kb[i] = sk[i];
    } else {
        for (int i = threadIdx.x; i < m; i += 1024) if (i >= n) kb[i] = 0ull;
        __syncthreads();
        for (int k = 2; k <= m; k <<= 1)
            for (int j = k >> 1; j > 0; j >>= 1) {
                for (int i = threadIdx.x; i < m; i += 1024) {
                    int ixj = i ^ j;
                    if (ixj > i) {
                        unsigned long long a = kb[i], b = kb[ixj];
                        bool desc = (i & k) == 0;
                        if (desc ? (a < b) : (a > b)) { kb[i] = b; kb[ixj] = a; }
                    }
                }
                __syncthreads();
            }
    }
}

// ---------------- emit top-1000 per level ----------------
__global__ void emit_k(const unsigned long long* __restrict__ keys, const int* __restrict__ cnt,
                       const float* __restrict__ regout, const float* __restrict__ anchors,
                       float* __restrict__ cs, float* __restrict__ cb, int* __restrict__ cl) {
#pragma clang fp contract(off)
    int r = blockIdx.x * 256 + threadIdx.x;
    if (r >= NCAND) return;
    int lvl = r / 1000, rr = r - lvl * 1000;
    int n = cnt[lvl]; if (n > KEY_CAP) n = KEY_CAP; if (n > 1000) n = 1000;
    float score = -1.0f, b0 = 0.f, b1 = 0.f, b2 = 0.f, b3 = 0.f;
    int label = 0;
    if (rr < n) {
        unsigned long long key = keys[(size_t)lvl * KEY_CAP + rr];
        score = __uint_as_float((unsigned)(key >> 32));
        unsigned flat = ~((unsigned)(key & 0xFFFFFFFFull));
        label = (int)(flat % NUM_CLASSES);
        int af = (int)(flat / NUM_CLASSES);
        int a = af % NUM_ANCH;
        int pix = af / NUM_ANCH;
        int gp = c_loff[lvl] + pix;
        float dx = regout[(size_t)(a * 4 + 0) * PITCH + gp];
        float dy = regout[(size_t)(a * 4 + 1) * PITCH + gp];
        float dw = regout[(size_t)(a * 4 + 2) * PITCH + gp];
        float dh = regout[(size_t)(a * 4 + 3) * PITCH + gp];
        const float* an = anchors + (size_t)(c_aoff[lvl] + af) * 4;
        float aw = an[2] - an[0];
        float ah = an[3] - an[1];
        float cx = an[0] + 0.5f * aw;
        float cy = an[1] + 0.5f * ah;
        dw = fminf(dw, BBOX_CLIP_F);
        dh = fminf(dh, BBOX_CLIP_F);
        float pcx = dx * aw + cx;
        float pcy = dy * ah + cy;
        float pw = expf(dw) * aw;
        float ph = expf(dh) * ah;
        b0 = fminf(fmaxf(pcx - 0.5f * pw, 0.0f), 512.0f);
        b1 = fminf(fmaxf(pcy - 0.5f * ph, 0.0f), 512.0f);
        b2 = fminf(fmaxf(pcx + 0.5f * pw, 0.0f), 512.0f);
        b3 = fminf(fmaxf(pcy + 0.5f * ph, 0.0f), 512.0f);
    }
    cs[r] = score;
    cb[(size_t)r * 4 + 0] = b0;
    cb[(size_t)r * 4 + 1] = b1;
    cb[(size_t)r * 4 + 2] = b2;
    cb[(size_t)r * 4 + 3] = b3;
    cl[r] = label;
}

// ---------------- global rank via per-level binary search ----------------
__global__ void rank_k(const float* __restrict__ cs, const float* __restrict__ cbx,
                       const int* __restrict__ cl, const int* __restrict__ cnt,
                       int* __restrict__ order, float* __restrict__ sbox,
                       float* __restrict__ sarea, int* __restrict__ nvp) {
#pragma clang fp contract(off)
    __shared__ int vls[5];
    int t = blockIdx.x * 256 + threadIdx.x;
    if (threadIdx.x < 5) {
        int n = cnt[threadIdx.x]; if (n > 1000) n = 1000;
        vls[threadIdx.x] = n;
    }
    __syncthreads();
    if (t >= NCAND) return;
    if (t == 0) *nvp = vls[0] + vls[1] + vls[2] + vls[3] + vls[4];
    int lvl = t / 1000, pos = t - lvl * 1000;
    if (pos >= vls[lvl]) return;                 // filler slot
    float s = cs[t];
    int rank = pos;
#pragma unroll
    for (int l2 = 0; l2 < 5; ++l2) {
        if (l2 == lvl) continue;
        int n = vls[l2];
        const float* seg = cs + l2 * 1000;       // descending
        int lo = 0, hi = n;
        if (l2 < lvl) {                          // count >= s
            while (lo < hi) { int mid = (lo + hi) >> 1; if (seg[mid] >= s) lo = mid + 1; else hi = mid; }
        } else {                                 // count > s
            while (lo < hi) { int mid = (lo + hi) >> 1; if (seg[mid] > s) lo = mid + 1; else hi = mid; }
        }
        rank += lo;
    }
    order[rank] = t;
    float off = (float)cl[t] * 513.0f;           // class spacing; cross-class IoU == 0 exactly
    float x1 = cbx[(size_t)t * 4 + 0] + off;
    float y1 = cbx[(size_t)t * 4 + 1] + off;
    float x2 = cbx[(size_t)t * 4 + 2] + off;
    float y2 = cbx[(size_t)t * 4 + 3] + off;
    sbox[(size_t)rank * 4 + 0] = x1;
    sbox[(size_t)rank * 4 + 1] = y1;
    sbox[(size_t)rank * 4 + 2] = x2;
    sbox[(size_t)rank * 4 + 3] = y2;
    sarea[rank] = (x2 - x1) * (y2 - y1);
}

// ---------------- IoU suppression bitmask over SORTED ranks ----------------
__global__ void mask_k(const float* __restrict__ sbox, const float* __restrict__ sarea,
                       const int* __restrict__ nvp, unsigned long long* __restrict__ mask) {
#pragma clang fp contract(off)
    int nv = *nvp;
    int t = blockIdx.x * 256 + threadIdx.x;
    if (t >= NCAND * 80) return;
    int i = t / 80, w = t - i * 80;
    if (i >= nv) return;
    float ix1 = sbox[(size_t)i * 4 + 0];
    float iy1 = sbox[(size_t)i * 4 + 1];
    float ix2 = sbox[(size_t)i * 4 + 2];
    float iy2 = sbox[(size_t)i * 4 + 3];
    float ai = sarea[i];
    unsigned long long bits = 0ull;
    int j0 = w * 64;
    for (int b = 0; b < 64; ++b) {
        int j = j0 + b;
        if (j < nv) {
            float jx1 = sbox[(size_t)j * 4 + 0];
            float jy1 = sbox[(size_t)j * 4 + 1];
            float jx2 = sbox[(size_t)j * 4 + 2];
            float jy2 = sbox[(size_t)j * 4 + 3];
            float aj = sarea[j];
            float ltx = fmaxf(ix1, jx1), lty = fmaxf(iy1, jy1);
            float rbx = fminf(ix2, jx2), rby = fminf(iy2, jy2);
            float wx = fmaxf(rbx - ltx, 0.0f), wy = fmaxf(rby - lty, 0.0f);
            float inter = wx * wy;
            float iou = inter / (ai + aj - inter + 1e-12f);
            if (iou > 0.5f) bits |= (1ull << b);
        }
    }
    mask[(size_t)i * 80 + w] = bits;
}

// ---------------- single-wave greedy sweep: tile-batched parallel row gather ----------------
__global__ __launch_bounds__(64) void sweep_k(const unsigned long long* __restrict__ mask,
        const int* __restrict__ nvp, int* __restrict__ accbuf, int* __restrict__ naccp) {
    const int l = threadIdx.x;
    int nv = *nvp; if (nv > NCAND) nv = NCAND;
    int nacc = 0;
    if (nv > 0) {
        unsigned long long sup0 = 0ull, sup1 = 0ull;
        int ntiles = (nv + 63) >> 6;
        bool done = false;
        for (int g0 = 0; g0 < ntiles && !done; g0 += 8) {
            int gcnt = ntiles - g0; if (gcnt > 8) gcnt = 8;
            unsigned long long ml[8];
#pragma unroll
            for (int g = 0; g < 8; ++g) {
                int t = g0 + g;
                int row = (t << 6) + l;
                ml[g] = (g < gcnt && row < nv) ? mask[(size_t)row * 80 + t] : 0ull;
            }
            for (int g = 0; g < gcnt && !done; ++g) {
                int t = g0 + g;
                unsigned long long cur = (t < 64)
                    ? (unsigned long long)__shfl((long long)sup0, t, 64)
                    : (unsigned long long)__shfl((long long)sup1, t - 64, 64);
                int lim = nv - (t << 6);
                unsigned long long valid = (lim >= 64) ? ~0ull : ((1ull << lim) - 1ull);
                unsigned long long rem = ~cur & valid;
                unsigned long long Aset = 0ull;
                while (rem) {
                    int k = __builtin_ctzll(rem);
                    Aset |= 1ull << k;
                    if (l == 0) accbuf[nacc] = (t << 6) + k;
                    ++nacc;
                    if (nacc == 300) { done = true; break; }
                    unsigned long long mlk = (unsigned long long)__shfl((long long)ml[g], k, 64);
                    cur |= mlk | (1ull << k);
                    rem = ~cur & valid;
                }
                if (!done) {
                    unsigned long long t2 = Aset;
                    while (t2) {
                        int i0 = __builtin_ctzll(t2); t2 &= t2 - 1;
                        int i1 = -1, i2 = -1, i3 = -1;
                        if (t2) { i1 = __builtin_ctzll(t2); t2 &= t2 - 1; }
                        if (t2) { i2 = __builtin_ctzll(t2); t2 &= t2 - 1; }
                        if (t2) { i3 = __builtin_ctzll(t2); t2 &= t2 - 1; }
                        size_t r0 = (size_t)((t << 6) + i0) * 80;
                        unsigned long long w0 = mask[r0 + l];
                        unsigned long long w1 = (i1 >= 0) ? mask[(size_t)((t << 6) + i1) * 80 + l] : 0ull;
                        unsigned long long w2 = (i2 >= 0) ? mask[(size_t)((t << 6) + i2) * 80 + l] : 0ull;
                        unsigned long long w3 = (i3 >= 0) ? mask[(size_t)((t << 6) + i3) * 80 + l] : 0ull;
                        sup0 |= w0 | w1 | w2 | w3;
                        if (l < 16) {
                            unsigned long long v0 = mask[r0 + 64 + l];
                            unsigned long long v1 = (i1 >= 0) ? mask[(size_t)((t << 6) + i1) * 80 + 64 + l] : 0ull;
                            unsigned long long v2 = (i2 >= 0) ? mask[(size_t)((t << 6) + i2) * 80 + 64 + l] : 0ull;
                            unsigned long long v3 = (i3 >= 0) ? mask[(size_t)((t << 6) + i3) * 80 + 64 + l] : 0ull;
                            sup1 |= v0 | v1 | v2 | v3;
                        }
                    }
                }
            }
        }
    }
    if (l == 0) *naccp = nacc;
}

// ---------------- fill outputs from accepted ranks ----------------
__global__ void fill_k(const float* __restrict__ cs, const float* __restrict__ cb,
                       const int* __restrict__ cl, const int* __restrict__ order,
                       const int* __restrict__ accbuf, const int* __restrict__ naccp,
                       float* __restrict__ out) {
    int t = blockIdx.x * 64 + threadIdx.x;
    if (t >= 300) return;
    int na = *naccp;
    if (t < na) {
        int c = order[accbuf[t]];
        out[t * 5 + 0] = cs[c];
        out[t * 5 + 1] = cb[(size_t)c * 4 + 0];
        out[t * 5 + 2] = cb[(size_t)c * 4 + 1];
        out[t * 5 + 3] = cb[(size_t)c * 4 + 2];
        out[t * 5 + 4] = cb[(size_t)c * 4 + 3];
        out[1500 + t] = (float)cl[c];
    } else {
        out[t * 5 + 0] = 0.0f; out[t * 5 + 1] = 0.0f; out[t * 5 + 2] = 0.0f;
        out[t * 5 + 3] = 0.0f; out[t * 5 + 4] = 0.0f;
        out[1500 + t] = -1.0f;
    }
}

// ---------------- host launch ----------------
extern "C" void kernel_launch(void* const* d_in, const int* in_sizes, int n_in,
                              void* d_out, int out_size, void* d_ws, size_t ws_size,
                              hipStream_t stream) {
    const float* f0 = (const float*)d_in[0];
    const float* f1 = (const float*)d_in[1];
    const float* f2 = (const float*)d_in[2];
    const float* f3 = (const float*)d_in[3];
    const float* f4 = (const float*)d_in[4];
    const float* anchors = (const float*)d_in[5];
    const float* ctw = (const float*)d_in[6];
    const float* ctb = (const float*)d_in[7];
    const float* cow = (const float*)d_in[8];
    const float* cob = (const float*)d_in[9];
    const float* rtw = (const float*)d_in[10];
    const float* rtb = (const float*)d_in[11];
    const float* row_ = (const float*)d_in[12];
    const float* rob = (const float*)d_in[13];
    float* out = (float*)d_out;

    char* base = (char*)d_ws;
    unsigned short* wf = (unsigned short*)base;
    unsigned short* C  = (unsigned short*)(base + 24772608);
    unsigned short* IN = (unsigned short*)(base + 30887936);
    unsigned short* A  = (unsigned short*)(base + 37003264);
    unsigned short* B  = (unsigned short*)(base + 43118592);
    int* cnt           = (int*)(base + 49233920);   // cnt[0..4], nv at [6], nacc at [7]
    int* nvp           = cnt + 6;
    int* naccp         = cnt + 7;
    float* cs    = (float*)(base + 0);              // wf head (dead after mhead)
    float* cbx   = (float*)(base + 32768);
    int*   cl    = (int*)(base + 131072);
    int*   order = (int*)(base + 163840);
    float* sbox  = (float*)(base + 262144);
    float* sarea = (float*)(base + 344064);
    int*   accbuf = (int*)(base + 368640);
    unsigned long long* keys = (unsigned long long*)A;          // A dead after layer 4
    float* regout            = (float*)(base + 37003264 + 2621440);
    unsigned long long* mask = (unsigned long long*)B;          // B dead after layer 4

    unsigned short* SL_clsL[4] = {wf + (size_t)168 * 73728, wf + (size_t)0 * 73728,
                                  wf + (size_t)16 * 73728,  wf + (size_t)32 * 73728};
    unsigned short* SL_regL[4] = {wf + (size_t)48 * 73728, wf + (size_t)64 * 73728,
                                  wf + (size_t)80 * 73728, wf + (size_t)96 * 73728};
    unsigned short* SL_clsH = wf + (size_t)112 * 73728;
    unsigned short* SL_regH = wf + (size_t)164 * 73728;

    hipMemsetAsync(C, 0, 4 * (size_t)ABUF_B, stream);   // zero C, IN, A, B (contiguous)
    hipMemsetAsync(cnt, 0, 32, stream);

    pad_k<<<(256 * PITCH + 255) / 256, 256, 0, stream>>>(f0, f1, f2, f3, f4, IN);
    wprep_k<<<(184 * 72 * 64 + 255) / 256, 256, 0, stream>>>(ctw, rtw, cow, row_, wf);

    // L1: (IN,IN)->(A,B)    [cls-L1 weights live where C will go]
    conv_t<<<86 * 8, 256, 0, stream>>>(IN, IN, A, B, SL_clsL[0], SL_regL[0], ctb, rtb);
    hipMemsetAsync(C, 0, (size_t)ABUF_B, stream);       // re-zero C (was weight data)
    // L2: (A,B)->(C,IN)
    conv_t<<<86 * 8, 256, 0, stream>>>(A, B, C, IN, SL_clsL[1], SL_regL[1], ctb + 256, rtb + 256);
    // L3: (C,IN)->(A,B)
    conv_t<<<86 * 8, 256, 0, stream>>>(C, IN, A, B, SL_clsL[2], SL_regL[2], ctb + 512, rtb + 512);
    // L4: (A,B)->(C,IN)
    conv_t<<<86 * 8, 256, 0, stream>>>(A, B, C, IN, SL_clsL[3], SL_regL[3], ctb + 768, rtb + 768);

    mhead_t<<<86 * 14, 256, 0, stream>>>(C, IN, SL_clsH, SL_regH, cob, rob, keys, cnt, regout);

    sort5_k<<<5, 1024, 0, stream>>>(keys, cnt);
    emit_k<<<(NCAND + 255) / 256, 256, 0, stream>>>(keys, cnt, regout, anchors, cs, cbx, cl);
    rank_k<<<(NCAND + 255) / 256, 256, 0, stream>>>(cs, cbx, cl, cnt, order, sbox, sarea, nvp);
    mask_k<<<(NCAND * 80 + 255) / 256, 256, 0, stream>>>(sbox, sarea, nvp, mask);
    sweep_k<<<1, 64, 0, stream>>>(mask, nvp, accbuf, naccp);
    fill_k<<<5, 64, 0, stream>>>(cs, cbx, cl, order, accbuf, naccp, out);
}